// Round 7
// baseline (1145.227 us; speedup 1.0000x reference)
//
#include <hip/hip_runtime.h>
#include <hip/hip_bf16.h>

#define D_ 128
#define L_ 65536
#define C_ 32768
#define E_ 262144

typedef __hip_bfloat16 bf16;
typedef __attribute__((ext_vector_type(8))) short short8;
typedef __attribute__((ext_vector_type(4))) float f32x4;

// flags[0] = 1 if float inputs are fp32 (else bf16); flags[1] = 1 if edge idx int32 (else int64)
__global__ void detect_k(const unsigned short* __restrict__ wmem,
                         const int* __restrict__ li, int* __restrict__ flags) {
    int t = blockIdx.x * 512 + threadIdx.x;
    if (t < 8192) {
        unsigned short h = wmem[2 * t];
        float v = __bfloat162float(*(const bf16*)&h);
        if (!(fabsf(v) < 0.5f)) atomicOr(&flags[0], 1);
    }
    if (t < 2048) {
        if (li[2 * t + 1] != 0) atomicOr(&flags[1], 1);
    }
}

__device__ __forceinline__ void split2(float v, unsigned short& h, unsigned short& l) {
    bf16 bh = __float2bfloat16(v);
    float fh = __bfloat162float(bh);
    bf16 bl = __float2bfloat16(v - fh);
    h = *(unsigned short*)&bh;
    l = *(unsigned short*)&bl;
}

__device__ __forceinline__ float ldf(const void* s, int i, int isf32) {
    return isf32 ? ((const float*)s)[i] : __bfloat162float(((const bf16*)s)[i]);
}

// index fix (int32/int64, clamp) + degree count, both sides in one launch
__global__ void fixdeg_k(const int* __restrict__ ls, const int* __restrict__ cs,
                         int* __restrict__ ld_idx, int* __restrict__ cd_idx,
                         int* __restrict__ ldeg, int* __restrict__ cdeg,
                         const int* __restrict__ flags) {
    int i = blockIdx.x * 256 + threadIdx.x;
    int is32 = flags[1];
    if (i < E_) {
        int v = is32 ? ls[i] : ls[2 * i];
        v = min(max(v, 0), L_ - 1);
        ld_idx[i] = v;
        atomicAdd(&ldeg[v], 1);
    } else {
        int j = i - E_;
        int v = is32 ? cs[j] : cs[2 * j];
        v = min(max(v, 0), C_ - 1);
        cd_idx[j] = v;
        atomicAdd(&cdeg[v], 1);
    }
}

// weights: W[k][n] -> transposed bf16 hi/lo [n][k] packed pool; tail: biases -> fp32
__global__ void cvtwb_k(const void* s0, const void* s1, const void* s2, const void* s3,
                        const void* s4, const void* s5, const void* s6, const void* s7,
                        const void* t0, const void* t1, const void* t2, const void* t3,
                        const void* t4, const void* t5, const void* t6, const void* t7,
                        unsigned short* __restrict__ hi, unsigned short* __restrict__ lo,
                        float* __restrict__ bb, const int* __restrict__ flags) {
    int i = blockIdx.x * 256 + threadIdx.x;  // 181248 total
    int isf = flags[0];
    if (i >= 180224) {
        int j = i - 180224;  // 0..1023
        const void* src;
        switch (j >> 7) {
            case 0: src = t0; break; case 1: src = t1; break;
            case 2: src = t2; break; case 3: src = t3; break;
            case 4: src = t4; break; case 5: src = t5; break;
            case 6: src = t6; break; default: src = t7; break;
        }
        bb[j] = ldf(src, j & 127, isf);
        return;
    }
    const void* src; int K, base;
    if      (i <  16384) { src = s0; K = 128; base = 0; }
    else if (i <  32768) { src = s1; K = 128; base = 16384; }
    else if (i <  49152) { src = s2; K = 128; base = 32768; }
    else if (i <  65536) { src = s3; K = 128; base = 49152; }
    else if (i <  81920) { src = s4; K = 128; base = 65536; }
    else if (i <  98304) { src = s5; K = 128; base = 81920; }
    else if (i < 131072) { src = s6; K = 256; base = 98304; }
    else                 { src = s7; K = 384; base = 131072; }
    int e = i - base;
    int k = e >> 7, n = e & 127;
    float v = ldf(src, e, isf);
    unsigned short h, l;
    split2(v, h, l);
    hi[base + n * K + k] = h;
    lo[base + n * K + k] = l;
}

// broadcast-init embeddings, float4 stores
__global__ void init2_k(const void* __restrict__ lv, const void* __restrict__ cv,
                        float* __restrict__ lemb, float* __restrict__ cemb,
                        const int* __restrict__ flags) {
    int i4 = blockIdx.x * 256 + threadIdx.x;  // float4 id, total (L+C)*32
    int isf = flags[0];
    const void* src; float* dst; int o;
    if (i4 < L_ * 32) { src = lv; dst = lemb; o = i4; }
    else              { src = cv; dst = cemb; o = i4 - L_ * 32; }
    int j = (o & 31) * 4;
    float4 v;
    v.x = ldf(src, j + 0, isf);
    v.y = ldf(src, j + 1, isf);
    v.z = ldf(src, j + 2, isf);
    v.w = ldf(src, j + 3, isf);
    ((float4*)dst)[o] = v;
}

// --- two-level exclusive scans, both sides fused ---
__global__ void scan1b_k(const int* __restrict__ ldeg, const int* __restrict__ cdeg,
                         int* __restrict__ lout, int* __restrict__ cout,
                         int* __restrict__ bsumL, int* __restrict__ bsumC) {
    __shared__ int s[256];
    const int* in; int* out; int* bs; int tile;
    if (blockIdx.x < 256) { in = ldeg; out = lout; bs = bsumL; tile = blockIdx.x; }
    else                  { in = cdeg; out = cout; bs = bsumC; tile = blockIdx.x - 256; }
    int i = tile * 256 + threadIdx.x;
    int v = in[i];
    s[threadIdx.x] = v;
    __syncthreads();
#pragma unroll
    for (int off = 1; off < 256; off <<= 1) {
        int t = (threadIdx.x >= off) ? s[threadIdx.x - off] : 0;
        __syncthreads();
        s[threadIdx.x] += t;
        __syncthreads();
    }
    out[i] = s[threadIdx.x] - v;
    if (threadIdx.x == 255) bs[tile] = s[255];
}

__global__ void scan2b_k(int* __restrict__ bL, int* __restrict__ bC) {
    __shared__ int s[256];
    int* b = blockIdx.x ? bC : bL;
    int nb = blockIdx.x ? 128 : 256;
    int v = (threadIdx.x < nb) ? b[threadIdx.x] : 0;
    s[threadIdx.x] = v;
    __syncthreads();
#pragma unroll
    for (int off = 1; off < 256; off <<= 1) {
        int t = (threadIdx.x >= off) ? s[threadIdx.x - off] : 0;
        __syncthreads();
        s[threadIdx.x] += t;
        __syncthreads();
    }
    if (threadIdx.x < nb) b[threadIdx.x] = s[threadIdx.x] - v;
}

// add block sums, init place cursors, compute invsq = deg ? 1/sqrt(deg) : 0
__global__ void scan3b_k(int* __restrict__ lptr, int* __restrict__ cptr,
                         const int* __restrict__ bsumL, const int* __restrict__ bsumC,
                         int* __restrict__ lcur, int* __restrict__ ccur,
                         const int* __restrict__ ldeg, const int* __restrict__ cdeg,
                         float* __restrict__ invsq_l, float* __restrict__ invsq_c) {
    int b = blockIdx.x, t = threadIdx.x;
    if (b < 256) {
        int i = b * 256 + t;
        int v = lptr[i] + bsumL[b];
        lptr[i] = v; lcur[i] = v;
        int d = ldeg[i];
        invsq_l[i] = d ? rsqrtf((float)d) : 0.0f;
    } else {
        int i = (b - 256) * 256 + t;
        int v = cptr[i] + bsumC[b - 256];
        cptr[i] = v; ccur[i] = v;
        int d = cdeg[i];
        invsq_c[i] = d ? rsqrtf((float)d) : 0.0f;
    }
}

// CSR placement (other endpoint only; norm is separable)
__global__ void place_k(const int* __restrict__ li, const int* __restrict__ ci,
                        int* __restrict__ lcur, int* __restrict__ ccur,
                        int* __restrict__ l_other, int* __restrict__ c_other) {
    int e = blockIdx.x * 256 + threadIdx.x;
    if (e >= E_) return;
    int l = li[e], c = ci[e];
    int p = atomicAdd(&ccur[c], 1);
    c_other[p] = l;
    int q = atomicAdd(&lcur[l], 1);
    l_other[q] = c;
}

// ---------- fused 2-layer MLPs, all three in one launch; 128-row tiles ----------
// blocks [0,nL): l2c on l_cur -> msgL (scaled by invsq_l)
// blocks [nL,nL+nC): c2l on c_cur -> msgC (scaled by invsq_c)
// blocks [nL+nC,...): l2l on l_cur with pair-SWAP -> l2lb (unscaled)
// (EXACT round-0 structure -- best measured: 57.4 us/dispatch.)
__global__ __launch_bounds__(256, 2) void mlp3_k(
    const float* __restrict__ l_cur, const float* __restrict__ c_cur,
    const unsigned short* __restrict__ wt_hi, const unsigned short* __restrict__ wt_lo,
    const float* __restrict__ bb,
    const float* __restrict__ invsq_l, const float* __restrict__ invsq_c,
    bf16* __restrict__ l_msg, bf16* __restrict__ c_msg, bf16* __restrict__ l2lb,
    int nL, int nC) {
    __shared__ char smem[66048];
    unsigned short (*a_hi)[40] = (unsigned short(*)[40])(smem);
    unsigned short (*a_lo)[40] = (unsigned short(*)[40])(smem + 10240);
    unsigned short (*b_hi)[40] = (unsigned short(*)[40])(smem + 20480);
    unsigned short (*b_lo)[40] = (unsigned short(*)[40])(smem + 30720);
    unsigned short* h_hi = (unsigned short*)(smem);          // phase 2 aliases tiles
    unsigned short* h_lo = (unsigned short*)(smem + 32768);
    float* scv = (float*)(smem + 65536);                     // 128 floats, non-aliased

    int b = blockIdx.x, seg, tile;
    if (b < nL)           { seg = 0; tile = b; }
    else if (b < nL + nC) { seg = 1; tile = b - nL; }
    else                  { seg = 2; tile = b - nL - nC; }
    const float* A = (seg == 1) ? c_cur : l_cur;
    bf16* outp = (seg == 0) ? l_msg : (seg == 1) ? c_msg : l2lb;
    const float* invsq = (seg == 0) ? invsq_l : (seg == 1) ? invsq_c : nullptr;
    const unsigned short* W1h = wt_hi + seg * 32768;
    const unsigned short* W1l = wt_lo + seg * 32768;
    const unsigned short* W2h = W1h + 16384;
    const unsigned short* W2l = W1l + 16384;
    const float* b1v = bb + seg * 256;
    const float* b2v = b1v + 128;
    const int swap = (seg == 2);

    const int t = threadIdx.x;
    const int br0 = tile * 128;
    const int w = t >> 6, lane = t & 63;
    const int wr = w >> 1, wc = w & 1;
    const int quad = lane >> 4, cl = lane & 15;

    if (t < 128) scv[t] = invsq ? invsq[br0 + t] : 1.0f;

    f32x4 acc[4][4];
#pragma unroll
    for (int i = 0; i < 4; i++)
#pragma unroll
        for (int j = 0; j < 4; j++) acc[i][j] = (f32x4){0.f, 0.f, 0.f, 0.f};

    // ---- phase 1: h = A @ W1 ----
    for (int kt = 0; kt < 128; kt += 32) {
#pragma unroll
        for (int i = 0; i < 4; i++) {
            int f = t + 256 * i;
            int r = f >> 3, kq = f & 7;
            int gr = br0 + r;
            if (swap) gr ^= 1;
            const float4 v = *(const float4*)&A[(size_t)gr * D_ + kt + 4 * kq];
            unsigned short h0, l0, h1, l1, h2, l2, h3, l3;
            split2(v.x, h0, l0); split2(v.y, h1, l1);
            split2(v.z, h2, l2); split2(v.w, h3, l3);
            *(ushort4*)&a_hi[r][4 * kq] = make_ushort4(h0, h1, h2, h3);
            *(ushort4*)&a_lo[r][4 * kq] = make_ushort4(l0, l1, l2, l3);
            *(ushort4*)&b_hi[r][4 * kq] = *(const ushort4*)&W1h[(size_t)r * 128 + kt + 4 * kq];
            *(ushort4*)&b_lo[r][4 * kq] = *(const ushort4*)&W1l[(size_t)r * 128 + kt + 4 * kq];
        }
        __syncthreads();
        short8 af_h[4], af_l[4];
#pragma unroll
        for (int i = 0; i < 4; i++) {
            int row = 64 * wr + 16 * i + cl;
            af_h[i] = *(const short8*)&a_hi[row][quad * 8];
            af_l[i] = *(const short8*)&a_lo[row][quad * 8];
        }
#pragma unroll
        for (int j = 0; j < 4; j++) {
            int col = 64 * wc + 16 * j + cl;
            short8 bf_h = *(const short8*)&b_hi[col][quad * 8];
            short8 bf_l = *(const short8*)&b_lo[col][quad * 8];
#pragma unroll
            for (int i = 0; i < 4; i++) {
                acc[i][j] = __builtin_amdgcn_mfma_f32_16x16x32_bf16(af_h[i], bf_h, acc[i][j], 0, 0, 0);
                acc[i][j] = __builtin_amdgcn_mfma_f32_16x16x32_bf16(af_h[i], bf_l, acc[i][j], 0, 0, 0);
                acc[i][j] = __builtin_amdgcn_mfma_f32_16x16x32_bf16(af_l[i], bf_h, acc[i][j], 0, 0, 0);
            }
        }
        __syncthreads();
    }
    // h epilogue: bias + relu + split -> swizzled LDS. C/D: col=cl, row=quad*4+reg.
#pragma unroll
    for (int j = 0; j < 4; j++) {
        int col = 64 * wc + 16 * j + cl;
        float bv = b1v[col];
        int g = col >> 3, go = col & 7;
#pragma unroll
        for (int i = 0; i < 4; i++) {
            int rloc = 64 * wr + 16 * i + quad * 4;
#pragma unroll
            for (int rg = 0; rg < 4; rg++) {
                float v = fmaxf(acc[i][j][rg] + bv, 0.0f);
                unsigned short hh, ll;
                split2(v, hh, ll);
                int r = rloc + rg;
                int off = r * 128 + ((g ^ (r & 15)) << 3) + go;
                h_hi[off] = hh;
                h_lo[off] = ll;
            }
        }
    }
    __syncthreads();
    // ---- phase 2: out = (h @ W2 + b2) * scv -> bf16 ----
#pragma unroll
    for (int i = 0; i < 4; i++)
#pragma unroll
        for (int j = 0; j < 4; j++) acc[i][j] = (f32x4){0.f, 0.f, 0.f, 0.f};

    for (int kt = 0; kt < 128; kt += 32) {
        short8 af_h[4], af_l[4];
        int gbase = (kt >> 3) + quad;
#pragma unroll
        for (int i = 0; i < 4; i++) {
            int r = 64 * wr + 16 * i + cl;
            int off = r * 128 + ((gbase ^ cl) << 3);
            af_h[i] = *(const short8*)&h_hi[off];
            af_l[i] = *(const short8*)&h_lo[off];
        }
#pragma unroll
        for (int j = 0; j < 4; j++) {
            int col = 64 * wc + 16 * j + cl;
            const short8 bf_h = *(const short8*)&W2h[(size_t)col * 128 + kt + quad * 8];
            const short8 bf_l = *(const short8*)&W2l[(size_t)col * 128 + kt + quad * 8];
#pragma unroll
            for (int i = 0; i < 4; i++) {
                acc[i][j] = __builtin_amdgcn_mfma_f32_16x16x32_bf16(af_h[i], bf_h, acc[i][j], 0, 0, 0);
                acc[i][j] = __builtin_amdgcn_mfma_f32_16x16x32_bf16(af_h[i], bf_l, acc[i][j], 0, 0, 0);
                acc[i][j] = __builtin_amdgcn_mfma_f32_16x16x32_bf16(af_l[i], bf_h, acc[i][j], 0, 0, 0);
            }
        }
    }
#pragma unroll
    for (int j = 0; j < 4; j++) {
        int col = 64 * wc + 16 * j + cl;
        float bv = b2v[col];
#pragma unroll
        for (int i = 0; i < 4; i++) {
            int rloc = 64 * wr + 16 * i + quad * 4;
#pragma unroll
            for (int rg = 0; rg < 4; rg++)
                outp[(size_t)(br0 + rloc + rg) * D_ + col] =
                    __float2bfloat16((acc[i][j][rg] + bv) * scv[rloc + rg]);
        }
    }
}

// ---------- fused GATHER + update GEMMs; 128-row tiles ----------
// FINAL=0: blocks [0,256) c-update K=256 -> c_nxt; [256,768) l-update K=384 -> l_nxt.
// FINAL=1: all blocks l-update K=384 -> d_out (fp32 or bf16 per flags[0]).
// CHANGE vs r0: the aggregate K-range (kt in [128,256)) is GATHERED IN-PLACE during
// staging: per row, sum the 32-col bf16 slice of each CSR neighbor's message
// (source invsq applied at mlp3 output), scale by dest invsq, split2 -> LDS.
// Eliminates the separate gather kernel and the 48MB aggr HBM round-trip per iter.
// A2 (l2l messages, kt>=256) is bf16 -> a_lo==0: skip the Al*Bh MFMA there.
template <int FINAL>
__global__ __launch_bounds__(256, 2) void update_k(
    const float* __restrict__ l_cur, const float* __restrict__ c_cur,
    const unsigned short* __restrict__ msgL, const unsigned short* __restrict__ msgC,
    const bf16* __restrict__ l2lb,
    const int* __restrict__ lptr, const int* __restrict__ ldeg,
    const int* __restrict__ l_other, const float* __restrict__ invsq_l,
    const int* __restrict__ cptr, const int* __restrict__ cdeg,
    const int* __restrict__ c_other, const float* __restrict__ invsq_c,
    const unsigned short* __restrict__ wt_hi, const unsigned short* __restrict__ wt_lo,
    const float* __restrict__ bb,
    float* __restrict__ c_nxt, float* __restrict__ l_nxt,
    void* __restrict__ dout, const int* __restrict__ flags) {
    __shared__ unsigned short a_hi[128][40], a_lo[128][40];
    __shared__ unsigned short b_hi[128][40], b_lo[128][40];
    const int t = threadIdx.x;
    int b = blockIdx.x;
    const bool cseg = (!FINAL) && (b < 256);
    const int tile = (FINAL || cseg) ? b : b - 256;
    const int K = cseg ? 256 : 384;
    const float* A0 = cseg ? c_cur : l_cur;
    const unsigned short* msg = cseg ? msgL : msgC;       // messages to aggregate
    const int* ptr = cseg ? cptr : lptr;
    const int* dgv = cseg ? cdeg : ldeg;
    const int* oth = cseg ? c_other : l_other;
    const float* invsq = cseg ? invsq_c : invsq_l;        // DEST-side scale
    const unsigned short* Wh = wt_hi + (cseg ? 98304 : 131072);
    const unsigned short* Wl = wt_lo + (cseg ? 98304 : 131072);
    const float* bias = bb + (cseg ? 768 : 896);
    const int br0 = tile * 128;
    const int w = t >> 6, lane = t & 63;
    const int wr = w >> 1, wc = w & 1;
    const int quad = lane >> 4, cl = lane & 15;

    f32x4 acc[4][4];
#pragma unroll
    for (int i = 0; i < 4; i++)
#pragma unroll
        for (int j = 0; j < 4; j++) acc[i][j] = (f32x4){0.f, 0.f, 0.f, 0.f};

    for (int kt = 0; kt < K; kt += 32) {
        const bool haslo = (kt < 256);
        const int koff = kt & 127;
#pragma unroll
        for (int i = 0; i < 4; i++) {
            int f = t + 256 * i;
            int r = f >> 3, kq = f & 7;
            if (kt < 128) {
                // embedding range: fp32 load + split (as r0)
                const float4 v = *(const float4*)&A0[(size_t)(br0 + r) * D_ + koff + 4 * kq];
                unsigned short h0, l0, h1, l1, h2, l2, h3, l3;
                split2(v.x, h0, l0); split2(v.y, h1, l1);
                split2(v.z, h2, l2); split2(v.w, h3, l3);
                *(ushort4*)&a_hi[r][4 * kq] = make_ushort4(h0, h1, h2, h3);
                *(ushort4*)&a_lo[r][4 * kq] = make_ushort4(l0, l1, l2, l3);
            } else if (kt < 256) {
                // aggregate range: gather CSR neighbors' bf16 message slice, fp32 sum
                int gr = br0 + r;
                int s = ptr[gr], cnt = dgv[gr];
                float4 sum = {0.f, 0.f, 0.f, 0.f};
                for (int e = 0; e < cnt; e++) {
                    int o = oth[s + e];
                    ushort4 m = *(const ushort4*)&msg[(size_t)o * D_ + koff + 4 * kq];
                    sum.x += __uint_as_float((unsigned)m.x << 16);
                    sum.y += __uint_as_float((unsigned)m.y << 16);
                    sum.z += __uint_as_float((unsigned)m.z << 16);
                    sum.w += __uint_as_float((unsigned)m.w << 16);
                }
                float sc = invsq[gr];
                unsigned short h0, l0, h1, l1, h2, l2, h3, l3;
                split2(sum.x * sc, h0, l0); split2(sum.y * sc, h1, l1);
                split2(sum.z * sc, h2, l2); split2(sum.w * sc, h3, l3);
                *(ushort4*)&a_hi[r][4 * kq] = make_ushort4(h0, h1, h2, h3);
                *(ushort4*)&a_lo[r][4 * kq] = make_ushort4(l0, l1, l2, l3);
            } else {
                // l2l message range: bf16 copy, hi only
                *(ushort4*)&a_hi[r][4 * kq] =
                    *(const ushort4*)&l2lb[(size_t)(br0 + r) * D_ + koff + 4 * kq];
            }
            *(ushort4*)&b_hi[r][4 * kq] = *(const ushort4*)&Wh[(size_t)r * K + kt + 4 * kq];
            *(ushort4*)&b_lo[r][4 * kq] = *(const ushort4*)&Wl[(size_t)r * K + kt + 4 * kq];
        }
        __syncthreads();
        short8 af_h[4], af_l[4];
#pragma unroll
        for (int i = 0; i < 4; i++) {
            int row = 64 * wr + 16 * i + cl;
            af_h[i] = *(const short8*)&a_hi[row][quad * 8];
            if (haslo) af_l[i] = *(const short8*)&a_lo[row][quad * 8];
        }
#pragma unroll
        for (int j = 0; j < 4; j++) {
            int col = 64 * wc + 16 * j + cl;
            short8 bf_h = *(const short8*)&b_hi[col][quad * 8];
            short8 bf_l = *(const short8*)&b_lo[col][quad * 8];
#pragma unroll
            for (int i = 0; i < 4; i++) {
                acc[i][j] = __builtin_amdgcn_mfma_f32_16x16x32_bf16(af_h[i], bf_h, acc[i][j], 0, 0, 0);
                acc[i][j] = __builtin_amdgcn_mfma_f32_16x16x32_bf16(af_h[i], bf_l, acc[i][j], 0, 0, 0);
                if (haslo)
                    acc[i][j] = __builtin_amdgcn_mfma_f32_16x16x32_bf16(af_l[i], bf_h, acc[i][j], 0, 0, 0);
            }
        }
        __syncthreads();
    }
    const int f32out = FINAL ? flags[0] : 1;
#pragma unroll
    for (int j = 0; j < 4; j++) {
        int col = 64 * wc + 16 * j + cl;
        float bv = bias[col];
#pragma unroll
        for (int i = 0; i < 4; i++) {
            int rbase = br0 + 64 * wr + 16 * i + quad * 4;
#pragma unroll
            for (int rg = 0; rg < 4; rg++) {
                float v = acc[i][j][rg] + bv;
                size_t idx = (size_t)(rbase + rg) * D_ + col;
                if (FINAL) {
                    if (f32out) ((float*)dout)[idx] = v;
                    else        ((bf16*)dout)[idx] = __float2bfloat16(v);
                } else {
                    (cseg ? c_nxt : l_nxt)[idx] = v;
                }
            }
        }
    }
}

extern "C" void kernel_launch(void* const* d_in, const int* in_sizes, int n_in,
                              void* d_out, int out_size, void* d_ws, size_t ws_size,
                              hipStream_t stream) {
    const int* li_raw = (const int*)d_in[0];
    const int* ci_raw = (const int*)d_in[1];

    // ---- workspace layout ----
    float* ws = (float*)d_ws;
    float* lbuf0 = ws;                               // L*D
    float* lbuf1 = lbuf0 + (size_t)L_ * D_;          // L*D
    float* l2lb  = lbuf1 + (size_t)L_ * D_;          // L*D  (bf16 l2l messages)
    float* msgLf = l2lb + (size_t)L_ * D_;           // L*D  (bf16 l2c messages)
    float* cbuf0 = msgLf + (size_t)L_ * D_;          // C*D
    float* cbuf1 = cbuf0 + (size_t)C_ * D_;          // C*D
    float* msgCf = cbuf1 + (size_t)C_ * D_;          // C*D  (bf16 c2l messages)
    float* invsq_l = msgCf + (size_t)C_ * D_;        // L
    float* invsq_c = invsq_l + L_;                   // C
    float* bb    = invsq_c + C_;                     // 1024 bias floats
    unsigned short* wt_hi = (unsigned short*)(bb + 1024);   // 180224 ushorts
    unsigned short* wt_lo = wt_hi + 180224;                 // 180224 ushorts
    int*   li    = (int*)(wt_lo + 180224);           // E
    int*   ci    = li + E_;                          // E
    int*   l_other = ci + E_;                        // E
    int*   c_other = l_other + E_;                   // E
    int*   ldegi = c_other + E_;                     // L
    int*   cdegi = ldegi + L_;                       // C
    int*   lptr  = cdegi + C_;                       // L
    int*   cptr  = lptr + L_;                        // C
    int*   lcur  = cptr + C_;                        // L
    int*   ccur  = lcur + L_;                        // C
    int*   bsumL = ccur + C_;                        // 256
    int*   bsumC = bsumL + 256;                      // 128
    int*   flags = bsumC + 128;                      // 2

    unsigned short* msgL = (unsigned short*)msgLf;
    unsigned short* msgC = (unsigned short*)msgCf;

    // --- dtype detection (device-side, graph-safe) ---
    hipMemsetAsync(flags, 0, 2 * sizeof(int), stream);
    detect_k<<<16, 512, 0, stream>>>((const unsigned short*)d_in[4], li_raw, flags);

    // --- idx fix + degrees (one launch) ---
    hipMemsetAsync(ldegi, 0, (size_t)(L_ + C_) * sizeof(int), stream);
    fixdeg_k<<<2 * E_ / 256, 256, 0, stream>>>(li_raw, ci_raw, li, ci, ldegi, cdegi, flags);

    // --- weight split + bias conversion (one launch) ---
    cvtwb_k<<<708, 256, 0, stream>>>(d_in[4], d_in[6], d_in[8], d_in[10], d_in[12],
                                     d_in[14], d_in[16], d_in[18],
                                     d_in[5], d_in[7], d_in[9], d_in[11], d_in[13],
                                     d_in[15], d_in[17], d_in[19], wt_hi, wt_lo, bb, flags);

    // --- CSR build ---
    scan1b_k<<<384, 256, 0, stream>>>(ldegi, cdegi, lptr, cptr, bsumL, bsumC);
    scan2b_k<<<2, 256, 0, stream>>>(bsumL, bsumC);
    scan3b_k<<<384, 256, 0, stream>>>(lptr, cptr, bsumL, bsumC, lcur, ccur,
                                      ldegi, cdegi, invsq_l, invsq_c);
    place_k<<<E_ / 256, 256, 0, stream>>>(li, ci, lcur, ccur, l_other, c_other);

    // --- broadcast-init embeddings (float4) ---
    init2_k<<<(L_ + C_) * 32 / 256, 256, 0, stream>>>(d_in[2], d_in[3], lbuf0, cbuf0, flags);

    float* l_cur = lbuf0; float* l_nxt = lbuf1;
    float* c_cur = cbuf0; float* c_nxt = cbuf1;

    const int nL = L_ / 128, nC = C_ / 128;
    for (int it = 0; it < 3; it++) {
        mlp3_k<<<2 * nL + nC, 256, 0, stream>>>(
            l_cur, c_cur, wt_hi, wt_lo, bb, invsq_l, invsq_c,
            (bf16*)msgL, (bf16*)msgC, (bf16*)l2lb, nL, nC);
        update_k<0><<<768, 256, 0, stream>>>(
            l_cur, c_cur, msgL, msgC, (const bf16*)l2lb,
            lptr, ldegi, l_other, invsq_l, cptr, cdegi, c_other, invsq_c,
            wt_hi, wt_lo, bb, c_nxt, l_nxt, nullptr, flags);
        float* tmp = l_cur; l_cur = l_nxt; l_nxt = tmp;
        tmp = c_cur; c_cur = c_nxt; c_nxt = tmp;
    }
    // --- final iteration: c-update dead -> skip l2c MLP and c-update;
    //     l-update gathers msgC directly and fuses the output conversion ---
    mlp3_k<<<nC + nL, 256, 0, stream>>>(
        l_cur, c_cur, wt_hi, wt_lo, bb, invsq_l, invsq_c,
        (bf16*)msgL, (bf16*)msgC, (bf16*)l2lb, 0, nC);
    update_k<1><<<512, 256, 0, stream>>>(
        l_cur, c_cur, msgL, msgC, (const bf16*)l2lb,
        lptr, ldegi, l_other, invsq_l, cptr, cdegi, c_other, invsq_c,
        wt_hi, wt_lo, bb, nullptr, nullptr, d_out, flags);
}

// Round 8
// 675.866 us; speedup vs baseline: 1.6945x; 1.6945x over previous
//
#include <hip/hip_runtime.h>
#include <hip/hip_bf16.h>

#define D_ 128
#define L_ 65536
#define C_ 32768
#define E_ 262144

typedef __hip_bfloat16 bf16;
typedef __attribute__((ext_vector_type(8))) short short8;
typedef __attribute__((ext_vector_type(4))) float f32x4;

// flags[0] = 1 if float inputs are fp32 (else bf16); flags[1] = 1 if edge idx int32 (else int64)
__global__ void detect_k(const unsigned short* __restrict__ wmem,
                         const int* __restrict__ li, int* __restrict__ flags) {
    int t = blockIdx.x * 512 + threadIdx.x;
    if (t < 8192) {
        unsigned short h = wmem[2 * t];
        float v = __bfloat162float(*(const bf16*)&h);
        if (!(fabsf(v) < 0.5f)) atomicOr(&flags[0], 1);
    }
    if (t < 2048) {
        if (li[2 * t + 1] != 0) atomicOr(&flags[1], 1);
    }
}

__device__ __forceinline__ void split2(float v, unsigned short& h, unsigned short& l) {
    bf16 bh = __float2bfloat16(v);
    float fh = __bfloat162float(bh);
    bf16 bl = __float2bfloat16(v - fh);
    h = *(unsigned short*)&bh;
    l = *(unsigned short*)&bl;
}

__device__ __forceinline__ float ldf(const void* s, int i, int isf32) {
    return isf32 ? ((const float*)s)[i] : __bfloat162float(((const bf16*)s)[i]);
}

// index fix (int32/int64, clamp) + degree count, both sides in one launch
__global__ void fixdeg_k(const int* __restrict__ ls, const int* __restrict__ cs,
                         int* __restrict__ ld_idx, int* __restrict__ cd_idx,
                         int* __restrict__ ldeg, int* __restrict__ cdeg,
                         const int* __restrict__ flags) {
    int i = blockIdx.x * 256 + threadIdx.x;
    int is32 = flags[1];
    if (i < E_) {
        int v = is32 ? ls[i] : ls[2 * i];
        v = min(max(v, 0), L_ - 1);
        ld_idx[i] = v;
        atomicAdd(&ldeg[v], 1);
    } else {
        int j = i - E_;
        int v = is32 ? cs[j] : cs[2 * j];
        v = min(max(v, 0), C_ - 1);
        cd_idx[j] = v;
        atomicAdd(&cdeg[v], 1);
    }
}

// weights: W[k][n] -> transposed bf16 hi/lo [n][k] packed pool; tail: biases -> fp32
__global__ void cvtwb_k(const void* s0, const void* s1, const void* s2, const void* s3,
                        const void* s4, const void* s5, const void* s6, const void* s7,
                        const void* t0, const void* t1, const void* t2, const void* t3,
                        const void* t4, const void* t5, const void* t6, const void* t7,
                        unsigned short* __restrict__ hi, unsigned short* __restrict__ lo,
                        float* __restrict__ bb, const int* __restrict__ flags) {
    int i = blockIdx.x * 256 + threadIdx.x;  // 181248 total
    int isf = flags[0];
    if (i >= 180224) {
        int j = i - 180224;  // 0..1023
        const void* src;
        switch (j >> 7) {
            case 0: src = t0; break; case 1: src = t1; break;
            case 2: src = t2; break; case 3: src = t3; break;
            case 4: src = t4; break; case 5: src = t5; break;
            case 6: src = t6; break; default: src = t7; break;
        }
        bb[j] = ldf(src, j & 127, isf);
        return;
    }
    const void* src; int K, base;
    if      (i <  16384) { src = s0; K = 128; base = 0; }
    else if (i <  32768) { src = s1; K = 128; base = 16384; }
    else if (i <  49152) { src = s2; K = 128; base = 32768; }
    else if (i <  65536) { src = s3; K = 128; base = 49152; }
    else if (i <  81920) { src = s4; K = 128; base = 65536; }
    else if (i <  98304) { src = s5; K = 128; base = 81920; }
    else if (i < 131072) { src = s6; K = 256; base = 98304; }
    else                 { src = s7; K = 384; base = 131072; }
    int e = i - base;
    int k = e >> 7, n = e & 127;
    float v = ldf(src, e, isf);
    unsigned short h, l;
    split2(v, h, l);
    hi[base + n * K + k] = h;
    lo[base + n * K + k] = l;
}

// broadcast-init embeddings, float4 stores
__global__ void init2_k(const void* __restrict__ lv, const void* __restrict__ cv,
                        float* __restrict__ lemb, float* __restrict__ cemb,
                        const int* __restrict__ flags) {
    int i4 = blockIdx.x * 256 + threadIdx.x;  // float4 id, total (L+C)*32
    int isf = flags[0];
    const void* src; float* dst; int o;
    if (i4 < L_ * 32) { src = lv; dst = lemb; o = i4; }
    else              { src = cv; dst = cemb; o = i4 - L_ * 32; }
    int j = (o & 31) * 4;
    float4 v;
    v.x = ldf(src, j + 0, isf);
    v.y = ldf(src, j + 1, isf);
    v.z = ldf(src, j + 2, isf);
    v.w = ldf(src, j + 3, isf);
    ((float4*)dst)[o] = v;
}

// --- two-level exclusive scans, both sides fused ---
__global__ void scan1b_k(const int* __restrict__ ldeg, const int* __restrict__ cdeg,
                         int* __restrict__ lout, int* __restrict__ cout,
                         int* __restrict__ bsumL, int* __restrict__ bsumC) {
    __shared__ int s[256];
    const int* in; int* out; int* bs; int tile;
    if (blockIdx.x < 256) { in = ldeg; out = lout; bs = bsumL; tile = blockIdx.x; }
    else                  { in = cdeg; out = cout; bs = bsumC; tile = blockIdx.x - 256; }
    int i = tile * 256 + threadIdx.x;
    int v = in[i];
    s[threadIdx.x] = v;
    __syncthreads();
#pragma unroll
    for (int off = 1; off < 256; off <<= 1) {
        int t = (threadIdx.x >= off) ? s[threadIdx.x - off] : 0;
        __syncthreads();
        s[threadIdx.x] += t;
        __syncthreads();
    }
    out[i] = s[threadIdx.x] - v;
    if (threadIdx.x == 255) bs[tile] = s[255];
}

__global__ void scan2b_k(int* __restrict__ bL, int* __restrict__ bC) {
    __shared__ int s[256];
    int* b = blockIdx.x ? bC : bL;
    int nb = blockIdx.x ? 128 : 256;
    int v = (threadIdx.x < nb) ? b[threadIdx.x] : 0;
    s[threadIdx.x] = v;
    __syncthreads();
#pragma unroll
    for (int off = 1; off < 256; off <<= 1) {
        int t = (threadIdx.x >= off) ? s[threadIdx.x - off] : 0;
        __syncthreads();
        s[threadIdx.x] += t;
        __syncthreads();
    }
    if (threadIdx.x < nb) b[threadIdx.x] = s[threadIdx.x] - v;
}

// add block sums, init place cursors, compute invsq = deg ? 1/sqrt(deg) : 0
__global__ void scan3b_k(int* __restrict__ lptr, int* __restrict__ cptr,
                         const int* __restrict__ bsumL, const int* __restrict__ bsumC,
                         int* __restrict__ lcur, int* __restrict__ ccur,
                         const int* __restrict__ ldeg, const int* __restrict__ cdeg,
                         float* __restrict__ invsq_l, float* __restrict__ invsq_c) {
    int b = blockIdx.x, t = threadIdx.x;
    if (b < 256) {
        int i = b * 256 + t;
        int v = lptr[i] + bsumL[b];
        lptr[i] = v; lcur[i] = v;
        int d = ldeg[i];
        invsq_l[i] = d ? rsqrtf((float)d) : 0.0f;
    } else {
        int i = (b - 256) * 256 + t;
        int v = cptr[i] + bsumC[b - 256];
        cptr[i] = v; ccur[i] = v;
        int d = cdeg[i];
        invsq_c[i] = d ? rsqrtf((float)d) : 0.0f;
    }
}

// CSR placement (other endpoint only; norm is separable)
__global__ void place_k(const int* __restrict__ li, const int* __restrict__ ci,
                        int* __restrict__ lcur, int* __restrict__ ccur,
                        int* __restrict__ l_other, int* __restrict__ c_other) {
    int e = blockIdx.x * 256 + threadIdx.x;
    if (e >= E_) return;
    int l = li[e], c = ci[e];
    int p = atomicAdd(&ccur[c], 1);
    c_other[p] = l;
    int q = atomicAdd(&lcur[l], 1);
    l_other[q] = c;
}

// Fused pull-aggregation, both directions. Messages are bf16 (row = 64 dwords);
// each lane loads one dword (2 bf16), accumulates fp32, dest invsq applied at end.
// CHANGE vs r0: TWO nodes per wave (adjacent CSR ranges), interleaved 4-deep
// unrolls -> 2x independent loads in flight per wave (latency-bound scatter).
// Per-node fp32 sum order is IDENTICAL to r0 (same a0/a1 pairing, same tail).
// Requires nC and total node count even (C=32768, L=65536: both even).
__global__ __launch_bounds__(256) void gather2_k(
    const int* __restrict__ cptr, const int* __restrict__ cdeg, const int* __restrict__ c_other,
    const unsigned int* __restrict__ lmsg, const float* __restrict__ invsq_c, float* __restrict__ caggr,
    const int* __restrict__ lptr, const int* __restrict__ ldeg, const int* __restrict__ l_other,
    const unsigned int* __restrict__ cmsg, const float* __restrict__ invsq_l, float* __restrict__ laggr,
    int nC) {
    int wid = (blockIdx.x * 256 + threadIdx.x) >> 6;
    int lane = threadIdx.x & 63;
    int n0 = 2 * wid;                       // pair (n0, n0+1): same side since nC even
    bool cside = n0 < nC;
    int j0 = cside ? n0 : n0 - nC;
    int j1 = j0 + 1;
    const int* ptr = cside ? cptr : lptr;
    const int* dg  = cside ? cdeg : ldeg;
    const int* oth = cside ? c_other : l_other;
    const unsigned int* msg = cside ? lmsg : cmsg;
    const float* invsq = cside ? invsq_c : invsq_l;
    float* out = cside ? caggr : laggr;
    float sc0 = invsq[j0], sc1 = invsq[j1];
    int s0 = ptr[j0], c0 = dg[j0];
    int s1 = ptr[j1], c1 = dg[j1];
    float2 p0 = {0.f, 0.f}, p1 = {0.f, 0.f};   // node0 accumulators (r0's a0/a1)
    float2 q0 = {0.f, 0.f}, q1 = {0.f, 0.f};   // node1 accumulators
    int k0 = 0, k1 = 0;
    // interleaved main loop: both nodes advance 4 edges/iter (8 loads in flight)
    for (; k0 + 4 <= c0 && k1 + 4 <= c1; k0 += 4, k1 += 4) {
        int o00 = oth[s0 + k0], o01 = oth[s0 + k0 + 1], o02 = oth[s0 + k0 + 2], o03 = oth[s0 + k0 + 3];
        int o10 = oth[s1 + k1], o11 = oth[s1 + k1 + 1], o12 = oth[s1 + k1 + 2], o13 = oth[s1 + k1 + 3];
        unsigned int u00 = msg[(size_t)o00 * 64 + lane];
        unsigned int u01 = msg[(size_t)o01 * 64 + lane];
        unsigned int u02 = msg[(size_t)o02 * 64 + lane];
        unsigned int u03 = msg[(size_t)o03 * 64 + lane];
        unsigned int u10 = msg[(size_t)o10 * 64 + lane];
        unsigned int u11 = msg[(size_t)o11 * 64 + lane];
        unsigned int u12 = msg[(size_t)o12 * 64 + lane];
        unsigned int u13 = msg[(size_t)o13 * 64 + lane];
        p0.x += __uint_as_float(u00 << 16) + __uint_as_float(u02 << 16);
        p0.y += __uint_as_float(u00 & 0xffff0000u) + __uint_as_float(u02 & 0xffff0000u);
        p1.x += __uint_as_float(u01 << 16) + __uint_as_float(u03 << 16);
        p1.y += __uint_as_float(u01 & 0xffff0000u) + __uint_as_float(u03 & 0xffff0000u);
        q0.x += __uint_as_float(u10 << 16) + __uint_as_float(u12 << 16);
        q0.y += __uint_as_float(u10 & 0xffff0000u) + __uint_as_float(u12 & 0xffff0000u);
        q1.x += __uint_as_float(u11 << 16) + __uint_as_float(u13 << 16);
        q1.y += __uint_as_float(u11 & 0xffff0000u) + __uint_as_float(u13 & 0xffff0000u);
    }
    // node0 remaining 4-blocks
    for (; k0 + 4 <= c0; k0 += 4) {
        int o0 = oth[s0 + k0], o1 = oth[s0 + k0 + 1], o2 = oth[s0 + k0 + 2], o3 = oth[s0 + k0 + 3];
        unsigned int u0 = msg[(size_t)o0 * 64 + lane];
        unsigned int u1 = msg[(size_t)o1 * 64 + lane];
        unsigned int u2 = msg[(size_t)o2 * 64 + lane];
        unsigned int u3 = msg[(size_t)o3 * 64 + lane];
        p0.x += __uint_as_float(u0 << 16) + __uint_as_float(u2 << 16);
        p0.y += __uint_as_float(u0 & 0xffff0000u) + __uint_as_float(u2 & 0xffff0000u);
        p1.x += __uint_as_float(u1 << 16) + __uint_as_float(u3 << 16);
        p1.y += __uint_as_float(u1 & 0xffff0000u) + __uint_as_float(u3 & 0xffff0000u);
    }
    // node1 remaining 4-blocks
    for (; k1 + 4 <= c1; k1 += 4) {
        int o0 = oth[s1 + k1], o1 = oth[s1 + k1 + 1], o2 = oth[s1 + k1 + 2], o3 = oth[s1 + k1 + 3];
        unsigned int u0 = msg[(size_t)o0 * 64 + lane];
        unsigned int u1 = msg[(size_t)o1 * 64 + lane];
        unsigned int u2 = msg[(size_t)o2 * 64 + lane];
        unsigned int u3 = msg[(size_t)o3 * 64 + lane];
        q0.x += __uint_as_float(u0 << 16) + __uint_as_float(u2 << 16);
        q0.y += __uint_as_float(u0 & 0xffff0000u) + __uint_as_float(u2 & 0xffff0000u);
        q1.x += __uint_as_float(u1 << 16) + __uint_as_float(u3 << 16);
        q1.y += __uint_as_float(u1 & 0xffff0000u) + __uint_as_float(u3 & 0xffff0000u);
    }
    // scalar tails (same order as r0: singles accumulate into the first pair)
    for (; k0 < c0; k0++) {
        int o = oth[s0 + k0];
        unsigned int u = msg[(size_t)o * 64 + lane];
        p0.x += __uint_as_float(u << 16);
        p0.y += __uint_as_float(u & 0xffff0000u);
    }
    for (; k1 < c1; k1++) {
        int o = oth[s1 + k1];
        unsigned int u = msg[(size_t)o * 64 + lane];
        q0.x += __uint_as_float(u << 16);
        q0.y += __uint_as_float(u & 0xffff0000u);
    }
    float2 r0v, r1v;
    r0v.x = (p0.x + p1.x) * sc0;
    r0v.y = (p0.y + p1.y) * sc0;
    r1v.x = (q0.x + q1.x) * sc1;
    r1v.y = (q0.y + q1.y) * sc1;
    *(float2*)&out[(size_t)j0 * D_ + 2 * lane] = r0v;
    *(float2*)&out[(size_t)j1 * D_ + 2 * lane] = r1v;
}

// ---------- fused 2-layer MLPs, all three in one launch; 128-row tiles ----------
// blocks [0,nL): l2c on l_cur -> l_msg (scaled by invsq_l)
// blocks [nL,nL+nC): c2l on c_cur -> c_msg (scaled by invsq_c)
// blocks [nL+nC,...): l2l on l_cur with pair-SWAP -> l2lb (unscaled)
// Outputs stored as bf16 (consumed by gather / l-update A2).
// (EXACT round-0 structure -- best measured: 57.4 us/dispatch.)
__global__ __launch_bounds__(256, 2) void mlp3_k(
    const float* __restrict__ l_cur, const float* __restrict__ c_cur,
    const unsigned short* __restrict__ wt_hi, const unsigned short* __restrict__ wt_lo,
    const float* __restrict__ bb,
    const float* __restrict__ invsq_l, const float* __restrict__ invsq_c,
    bf16* __restrict__ l_msg, bf16* __restrict__ c_msg, bf16* __restrict__ l2lb,
    int nL, int nC) {
    __shared__ char smem[66048];
    unsigned short (*a_hi)[40] = (unsigned short(*)[40])(smem);
    unsigned short (*a_lo)[40] = (unsigned short(*)[40])(smem + 10240);
    unsigned short (*b_hi)[40] = (unsigned short(*)[40])(smem + 20480);
    unsigned short (*b_lo)[40] = (unsigned short(*)[40])(smem + 30720);
    unsigned short* h_hi = (unsigned short*)(smem);          // phase 2 aliases tiles
    unsigned short* h_lo = (unsigned short*)(smem + 32768);
    float* scv = (float*)(smem + 65536);                     // 128 floats, non-aliased

    int b = blockIdx.x, seg, tile;
    if (b < nL)           { seg = 0; tile = b; }
    else if (b < nL + nC) { seg = 1; tile = b - nL; }
    else                  { seg = 2; tile = b - nL - nC; }
    const float* A = (seg == 1) ? c_cur : l_cur;
    bf16* outp = (seg == 0) ? l_msg : (seg == 1) ? c_msg : l2lb;
    const float* invsq = (seg == 0) ? invsq_l : (seg == 1) ? invsq_c : nullptr;
    const unsigned short* W1h = wt_hi + seg * 32768;
    const unsigned short* W1l = wt_lo + seg * 32768;
    const unsigned short* W2h = W1h + 16384;
    const unsigned short* W2l = W1l + 16384;
    const float* b1v = bb + seg * 256;
    const float* b2v = b1v + 128;
    const int swap = (seg == 2);

    const int t = threadIdx.x;
    const int br0 = tile * 128;
    const int w = t >> 6, lane = t & 63;
    const int wr = w >> 1, wc = w & 1;
    const int quad = lane >> 4, cl = lane & 15;

    if (t < 128) scv[t] = invsq ? invsq[br0 + t] : 1.0f;

    f32x4 acc[4][4];
#pragma unroll
    for (int i = 0; i < 4; i++)
#pragma unroll
        for (int j = 0; j < 4; j++) acc[i][j] = (f32x4){0.f, 0.f, 0.f, 0.f};

    // ---- phase 1: h = A @ W1 ----
    for (int kt = 0; kt < 128; kt += 32) {
#pragma unroll
        for (int i = 0; i < 4; i++) {
            int f = t + 256 * i;
            int r = f >> 3, kq = f & 7;
            int gr = br0 + r;
            if (swap) gr ^= 1;
            const float4 v = *(const float4*)&A[(size_t)gr * D_ + kt + 4 * kq];
            unsigned short h0, l0, h1, l1, h2, l2, h3, l3;
            split2(v.x, h0, l0); split2(v.y, h1, l1);
            split2(v.z, h2, l2); split2(v.w, h3, l3);
            *(ushort4*)&a_hi[r][4 * kq] = make_ushort4(h0, h1, h2, h3);
            *(ushort4*)&a_lo[r][4 * kq] = make_ushort4(l0, l1, l2, l3);
            *(ushort4*)&b_hi[r][4 * kq] = *(const ushort4*)&W1h[(size_t)r * 128 + kt + 4 * kq];
            *(ushort4*)&b_lo[r][4 * kq] = *(const ushort4*)&W1l[(size_t)r * 128 + kt + 4 * kq];
        }
        __syncthreads();
        short8 af_h[4], af_l[4];
#pragma unroll
        for (int i = 0; i < 4; i++) {
            int row = 64 * wr + 16 * i + cl;
            af_h[i] = *(const short8*)&a_hi[row][quad * 8];
            af_l[i] = *(const short8*)&a_lo[row][quad * 8];
        }
#pragma unroll
        for (int j = 0; j < 4; j++) {
            int col = 64 * wc + 16 * j + cl;
            short8 bf_h = *(const short8*)&b_hi[col][quad * 8];
            short8 bf_l = *(const short8*)&b_lo[col][quad * 8];
#pragma unroll
            for (int i = 0; i < 4; i++) {
                acc[i][j] = __builtin_amdgcn_mfma_f32_16x16x32_bf16(af_h[i], bf_h, acc[i][j], 0, 0, 0);
                acc[i][j] = __builtin_amdgcn_mfma_f32_16x16x32_bf16(af_h[i], bf_l, acc[i][j], 0, 0, 0);
                acc[i][j] = __builtin_amdgcn_mfma_f32_16x16x32_bf16(af_l[i], bf_h, acc[i][j], 0, 0, 0);
            }
        }
        __syncthreads();
    }
    // h epilogue: bias + relu + split -> swizzled LDS. C/D: col=cl, row=quad*4+reg.
#pragma unroll
    for (int j = 0; j < 4; j++) {
        int col = 64 * wc + 16 * j + cl;
        float bv = b1v[col];
        int g = col >> 3, go = col & 7;
#pragma unroll
        for (int i = 0; i < 4; i++) {
            int rloc = 64 * wr + 16 * i + quad * 4;
#pragma unroll
            for (int rg = 0; rg < 4; rg++) {
                float v = fmaxf(acc[i][j][rg] + bv, 0.0f);
                unsigned short hh, ll;
                split2(v, hh, ll);
                int r = rloc + rg;
                int off = r * 128 + ((g ^ (r & 15)) << 3) + go;
                h_hi[off] = hh;
                h_lo[off] = ll;
            }
        }
    }
    __syncthreads();
    // ---- phase 2: out = (h @ W2 + b2) * scv -> bf16 ----
#pragma unroll
    for (int i = 0; i < 4; i++)
#pragma unroll
        for (int j = 0; j < 4; j++) acc[i][j] = (f32x4){0.f, 0.f, 0.f, 0.f};

    for (int kt = 0; kt < 128; kt += 32) {
        short8 af_h[4], af_l[4];
        int gbase = (kt >> 3) + quad;
#pragma unroll
        for (int i = 0; i < 4; i++) {
            int r = 64 * wr + 16 * i + cl;
            int off = r * 128 + ((gbase ^ cl) << 3);
            af_h[i] = *(const short8*)&h_hi[off];
            af_l[i] = *(const short8*)&h_lo[off];
        }
#pragma unroll
        for (int j = 0; j < 4; j++) {
            int col = 64 * wc + 16 * j + cl;
            const short8 bf_h = *(const short8*)&W2h[(size_t)col * 128 + kt + quad * 8];
            const short8 bf_l = *(const short8*)&W2l[(size_t)col * 128 + kt + quad * 8];
#pragma unroll
            for (int i = 0; i < 4; i++) {
                acc[i][j] = __builtin_amdgcn_mfma_f32_16x16x32_bf16(af_h[i], bf_h, acc[i][j], 0, 0, 0);
                acc[i][j] = __builtin_amdgcn_mfma_f32_16x16x32_bf16(af_h[i], bf_l, acc[i][j], 0, 0, 0);
                acc[i][j] = __builtin_amdgcn_mfma_f32_16x16x32_bf16(af_l[i], bf_h, acc[i][j], 0, 0, 0);
            }
        }
    }
#pragma unroll
    for (int j = 0; j < 4; j++) {
        int col = 64 * wc + 16 * j + cl;
        float bv = b2v[col];
#pragma unroll
        for (int i = 0; i < 4; i++) {
            int rloc = 64 * wr + 16 * i + quad * 4;
#pragma unroll
            for (int rg = 0; rg < 4; rg++)
                outp[(size_t)(br0 + rloc + rg) * D_ + col] =
                    __float2bfloat16((acc[i][j][rg] + bv) * scv[rloc + rg]);
        }
    }
}

// ---------- fused update GEMMs; 128-row tiles (EXACT round-0 structure) ----------
// FINAL=0: blocks [0,256) c-update K=256 -> c_nxt; [256,768) l-update K=384 -> l_nxt.
// FINAL=1: all blocks l-update K=384 -> d_out (fp32 or bf16 per flags[0]).
// A2 (l2l messages) is bf16 -> a_lo==0 for kt>=256: skip the Al*Bh MFMA there.
template <int FINAL>
__global__ __launch_bounds__(256, 2) void update_k(
    const float* __restrict__ l_cur, const float* __restrict__ c_cur,
    const float* __restrict__ laggr, const float* __restrict__ caggr,
    const bf16* __restrict__ l2lb,
    const unsigned short* __restrict__ wt_hi, const unsigned short* __restrict__ wt_lo,
    const float* __restrict__ bb,
    float* __restrict__ c_nxt, float* __restrict__ l_nxt,
    void* __restrict__ dout, const int* __restrict__ flags) {
    __shared__ unsigned short a_hi[128][40], a_lo[128][40];
    __shared__ unsigned short b_hi[128][40], b_lo[128][40];
    const int t = threadIdx.x;
    int b = blockIdx.x;
    const bool cseg = (!FINAL) && (b < 256);
    const int tile = (FINAL || cseg) ? b : b - 256;
    const int K = cseg ? 256 : 384;
    const float* A0 = cseg ? c_cur : l_cur;
    const float* A1 = cseg ? caggr : laggr;
    const unsigned short* Wh = wt_hi + (cseg ? 98304 : 131072);
    const unsigned short* Wl = wt_lo + (cseg ? 98304 : 131072);
    const float* bias = bb + (cseg ? 768 : 896);
    const int br0 = tile * 128;
    const int w = t >> 6, lane = t & 63;
    const int wr = w >> 1, wc = w & 1;
    const int quad = lane >> 4, cl = lane & 15;

    f32x4 acc[4][4];
#pragma unroll
    for (int i = 0; i < 4; i++)
#pragma unroll
        for (int j = 0; j < 4; j++) acc[i][j] = (f32x4){0.f, 0.f, 0.f, 0.f};

    for (int kt = 0; kt < K; kt += 32) {
        const bool haslo = (kt < 256);
        const int koff = kt & 127;
#pragma unroll
        for (int i = 0; i < 4; i++) {
            int f = t + 256 * i;
            int r = f >> 3, kq = f & 7;
            if (haslo) {
                const float* As = (kt < 128) ? A0 : A1;
                const float4 v = *(const float4*)&As[(size_t)(br0 + r) * D_ + koff + 4 * kq];
                unsigned short h0, l0, h1, l1, h2, l2, h3, l3;
                split2(v.x, h0, l0); split2(v.y, h1, l1);
                split2(v.z, h2, l2); split2(v.w, h3, l3);
                *(ushort4*)&a_hi[r][4 * kq] = make_ushort4(h0, h1, h2, h3);
                *(ushort4*)&a_lo[r][4 * kq] = make_ushort4(l0, l1, l2, l3);
            } else {
                *(ushort4*)&a_hi[r][4 * kq] =
                    *(const ushort4*)&l2lb[(size_t)(br0 + r) * D_ + koff + 4 * kq];
            }
            *(ushort4*)&b_hi[r][4 * kq] = *(const ushort4*)&Wh[(size_t)r * K + kt + 4 * kq];
            *(ushort4*)&b_lo[r][4 * kq] = *(const ushort4*)&Wl[(size_t)r * K + kt + 4 * kq];
        }
        __syncthreads();
        short8 af_h[4], af_l[4];
#pragma unroll
        for (int i = 0; i < 4; i++) {
            int row = 64 * wr + 16 * i + cl;
            af_h[i] = *(const short8*)&a_hi[row][quad * 8];
            if (haslo) af_l[i] = *(const short8*)&a_lo[row][quad * 8];
        }
#pragma unroll
        for (int j = 0; j < 4; j++) {
            int col = 64 * wc + 16 * j + cl;
            short8 bf_h = *(const short8*)&b_hi[col][quad * 8];
            short8 bf_l = *(const short8*)&b_lo[col][quad * 8];
#pragma unroll
            for (int i = 0; i < 4; i++) {
                acc[i][j] = __builtin_amdgcn_mfma_f32_16x16x32_bf16(af_h[i], bf_h, acc[i][j], 0, 0, 0);
                acc[i][j] = __builtin_amdgcn_mfma_f32_16x16x32_bf16(af_h[i], bf_l, acc[i][j], 0, 0, 0);
                if (haslo)
                    acc[i][j] = __builtin_amdgcn_mfma_f32_16x16x32_bf16(af_l[i], bf_h, acc[i][j], 0, 0, 0);
            }
        }
        __syncthreads();
    }
    const int f32out = FINAL ? flags[0] : 1;
#pragma unroll
    for (int j = 0; j < 4; j++) {
        int col = 64 * wc + 16 * j + cl;
        float bv = bias[col];
#pragma unroll
        for (int i = 0; i < 4; i++) {
            int rbase = br0 + 64 * wr + 16 * i + quad * 4;
#pragma unroll
            for (int rg = 0; rg < 4; rg++) {
                float v = acc[i][j][rg] + bv;
                size_t idx = (size_t)(rbase + rg) * D_ + col;
                if (FINAL) {
                    if (f32out) ((float*)dout)[idx] = v;
                    else        ((bf16*)dout)[idx] = __float2bfloat16(v);
                } else {
                    (cseg ? c_nxt : l_nxt)[idx] = v;
                }
            }
        }
    }
}

extern "C" void kernel_launch(void* const* d_in, const int* in_sizes, int n_in,
                              void* d_out, int out_size, void* d_ws, size_t ws_size,
                              hipStream_t stream) {
    const int* li_raw = (const int*)d_in[0];
    const int* ci_raw = (const int*)d_in[1];

    // ---- workspace layout ----
    float* ws = (float*)d_ws;
    float* lbuf0 = ws;                               // L*D
    float* lbuf1 = lbuf0 + (size_t)L_ * D_;          // L*D  (doubles as bf16 l_msg)
    float* l2lb  = lbuf1 + (size_t)L_ * D_;          // L*D  (bf16 l2l messages)
    float* laggr = l2lb + (size_t)L_ * D_;           // L*D
    float* cbuf0 = laggr + (size_t)L_ * D_;          // C*D
    float* cbuf1 = cbuf0 + (size_t)C_ * D_;          // C*D  (doubles as bf16 c_msg)
    float* caggr = cbuf1 + (size_t)C_ * D_;          // C*D
    float* invsq_l = caggr + (size_t)C_ * D_;        // L
    float* invsq_c = invsq_l + L_;                   // C
    float* bb    = invsq_c + C_;                     // 1024 bias floats
    unsigned short* wt_hi = (unsigned short*)(bb + 1024);   // 180224 ushorts
    unsigned short* wt_lo = wt_hi + 180224;                 // 180224 ushorts
    int*   li    = (int*)(wt_lo + 180224);           // E
    int*   ci    = li + E_;                          // E
    int*   l_other = ci + E_;                        // E
    int*   c_other = l_other + E_;                   // E
    int*   ldegi = c_other + E_;                     // L
    int*   cdegi = ldegi + L_;                       // C
    int*   lptr  = cdegi + C_;                       // L
    int*   cptr  = lptr + L_;                        // C
    int*   lcur  = cptr + C_;                        // L
    int*   ccur  = lcur + L_;                        // C
    int*   bsumL = ccur + C_;                        // 256
    int*   bsumC = bsumL + 256;                      // 128
    int*   flags = bsumC + 128;                      // 2

    // --- dtype detection (device-side, graph-safe) ---
    hipMemsetAsync(flags, 0, 2 * sizeof(int), stream);
    detect_k<<<16, 512, 0, stream>>>((const unsigned short*)d_in[4], li_raw, flags);

    // --- idx fix + degrees (one launch) ---
    hipMemsetAsync(ldegi, 0, (size_t)(L_ + C_) * sizeof(int), stream);
    fixdeg_k<<<2 * E_ / 256, 256, 0, stream>>>(li_raw, ci_raw, li, ci, ldegi, cdegi, flags);

    // --- weight split + bias conversion (one launch) ---
    cvtwb_k<<<708, 256, 0, stream>>>(d_in[4], d_in[6], d_in[8], d_in[10], d_in[12],
                                     d_in[14], d_in[16], d_in[18],
                                     d_in[5], d_in[7], d_in[9], d_in[11], d_in[13],
                                     d_in[15], d_in[17], d_in[19], wt_hi, wt_lo, bb, flags);

    // --- CSR build ---
    scan1b_k<<<384, 256, 0, stream>>>(ldegi, cdegi, lptr, cptr, bsumL, bsumC);
    scan2b_k<<<2, 256, 0, stream>>>(bsumL, bsumC);
    scan3b_k<<<384, 256, 0, stream>>>(lptr, cptr, bsumL, bsumC, lcur, ccur,
                                      ldegi, cdegi, invsq_l, invsq_c);
    place_k<<<E_ / 256, 256, 0, stream>>>(li, ci, lcur, ccur, l_other, c_other);

    // --- broadcast-init embeddings (float4) ---
    init2_k<<<(L_ + C_) * 32 / 256, 256, 0, stream>>>(d_in[2], d_in[3], lbuf0, cbuf0, flags);

    float* l_cur = lbuf0; float* l_nxt = lbuf1;
    float* c_cur = cbuf0; float* c_nxt = cbuf1;

    const int nL = L_ / 128, nC = C_ / 128;
    for (int it = 0; it < 3; it++) {
        mlp3_k<<<2 * nL + nC, 256, 0, stream>>>(
            l_cur, c_cur, wt_hi, wt_lo, bb, invsq_l, invsq_c,
            (bf16*)l_nxt, (bf16*)c_nxt, (bf16*)l2lb, nL, nC);
        gather2_k<<<(C_ + L_) / 8, 256, 0, stream>>>(
            cptr, cdegi, c_other, (const unsigned int*)l_nxt, invsq_c, caggr,
            lptr, ldegi, l_other, (const unsigned int*)c_nxt, invsq_l, laggr, C_);
        update_k<0><<<768, 256, 0, stream>>>(
            l_cur, c_cur, laggr, caggr, (const bf16*)l2lb, wt_hi, wt_lo, bb,
            c_nxt, l_nxt, nullptr, flags);
        float* tmp = l_cur; l_cur = l_nxt; l_nxt = tmp;
        tmp = c_cur; c_cur = c_nxt; c_nxt = tmp;
    }
    // --- final iteration: c-update dead -> skip l2c MLP, c-gather, c-update;
    //     fuse output dtype conversion into the l-update epilogue ---
    mlp3_k<<<nC + nL, 256, 0, stream>>>(
        l_cur, c_cur, wt_hi, wt_lo, bb, invsq_l, invsq_c,
        (bf16*)l_nxt, (bf16*)c_nxt, (bf16*)l2lb, 0, nC);
    gather2_k<<<L_ / 8, 256, 0, stream>>>(
        cptr, cdegi, c_other, (const unsigned int*)l_nxt, invsq_c, caggr,
        lptr, ldegi, l_other, (const unsigned int*)c_nxt, invsq_l, laggr, 0);
    update_k<1><<<512, 256, 0, stream>>>(
        l_cur, c_cur, laggr, caggr, (const bf16*)l2lb, wt_hi, wt_lo, bb,
        nullptr, nullptr, d_out, flags);
}

// Round 9
// 674.918 us; speedup vs baseline: 1.6968x; 1.0014x over previous
//
#include <hip/hip_runtime.h>
#include <hip/hip_bf16.h>

#define D_ 128
#define L_ 65536
#define C_ 32768
#define E_ 262144

typedef __hip_bfloat16 bf16;
typedef __attribute__((ext_vector_type(8))) short short8;
typedef __attribute__((ext_vector_type(4))) float f32x4;

// flags[0] = 1 if float inputs are fp32 (else bf16); flags[1] = 1 if edge idx int32 (else int64)
__global__ void detect_k(const unsigned short* __restrict__ wmem,
                         const int* __restrict__ li, int* __restrict__ flags) {
    int t = blockIdx.x * 512 + threadIdx.x;
    if (t < 8192) {
        unsigned short h = wmem[2 * t];
        float v = __bfloat162float(*(const bf16*)&h);
        if (!(fabsf(v) < 0.5f)) atomicOr(&flags[0], 1);
    }
    if (t < 2048) {
        if (li[2 * t + 1] != 0) atomicOr(&flags[1], 1);
    }
}

__device__ __forceinline__ void split2(float v, unsigned short& h, unsigned short& l) {
    bf16 bh = __float2bfloat16(v);
    float fh = __bfloat162float(bh);
    bf16 bl = __float2bfloat16(v - fh);
    h = *(unsigned short*)&bh;
    l = *(unsigned short*)&bl;
}

__device__ __forceinline__ float ldf(const void* s, int i, int isf32) {
    return isf32 ? ((const float*)s)[i] : __bfloat162float(((const bf16*)s)[i]);
}

// index fix (int32/int64, clamp) + degree count, both sides in one launch
__global__ void fixdeg_k(const int* __restrict__ ls, const int* __restrict__ cs,
                         int* __restrict__ ld_idx, int* __restrict__ cd_idx,
                         int* __restrict__ ldeg, int* __restrict__ cdeg,
                         const int* __restrict__ flags) {
    int i = blockIdx.x * 256 + threadIdx.x;
    int is32 = flags[1];
    if (i < E_) {
        int v = is32 ? ls[i] : ls[2 * i];
        v = min(max(v, 0), L_ - 1);
        ld_idx[i] = v;
        atomicAdd(&ldeg[v], 1);
    } else {
        int j = i - E_;
        int v = is32 ? cs[j] : cs[2 * j];
        v = min(max(v, 0), C_ - 1);
        cd_idx[j] = v;
        atomicAdd(&cdeg[v], 1);
    }
}

// weights: W[k][n] -> transposed bf16 hi/lo [n][k] packed pool; tail: biases -> fp32
__global__ void cvtwb_k(const void* s0, const void* s1, const void* s2, const void* s3,
                        const void* s4, const void* s5, const void* s6, const void* s7,
                        const void* t0, const void* t1, const void* t2, const void* t3,
                        const void* t4, const void* t5, const void* t6, const void* t7,
                        unsigned short* __restrict__ hi, unsigned short* __restrict__ lo,
                        float* __restrict__ bb, const int* __restrict__ flags) {
    int i = blockIdx.x * 256 + threadIdx.x;  // 181248 total
    int isf = flags[0];
    if (i >= 180224) {
        int j = i - 180224;  // 0..1023
        const void* src;
        switch (j >> 7) {
            case 0: src = t0; break; case 1: src = t1; break;
            case 2: src = t2; break; case 3: src = t3; break;
            case 4: src = t4; break; case 5: src = t5; break;
            case 6: src = t6; break; default: src = t7; break;
        }
        bb[j] = ldf(src, j & 127, isf);
        return;
    }
    const void* src; int K, base;
    if      (i <  16384) { src = s0; K = 128; base = 0; }
    else if (i <  32768) { src = s1; K = 128; base = 16384; }
    else if (i <  49152) { src = s2; K = 128; base = 32768; }
    else if (i <  65536) { src = s3; K = 128; base = 49152; }
    else if (i <  81920) { src = s4; K = 128; base = 65536; }
    else if (i <  98304) { src = s5; K = 128; base = 81920; }
    else if (i < 131072) { src = s6; K = 256; base = 98304; }
    else                 { src = s7; K = 384; base = 131072; }
    int e = i - base;
    int k = e >> 7, n = e & 127;
    float v = ldf(src, e, isf);
    unsigned short h, l;
    split2(v, h, l);
    hi[base + n * K + k] = h;
    lo[base + n * K + k] = l;
}

// broadcast-init embeddings, float4 stores
__global__ void init2_k(const void* __restrict__ lv, const void* __restrict__ cv,
                        float* __restrict__ lemb, float* __restrict__ cemb,
                        const int* __restrict__ flags) {
    int i4 = blockIdx.x * 256 + threadIdx.x;  // float4 id, total (L+C)*32
    int isf = flags[0];
    const void* src; float* dst; int o;
    if (i4 < L_ * 32) { src = lv; dst = lemb; o = i4; }
    else              { src = cv; dst = cemb; o = i4 - L_ * 32; }
    int j = (o & 31) * 4;
    float4 v;
    v.x = ldf(src, j + 0, isf);
    v.y = ldf(src, j + 1, isf);
    v.z = ldf(src, j + 2, isf);
    v.w = ldf(src, j + 3, isf);
    ((float4*)dst)[o] = v;
}

// --- two-level exclusive scans, both sides fused ---
__global__ void scan1b_k(const int* __restrict__ ldeg, const int* __restrict__ cdeg,
                         int* __restrict__ lout, int* __restrict__ cout,
                         int* __restrict__ bsumL, int* __restrict__ bsumC) {
    __shared__ int s[256];
    const int* in; int* out; int* bs; int tile;
    if (blockIdx.x < 256) { in = ldeg; out = lout; bs = bsumL; tile = blockIdx.x; }
    else                  { in = cdeg; out = cout; bs = bsumC; tile = blockIdx.x - 256; }
    int i = tile * 256 + threadIdx.x;
    int v = in[i];
    s[threadIdx.x] = v;
    __syncthreads();
#pragma unroll
    for (int off = 1; off < 256; off <<= 1) {
        int t = (threadIdx.x >= off) ? s[threadIdx.x - off] : 0;
        __syncthreads();
        s[threadIdx.x] += t;
        __syncthreads();
    }
    out[i] = s[threadIdx.x] - v;
    if (threadIdx.x == 255) bs[tile] = s[255];
}

__global__ void scan2b_k(int* __restrict__ bL, int* __restrict__ bC) {
    __shared__ int s[256];
    int* b = blockIdx.x ? bC : bL;
    int nb = blockIdx.x ? 128 : 256;
    int v = (threadIdx.x < nb) ? b[threadIdx.x] : 0;
    s[threadIdx.x] = v;
    __syncthreads();
#pragma unroll
    for (int off = 1; off < 256; off <<= 1) {
        int t = (threadIdx.x >= off) ? s[threadIdx.x - off] : 0;
        __syncthreads();
        s[threadIdx.x] += t;
        __syncthreads();
    }
    if (threadIdx.x < nb) b[threadIdx.x] = s[threadIdx.x] - v;
}

// add block sums, init place cursors, compute invsq = deg ? 1/sqrt(deg) : 0
__global__ void scan3b_k(int* __restrict__ lptr, int* __restrict__ cptr,
                         const int* __restrict__ bsumL, const int* __restrict__ bsumC,
                         int* __restrict__ lcur, int* __restrict__ ccur,
                         const int* __restrict__ ldeg, const int* __restrict__ cdeg,
                         float* __restrict__ invsq_l, float* __restrict__ invsq_c) {
    int b = blockIdx.x, t = threadIdx.x;
    if (b < 256) {
        int i = b * 256 + t;
        int v = lptr[i] + bsumL[b];
        lptr[i] = v; lcur[i] = v;
        int d = ldeg[i];
        invsq_l[i] = d ? rsqrtf((float)d) : 0.0f;
    } else {
        int i = (b - 256) * 256 + t;
        int v = cptr[i] + bsumC[b - 256];
        cptr[i] = v; ccur[i] = v;
        int d = cdeg[i];
        invsq_c[i] = d ? rsqrtf((float)d) : 0.0f;
    }
}

// CSR placement (other endpoint only; norm is separable)
__global__ void place_k(const int* __restrict__ li, const int* __restrict__ ci,
                        int* __restrict__ lcur, int* __restrict__ ccur,
                        int* __restrict__ l_other, int* __restrict__ c_other) {
    int e = blockIdx.x * 256 + threadIdx.x;
    if (e >= E_) return;
    int l = li[e], c = ci[e];
    int p = atomicAdd(&ccur[c], 1);
    c_other[p] = l;
    int q = atomicAdd(&lcur[l], 1);
    l_other[q] = c;
}

// Fused pull-aggregation, both directions. Messages are bf16 (row = 64 dwords);
// each lane loads one dword (2 bf16), accumulates fp32, dest invsq applied at end.
// CHANGE vs r8: FOUR nodes per wave, 2-deep each -> 8 loads in flight with only
// deg>=2 per node required (vs r8's deg>=4 on both of 2), so far more of the
// low-degree l-side work runs at high ILP. Graceful degradation: 4-node main ->
// pairwise -> per-node 2-deep -> 4 INDEPENDENT single leftovers (also ILP-4).
// (Sum-order differs from r8; r7 proved absmax is set by output bf16 quantization,
// not gather fp32 order.) Requires node count % 4 == 0 per side (C, L: yes).
__global__ __launch_bounds__(256) void gather2_k(
    const int* __restrict__ cptr, const int* __restrict__ cdeg, const int* __restrict__ c_other,
    const unsigned int* __restrict__ lmsg, const float* __restrict__ invsq_c, float* __restrict__ caggr,
    const int* __restrict__ lptr, const int* __restrict__ ldeg, const int* __restrict__ l_other,
    const unsigned int* __restrict__ cmsg, const float* __restrict__ invsq_l, float* __restrict__ laggr,
    int nC) {
    int wid = (blockIdx.x * 256 + threadIdx.x) >> 6;
    int lane = threadIdx.x & 63;
    int n0 = 4 * wid;                       // quad (n0..n0+3): same side since C,L %4==0
    bool cside = n0 < nC;
    int j0 = cside ? n0 : n0 - nC;
    const int* ptr = cside ? cptr : lptr;
    const int* dg  = cside ? cdeg : ldeg;
    const int* oth = cside ? c_other : l_other;
    const unsigned int* msg = cside ? lmsg : cmsg;
    const float* invsq = cside ? invsq_c : invsq_l;
    float* out = cside ? caggr : laggr;

    int s0 = ptr[j0],     c0 = dg[j0];
    int s1 = ptr[j0 + 1], c1 = dg[j0 + 1];
    int s2 = ptr[j0 + 2], c2 = dg[j0 + 2];
    int s3 = ptr[j0 + 3], c3 = dg[j0 + 3];
    float2 A0 = {0.f, 0.f}, B0 = {0.f, 0.f};
    float2 A1 = {0.f, 0.f}, B1 = {0.f, 0.f};
    float2 A2 = {0.f, 0.f}, B2 = {0.f, 0.f};
    float2 A3 = {0.f, 0.f}, B3 = {0.f, 0.f};
    int k0 = 0, k1 = 0, k2 = 0, k3 = 0;

#define GLD_(s, k) msg[(size_t)oth[(s) + (k)] * 64 + lane]
#define GACC_(a, u) { (a).x += __uint_as_float((u) << 16); \
                      (a).y += __uint_as_float((u) & 0xffff0000u); }

    // 4-node x 2-deep main loop: 8 independent loads in flight
    for (; k0 + 2 <= c0 && k1 + 2 <= c1 && k2 + 2 <= c2 && k3 + 2 <= c3;
         k0 += 2, k1 += 2, k2 += 2, k3 += 2) {
        unsigned int u00 = GLD_(s0, k0), u01 = GLD_(s0, k0 + 1);
        unsigned int u10 = GLD_(s1, k1), u11 = GLD_(s1, k1 + 1);
        unsigned int u20 = GLD_(s2, k2), u21 = GLD_(s2, k2 + 1);
        unsigned int u30 = GLD_(s3, k3), u31 = GLD_(s3, k3 + 1);
        GACC_(A0, u00); GACC_(B0, u01);
        GACC_(A1, u10); GACC_(B1, u11);
        GACC_(A2, u20); GACC_(B2, u21);
        GACC_(A3, u30); GACC_(B3, u31);
    }
    // pairwise 2-deep: (0,1) then (2,3) -> 4 loads in flight
    for (; k0 + 2 <= c0 && k1 + 2 <= c1; k0 += 2, k1 += 2) {
        unsigned int u00 = GLD_(s0, k0), u01 = GLD_(s0, k0 + 1);
        unsigned int u10 = GLD_(s1, k1), u11 = GLD_(s1, k1 + 1);
        GACC_(A0, u00); GACC_(B0, u01);
        GACC_(A1, u10); GACC_(B1, u11);
    }
    for (; k2 + 2 <= c2 && k3 + 2 <= c3; k2 += 2, k3 += 2) {
        unsigned int u20 = GLD_(s2, k2), u21 = GLD_(s2, k2 + 1);
        unsigned int u30 = GLD_(s3, k3), u31 = GLD_(s3, k3 + 1);
        GACC_(A2, u20); GACC_(B2, u21);
        GACC_(A3, u30); GACC_(B3, u31);
    }
    // per-node 2-deep remainders
    for (; k0 + 2 <= c0; k0 += 2) {
        unsigned int ua = GLD_(s0, k0), ub = GLD_(s0, k0 + 1);
        GACC_(A0, ua); GACC_(B0, ub);
    }
    for (; k1 + 2 <= c1; k1 += 2) {
        unsigned int ua = GLD_(s1, k1), ub = GLD_(s1, k1 + 1);
        GACC_(A1, ua); GACC_(B1, ub);
    }
    for (; k2 + 2 <= c2; k2 += 2) {
        unsigned int ua = GLD_(s2, k2), ub = GLD_(s2, k2 + 1);
        GACC_(A2, ua); GACC_(B2, ub);
    }
    for (; k3 + 2 <= c3; k3 += 2) {
        unsigned int ua = GLD_(s3, k3), ub = GLD_(s3, k3 + 1);
        GACC_(A3, ua); GACC_(B3, ub);
    }
    // <=1 leftover per node; the four singles are independent (ILP-4 tail)
    if (k0 < c0) { unsigned int u = GLD_(s0, k0); GACC_(A0, u); }
    if (k1 < c1) { unsigned int u = GLD_(s1, k1); GACC_(A1, u); }
    if (k2 < c2) { unsigned int u = GLD_(s2, k2); GACC_(A2, u); }
    if (k3 < c3) { unsigned int u = GLD_(s3, k3); GACC_(A3, u); }
#undef GLD_
#undef GACC_

    float sc0 = invsq[j0], sc1 = invsq[j0 + 1];
    float sc2 = invsq[j0 + 2], sc3 = invsq[j0 + 3];
    float2 r;
    r.x = (A0.x + B0.x) * sc0; r.y = (A0.y + B0.y) * sc0;
    *(float2*)&out[(size_t)j0 * D_ + 2 * lane] = r;
    r.x = (A1.x + B1.x) * sc1; r.y = (A1.y + B1.y) * sc1;
    *(float2*)&out[(size_t)(j0 + 1) * D_ + 2 * lane] = r;
    r.x = (A2.x + B2.x) * sc2; r.y = (A2.y + B2.y) * sc2;
    *(float2*)&out[(size_t)(j0 + 2) * D_ + 2 * lane] = r;
    r.x = (A3.x + B3.x) * sc3; r.y = (A3.y + B3.y) * sc3;
    *(float2*)&out[(size_t)(j0 + 3) * D_ + 2 * lane] = r;
}

// ---------- fused 2-layer MLPs, all three in one launch; 128-row tiles ----------
// blocks [0,nL): l2c on l_cur -> l_msg (scaled by invsq_l)
// blocks [nL,nL+nC): c2l on c_cur -> c_msg (scaled by invsq_c)
// blocks [nL+nC,...): l2l on l_cur with pair-SWAP -> l2lb (unscaled)
// Outputs stored as bf16 (consumed by gather / l-update A2).
// (EXACT round-0 structure -- best measured: 57.4 us/dispatch.)
__global__ __launch_bounds__(256, 2) void mlp3_k(
    const float* __restrict__ l_cur, const float* __restrict__ c_cur,
    const unsigned short* __restrict__ wt_hi, const unsigned short* __restrict__ wt_lo,
    const float* __restrict__ bb,
    const float* __restrict__ invsq_l, const float* __restrict__ invsq_c,
    bf16* __restrict__ l_msg, bf16* __restrict__ c_msg, bf16* __restrict__ l2lb,
    int nL, int nC) {
    __shared__ char smem[66048];
    unsigned short (*a_hi)[40] = (unsigned short(*)[40])(smem);
    unsigned short (*a_lo)[40] = (unsigned short(*)[40])(smem + 10240);
    unsigned short (*b_hi)[40] = (unsigned short(*)[40])(smem + 20480);
    unsigned short (*b_lo)[40] = (unsigned short(*)[40])(smem + 30720);
    unsigned short* h_hi = (unsigned short*)(smem);          // phase 2 aliases tiles
    unsigned short* h_lo = (unsigned short*)(smem + 32768);
    float* scv = (float*)(smem + 65536);                     // 128 floats, non-aliased

    int b = blockIdx.x, seg, tile;
    if (b < nL)           { seg = 0; tile = b; }
    else if (b < nL + nC) { seg = 1; tile = b - nL; }
    else                  { seg = 2; tile = b - nL - nC; }
    const float* A = (seg == 1) ? c_cur : l_cur;
    bf16* outp = (seg == 0) ? l_msg : (seg == 1) ? c_msg : l2lb;
    const float* invsq = (seg == 0) ? invsq_l : (seg == 1) ? invsq_c : nullptr;
    const unsigned short* W1h = wt_hi + seg * 32768;
    const unsigned short* W1l = wt_lo + seg * 32768;
    const unsigned short* W2h = W1h + 16384;
    const unsigned short* W2l = W1l + 16384;
    const float* b1v = bb + seg * 256;
    const float* b2v = b1v + 128;
    const int swap = (seg == 2);

    const int t = threadIdx.x;
    const int br0 = tile * 128;
    const int w = t >> 6, lane = t & 63;
    const int wr = w >> 1, wc = w & 1;
    const int quad = lane >> 4, cl = lane & 15;

    if (t < 128) scv[t] = invsq ? invsq[br0 + t] : 1.0f;

    f32x4 acc[4][4];
#pragma unroll
    for (int i = 0; i < 4; i++)
#pragma unroll
        for (int j = 0; j < 4; j++) acc[i][j] = (f32x4){0.f, 0.f, 0.f, 0.f};

    // ---- phase 1: h = A @ W1 ----
    for (int kt = 0; kt < 128; kt += 32) {
#pragma unroll
        for (int i = 0; i < 4; i++) {
            int f = t + 256 * i;
            int r = f >> 3, kq = f & 7;
            int gr = br0 + r;
            if (swap) gr ^= 1;
            const float4 v = *(const float4*)&A[(size_t)gr * D_ + kt + 4 * kq];
            unsigned short h0, l0, h1, l1, h2, l2, h3, l3;
            split2(v.x, h0, l0); split2(v.y, h1, l1);
            split2(v.z, h2, l2); split2(v.w, h3, l3);
            *(ushort4*)&a_hi[r][4 * kq] = make_ushort4(h0, h1, h2, h3);
            *(ushort4*)&a_lo[r][4 * kq] = make_ushort4(l0, l1, l2, l3);
            *(ushort4*)&b_hi[r][4 * kq] = *(const ushort4*)&W1h[(size_t)r * 128 + kt + 4 * kq];
            *(ushort4*)&b_lo[r][4 * kq] = *(const ushort4*)&W1l[(size_t)r * 128 + kt + 4 * kq];
        }
        __syncthreads();
        short8 af_h[4], af_l[4];
#pragma unroll
        for (int i = 0; i < 4; i++) {
            int row = 64 * wr + 16 * i + cl;
            af_h[i] = *(const short8*)&a_hi[row][quad * 8];
            af_l[i] = *(const short8*)&a_lo[row][quad * 8];
        }
#pragma unroll
        for (int j = 0; j < 4; j++) {
            int col = 64 * wc + 16 * j + cl;
            short8 bf_h = *(const short8*)&b_hi[col][quad * 8];
            short8 bf_l = *(const short8*)&b_lo[col][quad * 8];
#pragma unroll
            for (int i = 0; i < 4; i++) {
                acc[i][j] = __builtin_amdgcn_mfma_f32_16x16x32_bf16(af_h[i], bf_h, acc[i][j], 0, 0, 0);
                acc[i][j] = __builtin_amdgcn_mfma_f32_16x16x32_bf16(af_h[i], bf_l, acc[i][j], 0, 0, 0);
                acc[i][j] = __builtin_amdgcn_mfma_f32_16x16x32_bf16(af_l[i], bf_h, acc[i][j], 0, 0, 0);
            }
        }
        __syncthreads();
    }
    // h epilogue: bias + relu + split -> swizzled LDS. C/D: col=cl, row=quad*4+reg.
#pragma unroll
    for (int j = 0; j < 4; j++) {
        int col = 64 * wc + 16 * j + cl;
        float bv = b1v[col];
        int g = col >> 3, go = col & 7;
#pragma unroll
        for (int i = 0; i < 4; i++) {
            int rloc = 64 * wr + 16 * i + quad * 4;
#pragma unroll
            for (int rg = 0; rg < 4; rg++) {
                float v = fmaxf(acc[i][j][rg] + bv, 0.0f);
                unsigned short hh, ll;
                split2(v, hh, ll);
                int r = rloc + rg;
                int off = r * 128 + ((g ^ (r & 15)) << 3) + go;
                h_hi[off] = hh;
                h_lo[off] = ll;
            }
        }
    }
    __syncthreads();
    // ---- phase 2: out = (h @ W2 + b2) * scv -> bf16 ----
#pragma unroll
    for (int i = 0; i < 4; i++)
#pragma unroll
        for (int j = 0; j < 4; j++) acc[i][j] = (f32x4){0.f, 0.f, 0.f, 0.f};

    for (int kt = 0; kt < 128; kt += 32) {
        short8 af_h[4], af_l[4];
        int gbase = (kt >> 3) + quad;
#pragma unroll
        for (int i = 0; i < 4; i++) {
            int r = 64 * wr + 16 * i + cl;
            int off = r * 128 + ((gbase ^ cl) << 3);
            af_h[i] = *(const short8*)&h_hi[off];
            af_l[i] = *(const short8*)&h_lo[off];
        }
#pragma unroll
        for (int j = 0; j < 4; j++) {
            int col = 64 * wc + 16 * j + cl;
            const short8 bf_h = *(const short8*)&W2h[(size_t)col * 128 + kt + quad * 8];
            const short8 bf_l = *(const short8*)&W2l[(size_t)col * 128 + kt + quad * 8];
#pragma unroll
            for (int i = 0; i < 4; i++) {
                acc[i][j] = __builtin_amdgcn_mfma_f32_16x16x32_bf16(af_h[i], bf_h, acc[i][j], 0, 0, 0);
                acc[i][j] = __builtin_amdgcn_mfma_f32_16x16x32_bf16(af_h[i], bf_l, acc[i][j], 0, 0, 0);
                acc[i][j] = __builtin_amdgcn_mfma_f32_16x16x32_bf16(af_l[i], bf_h, acc[i][j], 0, 0, 0);
            }
        }
    }
#pragma unroll
    for (int j = 0; j < 4; j++) {
        int col = 64 * wc + 16 * j + cl;
        float bv = b2v[col];
#pragma unroll
        for (int i = 0; i < 4; i++) {
            int rloc = 64 * wr + 16 * i + quad * 4;
#pragma unroll
            for (int rg = 0; rg < 4; rg++)
                outp[(size_t)(br0 + rloc + rg) * D_ + col] =
                    __float2bfloat16((acc[i][j][rg] + bv) * scv[rloc + rg]);
        }
    }
}

// ---------- fused update GEMMs; 128-row tiles (EXACT round-0 structure) ----------
// FINAL=0: blocks [0,256) c-update K=256 -> c_nxt; [256,768) l-update K=384 -> l_nxt.
// FINAL=1: all blocks l-update K=384 -> d_out (fp32 or bf16 per flags[0]).
// A2 (l2l messages) is bf16 -> a_lo==0 for kt>=256: skip the Al*Bh MFMA there.
template <int FINAL>
__global__ __launch_bounds__(256, 2) void update_k(
    const float* __restrict__ l_cur, const float* __restrict__ c_cur,
    const float* __restrict__ laggr, const float* __restrict__ caggr,
    const bf16* __restrict__ l2lb,
    const unsigned short* __restrict__ wt_hi, const unsigned short* __restrict__ wt_lo,
    const float* __restrict__ bb,
    float* __restrict__ c_nxt, float* __restrict__ l_nxt,
    void* __restrict__ dout, const int* __restrict__ flags) {
    __shared__ unsigned short a_hi[128][40], a_lo[128][40];
    __shared__ unsigned short b_hi[128][40], b_lo[128][40];
    const int t = threadIdx.x;
    int b = blockIdx.x;
    const bool cseg = (!FINAL) && (b < 256);
    const int tile = (FINAL || cseg) ? b : b - 256;
    const int K = cseg ? 256 : 384;
    const float* A0 = cseg ? c_cur : l_cur;
    const float* A1 = cseg ? caggr : laggr;
    const unsigned short* Wh = wt_hi + (cseg ? 98304 : 131072);
    const unsigned short* Wl = wt_lo + (cseg ? 98304 : 131072);
    const float* bias = bb + (cseg ? 768 : 896);
    const int br0 = tile * 128;
    const int w = t >> 6, lane = t & 63;
    const int wr = w >> 1, wc = w & 1;
    const int quad = lane >> 4, cl = lane & 15;

    f32x4 acc[4][4];
#pragma unroll
    for (int i = 0; i < 4; i++)
#pragma unroll
        for (int j = 0; j < 4; j++) acc[i][j] = (f32x4){0.f, 0.f, 0.f, 0.f};

    for (int kt = 0; kt < K; kt += 32) {
        const bool haslo = (kt < 256);
        const int koff = kt & 127;
#pragma unroll
        for (int i = 0; i < 4; i++) {
            int f = t + 256 * i;
            int r = f >> 3, kq = f & 7;
            if (haslo) {
                const float* As = (kt < 128) ? A0 : A1;
                const float4 v = *(const float4*)&As[(size_t)(br0 + r) * D_ + koff + 4 * kq];
                unsigned short h0, l0, h1, l1, h2, l2, h3, l3;
                split2(v.x, h0, l0); split2(v.y, h1, l1);
                split2(v.z, h2, l2); split2(v.w, h3, l3);
                *(ushort4*)&a_hi[r][4 * kq] = make_ushort4(h0, h1, h2, h3);
                *(ushort4*)&a_lo[r][4 * kq] = make_ushort4(l0, l1, l2, l3);
            } else {
                *(ushort4*)&a_hi[r][4 * kq] =
                    *(const ushort4*)&l2lb[(size_t)(br0 + r) * D_ + koff + 4 * kq];
            }
            *(ushort4*)&b_hi[r][4 * kq] = *(const ushort4*)&Wh[(size_t)r * K + kt + 4 * kq];
            *(ushort4*)&b_lo[r][4 * kq] = *(const ushort4*)&Wl[(size_t)r * K + kt + 4 * kq];
        }
        __syncthreads();
        short8 af_h[4], af_l[4];
#pragma unroll
        for (int i = 0; i < 4; i++) {
            int row = 64 * wr + 16 * i + cl;
            af_h[i] = *(const short8*)&a_hi[row][quad * 8];
            if (haslo) af_l[i] = *(const short8*)&a_lo[row][quad * 8];
        }
#pragma unroll
        for (int j = 0; j < 4; j++) {
            int col = 64 * wc + 16 * j + cl;
            short8 bf_h = *(const short8*)&b_hi[col][quad * 8];
            short8 bf_l = *(const short8*)&b_lo[col][quad * 8];
#pragma unroll
            for (int i = 0; i < 4; i++) {
                acc[i][j] = __builtin_amdgcn_mfma_f32_16x16x32_bf16(af_h[i], bf_h, acc[i][j], 0, 0, 0);
                acc[i][j] = __builtin_amdgcn_mfma_f32_16x16x32_bf16(af_h[i], bf_l, acc[i][j], 0, 0, 0);
                if (haslo)
                    acc[i][j] = __builtin_amdgcn_mfma_f32_16x16x32_bf16(af_l[i], bf_h, acc[i][j], 0, 0, 0);
            }
        }
        __syncthreads();
    }
    const int f32out = FINAL ? flags[0] : 1;
#pragma unroll
    for (int j = 0; j < 4; j++) {
        int col = 64 * wc + 16 * j + cl;
        float bv = bias[col];
#pragma unroll
        for (int i = 0; i < 4; i++) {
            int rbase = br0 + 64 * wr + 16 * i + quad * 4;
#pragma unroll
            for (int rg = 0; rg < 4; rg++) {
                float v = acc[i][j][rg] + bv;
                size_t idx = (size_t)(rbase + rg) * D_ + col;
                if (FINAL) {
                    if (f32out) ((float*)dout)[idx] = v;
                    else        ((bf16*)dout)[idx] = __float2bfloat16(v);
                } else {
                    (cseg ? c_nxt : l_nxt)[idx] = v;
                }
            }
        }
    }
}

extern "C" void kernel_launch(void* const* d_in, const int* in_sizes, int n_in,
                              void* d_out, int out_size, void* d_ws, size_t ws_size,
                              hipStream_t stream) {
    const int* li_raw = (const int*)d_in[0];
    const int* ci_raw = (const int*)d_in[1];

    // ---- workspace layout ----
    float* ws = (float*)d_ws;
    float* lbuf0 = ws;                               // L*D
    float* lbuf1 = lbuf0 + (size_t)L_ * D_;          // L*D  (doubles as bf16 l_msg)
    float* l2lb  = lbuf1 + (size_t)L_ * D_;          // L*D  (bf16 l2l messages)
    float* laggr = l2lb + (size_t)L_ * D_;           // L*D
    float* cbuf0 = laggr + (size_t)L_ * D_;          // C*D
    float* cbuf1 = cbuf0 + (size_t)C_ * D_;          // C*D  (doubles as bf16 c_msg)
    float* caggr = cbuf1 + (size_t)C_ * D_;          // C*D
    float* invsq_l = caggr + (size_t)C_ * D_;        // L
    float* invsq_c = invsq_l + L_;                   // C
    float* bb    = invsq_c + C_;                     // 1024 bias floats
    unsigned short* wt_hi = (unsigned short*)(bb + 1024);   // 180224 ushorts
    unsigned short* wt_lo = wt_hi + 180224;                 // 180224 ushorts
    int*   li    = (int*)(wt_lo + 180224);           // E
    int*   ci    = li + E_;                          // E
    int*   l_other = ci + E_;                        // E
    int*   c_other = l_other + E_;                   // E
    int*   ldegi = c_other + E_;                     // L
    int*   cdegi = ldegi + L_;                       // C
    int*   lptr  = cdegi + C_;                       // L
    int*   cptr  = lptr + L_;                        // C
    int*   lcur  = cptr + C_;                        // L
    int*   ccur  = lcur + L_;                        // C
    int*   bsumL = ccur + C_;                        // 256
    int*   bsumC = bsumL + 256;                      // 128
    int*   flags = bsumC + 128;                      // 2

    // --- dtype detection (device-side, graph-safe) ---
    hipMemsetAsync(flags, 0, 2 * sizeof(int), stream);
    detect_k<<<16, 512, 0, stream>>>((const unsigned short*)d_in[4], li_raw, flags);

    // --- idx fix + degrees (one launch) ---
    hipMemsetAsync(ldegi, 0, (size_t)(L_ + C_) * sizeof(int), stream);
    fixdeg_k<<<2 * E_ / 256, 256, 0, stream>>>(li_raw, ci_raw, li, ci, ldegi, cdegi, flags);

    // --- weight split + bias conversion (one launch) ---
    cvtwb_k<<<708, 256, 0, stream>>>(d_in[4], d_in[6], d_in[8], d_in[10], d_in[12],
                                     d_in[14], d_in[16], d_in[18],
                                     d_in[5], d_in[7], d_in[9], d_in[11], d_in[13],
                                     d_in[15], d_in[17], d_in[19], wt_hi, wt_lo, bb, flags);

    // --- CSR build ---
    scan1b_k<<<384, 256, 0, stream>>>(ldegi, cdegi, lptr, cptr, bsumL, bsumC);
    scan2b_k<<<2, 256, 0, stream>>>(bsumL, bsumC);
    scan3b_k<<<384, 256, 0, stream>>>(lptr, cptr, bsumL, bsumC, lcur, ccur,
                                      ldegi, cdegi, invsq_l, invsq_c);
    place_k<<<E_ / 256, 256, 0, stream>>>(li, ci, lcur, ccur, l_other, c_other);

    // --- broadcast-init embeddings (float4) ---
    init2_k<<<(L_ + C_) * 32 / 256, 256, 0, stream>>>(d_in[2], d_in[3], lbuf0, cbuf0, flags);

    float* l_cur = lbuf0; float* l_nxt = lbuf1;
    float* c_cur = cbuf0; float* c_nxt = cbuf1;

    const int nL = L_ / 128, nC = C_ / 128;
    for (int it = 0; it < 3; it++) {
        mlp3_k<<<2 * nL + nC, 256, 0, stream>>>(
            l_cur, c_cur, wt_hi, wt_lo, bb, invsq_l, invsq_c,
            (bf16*)l_nxt, (bf16*)c_nxt, (bf16*)l2lb, nL, nC);
        gather2_k<<<(C_ + L_) / 16, 256, 0, stream>>>(
            cptr, cdegi, c_other, (const unsigned int*)l_nxt, invsq_c, caggr,
            lptr, ldegi, l_other, (const unsigned int*)c_nxt, invsq_l, laggr, C_);
        update_k<0><<<768, 256, 0, stream>>>(
            l_cur, c_cur, laggr, caggr, (const bf16*)l2lb, wt_hi, wt_lo, bb,
            c_nxt, l_nxt, nullptr, flags);
        float* tmp = l_cur; l_cur = l_nxt; l_nxt = tmp;
        tmp = c_cur; c_cur = c_nxt; c_nxt = tmp;
    }
    // --- final iteration: c-update dead -> skip l2c MLP, c-gather, c-update;
    //     fuse output dtype conversion into the l-update epilogue ---
    mlp3_k<<<nC + nL, 256, 0, stream>>>(
        l_cur, c_cur, wt_hi, wt_lo, bb, invsq_l, invsq_c,
        (bf16*)l_nxt, (bf16*)c_nxt, (bf16*)l2lb, 0, nC);
    gather2_k<<<L_ / 16, 256, 0, stream>>>(
        cptr, cdegi, c_other, (const unsigned int*)l_nxt, invsq_c, caggr,
        lptr, ldegi, l_other, (const unsigned int*)c_nxt, invsq_l, laggr, 0);
    update_k<1><<<512, 256, 0, stream>>>(
        l_cur, c_cur, laggr, caggr, (const bf16*)l2lb, wt_hi, wt_lo, bb,
        nullptr, nullptr, d_out, flags);
}

// Round 10
// 663.038 us; speedup vs baseline: 1.7272x; 1.0179x over previous
//
#include <hip/hip_runtime.h>
#include <hip/hip_bf16.h>

#define D_ 128
#define L_ 65536
#define C_ 32768
#define E_ 262144

typedef __hip_bfloat16 bf16;
typedef __attribute__((ext_vector_type(8))) short short8;
typedef __attribute__((ext_vector_type(4))) float f32x4;

// flags[0] = 1 if float inputs are fp32 (else bf16); flags[1] = 1 if edge idx int32 (else int64)
__global__ void detect_k(const unsigned short* __restrict__ wmem,
                         const int* __restrict__ li, int* __restrict__ flags) {
    int t = blockIdx.x * 512 + threadIdx.x;
    if (t < 8192) {
        unsigned short h = wmem[2 * t];
        float v = __bfloat162float(*(const bf16*)&h);
        if (!(fabsf(v) < 0.5f)) atomicOr(&flags[0], 1);
    }
    if (t < 2048) {
        if (li[2 * t + 1] != 0) atomicOr(&flags[1], 1);
    }
}

__device__ __forceinline__ void split2(float v, unsigned short& h, unsigned short& l) {
    bf16 bh = __float2bfloat16(v);
    float fh = __bfloat162float(bh);
    bf16 bl = __float2bfloat16(v - fh);
    h = *(unsigned short*)&bh;
    l = *(unsigned short*)&bl;
}

__device__ __forceinline__ float ldf(const void* s, int i, int isf32) {
    return isf32 ? ((const float*)s)[i] : __bfloat162float(((const bf16*)s)[i]);
}

// ---- fused preamble: fixdeg (2048 blocks) + cvtwb (708) + init2 (12288) ----
// All three are independent and gated only on detect_k's flags.
// blocks [0,2048): index fix + degree count (both sides)
// blocks [2048,2756): weight split W[k][n]->[n][k] hi/lo pool + biases
// blocks [2756,15044): broadcast-init embeddings (float4 stores)
__global__ void prep_k(const int* __restrict__ ls, const int* __restrict__ cs,
                       int* __restrict__ ld_idx, int* __restrict__ cd_idx,
                       int* __restrict__ ldeg, int* __restrict__ cdeg,
                       const void* s0, const void* s1, const void* s2, const void* s3,
                       const void* s4, const void* s5, const void* s6, const void* s7,
                       const void* t0, const void* t1, const void* t2, const void* t3,
                       const void* t4, const void* t5, const void* t6, const void* t7,
                       unsigned short* __restrict__ hi, unsigned short* __restrict__ lo,
                       float* __restrict__ bb,
                       const void* __restrict__ lv, const void* __restrict__ cv,
                       float* __restrict__ lemb, float* __restrict__ cemb,
                       const int* __restrict__ flags) {
    const int blk = blockIdx.x;
    const int isf = flags[0];
    if (blk < 2048) {
        // ---- fixdeg ----
        int i = blk * 256 + threadIdx.x;
        int is32 = flags[1];
        if (i < E_) {
            int v = is32 ? ls[i] : ls[2 * i];
            v = min(max(v, 0), L_ - 1);
            ld_idx[i] = v;
            atomicAdd(&ldeg[v], 1);
        } else {
            int j = i - E_;
            int v = is32 ? cs[j] : cs[2 * j];
            v = min(max(v, 0), C_ - 1);
            cd_idx[j] = v;
            atomicAdd(&cdeg[v], 1);
        }
        return;
    }
    if (blk < 2756) {
        // ---- cvtwb ----
        int i = (blk - 2048) * 256 + threadIdx.x;  // 181248 total
        if (i >= 180224) {
            int j = i - 180224;  // 0..1023
            const void* src;
            switch (j >> 7) {
                case 0: src = t0; break; case 1: src = t1; break;
                case 2: src = t2; break; case 3: src = t3; break;
                case 4: src = t4; break; case 5: src = t5; break;
                case 6: src = t6; break; default: src = t7; break;
            }
            bb[j] = ldf(src, j & 127, isf);
            return;
        }
        const void* src; int K, base;
        if      (i <  16384) { src = s0; K = 128; base = 0; }
        else if (i <  32768) { src = s1; K = 128; base = 16384; }
        else if (i <  49152) { src = s2; K = 128; base = 32768; }
        else if (i <  65536) { src = s3; K = 128; base = 49152; }
        else if (i <  81920) { src = s4; K = 128; base = 65536; }
        else if (i <  98304) { src = s5; K = 128; base = 81920; }
        else if (i < 131072) { src = s6; K = 256; base = 98304; }
        else                 { src = s7; K = 384; base = 131072; }
        int e = i - base;
        int k = e >> 7, n = e & 127;
        float v = ldf(src, e, isf);
        unsigned short h, l;
        split2(v, h, l);
        hi[base + n * K + k] = h;
        lo[base + n * K + k] = l;
        return;
    }
    // ---- init2 ----
    int i4 = (blk - 2756) * 256 + threadIdx.x;  // float4 id, total (L+C)*32
    const void* src; float* dst; int o;
    if (i4 < L_ * 32) { src = lv; dst = lemb; o = i4; }
    else              { src = cv; dst = cemb; o = i4 - L_ * 32; }
    int j = (o & 31) * 4;
    float4 v;
    v.x = ldf(src, j + 0, isf);
    v.y = ldf(src, j + 1, isf);
    v.z = ldf(src, j + 2, isf);
    v.w = ldf(src, j + 3, isf);
    ((float4*)dst)[o] = v;
}

// --- per-tile exclusive scan (stage 1), both sides fused ---
__global__ void scan1b_k(const int* __restrict__ ldeg, const int* __restrict__ cdeg,
                         int* __restrict__ lout, int* __restrict__ cout,
                         int* __restrict__ bsumL, int* __restrict__ bsumC) {
    __shared__ int s[256];
    const int* in; int* out; int* bs; int tile;
    if (blockIdx.x < 256) { in = ldeg; out = lout; bs = bsumL; tile = blockIdx.x; }
    else                  { in = cdeg; out = cout; bs = bsumC; tile = blockIdx.x - 256; }
    int i = tile * 256 + threadIdx.x;
    int v = in[i];
    s[threadIdx.x] = v;
    __syncthreads();
#pragma unroll
    for (int off = 1; off < 256; off <<= 1) {
        int t = (threadIdx.x >= off) ? s[threadIdx.x - off] : 0;
        __syncthreads();
        s[threadIdx.x] += t;
        __syncthreads();
    }
    out[i] = s[threadIdx.x] - v;
    if (threadIdx.x == 255) bs[tile] = s[255];
}

// stage 2+3 fused: each block redundantly computes its own bsum prefix
// (sum of RAW bsum[0..tile-1], <=256 L2-resident ints, in-block tree reduce)
// -- identical value to the old scan2b exclusive scan; saves one launch.
// Then: lptr += prefix, init cursors, invsq = deg ? rsqrt(deg) : 0.
__global__ void scan3b_k(int* __restrict__ lptr, int* __restrict__ cptr,
                         const int* __restrict__ bsumL, const int* __restrict__ bsumC,
                         int* __restrict__ lcur, int* __restrict__ ccur,
                         const int* __restrict__ ldeg, const int* __restrict__ cdeg,
                         float* __restrict__ invsq_l, float* __restrict__ invsq_c) {
    __shared__ int sh[256];
    int b = blockIdx.x, t = threadIdx.x;
    const bool lside = (b < 256);
    const int tile = lside ? b : b - 256;
    const int* bs = lside ? bsumL : bsumC;
    sh[t] = (t < tile) ? bs[t] : 0;
    __syncthreads();
#pragma unroll
    for (int off = 128; off > 0; off >>= 1) {
        if (t < off) sh[t] += sh[t + off];
        __syncthreads();
    }
    const int pref = sh[0];
    int i = tile * 256 + t;
    if (lside) {
        int v = lptr[i] + pref;
        lptr[i] = v; lcur[i] = v;
        int d = ldeg[i];
        invsq_l[i] = d ? rsqrtf((float)d) : 0.0f;
    } else {
        int v = cptr[i] + pref;
        cptr[i] = v; ccur[i] = v;
        int d = cdeg[i];
        invsq_c[i] = d ? rsqrtf((float)d) : 0.0f;
    }
}

// CSR placement (other endpoint only; norm is separable)
__global__ void place_k(const int* __restrict__ li, const int* __restrict__ ci,
                        int* __restrict__ lcur, int* __restrict__ ccur,
                        int* __restrict__ l_other, int* __restrict__ c_other) {
    int e = blockIdx.x * 256 + threadIdx.x;
    if (e >= E_) return;
    int l = li[e], c = ci[e];
    int p = atomicAdd(&ccur[c], 1);
    c_other[p] = l;
    int q = atomicAdd(&lcur[l], 1);
    l_other[q] = c;
}

// Fused pull-aggregation, both directions. Messages are bf16 (row = 64 dwords);
// each lane loads one dword (2 bf16), accumulates fp32, dest invsq applied at end.
// FOUR nodes per wave, 2-deep each -> 8 loads in flight (r9 structure, kept).
__global__ __launch_bounds__(256) void gather2_k(
    const int* __restrict__ cptr, const int* __restrict__ cdeg, const int* __restrict__ c_other,
    const unsigned int* __restrict__ lmsg, const float* __restrict__ invsq_c, float* __restrict__ caggr,
    const int* __restrict__ lptr, const int* __restrict__ ldeg, const int* __restrict__ l_other,
    const unsigned int* __restrict__ cmsg, const float* __restrict__ invsq_l, float* __restrict__ laggr,
    int nC) {
    int wid = (blockIdx.x * 256 + threadIdx.x) >> 6;
    int lane = threadIdx.x & 63;
    int n0 = 4 * wid;                       // quad (n0..n0+3): same side since C,L %4==0
    bool cside = n0 < nC;
    int j0 = cside ? n0 : n0 - nC;
    const int* ptr = cside ? cptr : lptr;
    const int* dg  = cside ? cdeg : ldeg;
    const int* oth = cside ? c_other : l_other;
    const unsigned int* msg = cside ? lmsg : cmsg;
    const float* invsq = cside ? invsq_c : invsq_l;
    float* out = cside ? caggr : laggr;

    int s0 = ptr[j0],     c0 = dg[j0];
    int s1 = ptr[j0 + 1], c1 = dg[j0 + 1];
    int s2 = ptr[j0 + 2], c2 = dg[j0 + 2];
    int s3 = ptr[j0 + 3], c3 = dg[j0 + 3];
    float2 A0 = {0.f, 0.f}, B0 = {0.f, 0.f};
    float2 A1 = {0.f, 0.f}, B1 = {0.f, 0.f};
    float2 A2 = {0.f, 0.f}, B2 = {0.f, 0.f};
    float2 A3 = {0.f, 0.f}, B3 = {0.f, 0.f};
    int k0 = 0, k1 = 0, k2 = 0, k3 = 0;

#define GLD_(s, k) msg[(size_t)oth[(s) + (k)] * 64 + lane]
#define GACC_(a, u) { (a).x += __uint_as_float((u) << 16); \
                      (a).y += __uint_as_float((u) & 0xffff0000u); }

    for (; k0 + 2 <= c0 && k1 + 2 <= c1 && k2 + 2 <= c2 && k3 + 2 <= c3;
         k0 += 2, k1 += 2, k2 += 2, k3 += 2) {
        unsigned int u00 = GLD_(s0, k0), u01 = GLD_(s0, k0 + 1);
        unsigned int u10 = GLD_(s1, k1), u11 = GLD_(s1, k1 + 1);
        unsigned int u20 = GLD_(s2, k2), u21 = GLD_(s2, k2 + 1);
        unsigned int u30 = GLD_(s3, k3), u31 = GLD_(s3, k3 + 1);
        GACC_(A0, u00); GACC_(B0, u01);
        GACC_(A1, u10); GACC_(B1, u11);
        GACC_(A2, u20); GACC_(B2, u21);
        GACC_(A3, u30); GACC_(B3, u31);
    }
    for (; k0 + 2 <= c0 && k1 + 2 <= c1; k0 += 2, k1 += 2) {
        unsigned int u00 = GLD_(s0, k0), u01 = GLD_(s0, k0 + 1);
        unsigned int u10 = GLD_(s1, k1), u11 = GLD_(s1, k1 + 1);
        GACC_(A0, u00); GACC_(B0, u01);
        GACC_(A1, u10); GACC_(B1, u11);
    }
    for (; k2 + 2 <= c2 && k3 + 2 <= c3; k2 += 2, k3 += 2) {
        unsigned int u20 = GLD_(s2, k2), u21 = GLD_(s2, k2 + 1);
        unsigned int u30 = GLD_(s3, k3), u31 = GLD_(s3, k3 + 1);
        GACC_(A2, u20); GACC_(B2, u21);
        GACC_(A3, u30); GACC_(B3, u31);
    }
    for (; k0 + 2 <= c0; k0 += 2) {
        unsigned int ua = GLD_(s0, k0), ub = GLD_(s0, k0 + 1);
        GACC_(A0, ua); GACC_(B0, ub);
    }
    for (; k1 + 2 <= c1; k1 += 2) {
        unsigned int ua = GLD_(s1, k1), ub = GLD_(s1, k1 + 1);
        GACC_(A1, ua); GACC_(B1, ub);
    }
    for (; k2 + 2 <= c2; k2 += 2) {
        unsigned int ua = GLD_(s2, k2), ub = GLD_(s2, k2 + 1);
        GACC_(A2, ua); GACC_(B2, ub);
    }
    for (; k3 + 2 <= c3; k3 += 2) {
        unsigned int ua = GLD_(s3, k3), ub = GLD_(s3, k3 + 1);
        GACC_(A3, ua); GACC_(B3, ub);
    }
    if (k0 < c0) { unsigned int u = GLD_(s0, k0); GACC_(A0, u); }
    if (k1 < c1) { unsigned int u = GLD_(s1, k1); GACC_(A1, u); }
    if (k2 < c2) { unsigned int u = GLD_(s2, k2); GACC_(A2, u); }
    if (k3 < c3) { unsigned int u = GLD_(s3, k3); GACC_(A3, u); }
#undef GLD_
#undef GACC_

    float sc0 = invsq[j0], sc1 = invsq[j0 + 1];
    float sc2 = invsq[j0 + 2], sc3 = invsq[j0 + 3];
    float2 r;
    r.x = (A0.x + B0.x) * sc0; r.y = (A0.y + B0.y) * sc0;
    *(float2*)&out[(size_t)j0 * D_ + 2 * lane] = r;
    r.x = (A1.x + B1.x) * sc1; r.y = (A1.y + B1.y) * sc1;
    *(float2*)&out[(size_t)(j0 + 1) * D_ + 2 * lane] = r;
    r.x = (A2.x + B2.x) * sc2; r.y = (A2.y + B2.y) * sc2;
    *(float2*)&out[(size_t)(j0 + 2) * D_ + 2 * lane] = r;
    r.x = (A3.x + B3.x) * sc3; r.y = (A3.y + B3.y) * sc3;
    *(float2*)&out[(size_t)(j0 + 3) * D_ + 2 * lane] = r;
}

// ---------- fused 2-layer MLPs, all three in one launch; 128-row tiles ----------
// blocks [0,nL): l2c on l_cur -> l_msg (scaled by invsq_l)
// blocks [nL,nL+nC): c2l on c_cur -> c_msg (scaled by invsq_c)
// blocks [nL+nC,...): l2l on l_cur with pair-SWAP -> l2lb (unscaled)
// Outputs stored as bf16 (consumed by gather / l-update A2).
// (EXACT round-0 structure -- best measured: 57.4 us/dispatch.)
__global__ __launch_bounds__(256, 2) void mlp3_k(
    const float* __restrict__ l_cur, const float* __restrict__ c_cur,
    const unsigned short* __restrict__ wt_hi, const unsigned short* __restrict__ wt_lo,
    const float* __restrict__ bb,
    const float* __restrict__ invsq_l, const float* __restrict__ invsq_c,
    bf16* __restrict__ l_msg, bf16* __restrict__ c_msg, bf16* __restrict__ l2lb,
    int nL, int nC) {
    __shared__ char smem[66048];
    unsigned short (*a_hi)[40] = (unsigned short(*)[40])(smem);
    unsigned short (*a_lo)[40] = (unsigned short(*)[40])(smem + 10240);
    unsigned short (*b_hi)[40] = (unsigned short(*)[40])(smem + 20480);
    unsigned short (*b_lo)[40] = (unsigned short(*)[40])(smem + 30720);
    unsigned short* h_hi = (unsigned short*)(smem);          // phase 2 aliases tiles
    unsigned short* h_lo = (unsigned short*)(smem + 32768);
    float* scv = (float*)(smem + 65536);                     // 128 floats, non-aliased

    int b = blockIdx.x, seg, tile;
    if (b < nL)           { seg = 0; tile = b; }
    else if (b < nL + nC) { seg = 1; tile = b - nL; }
    else                  { seg = 2; tile = b - nL - nC; }
    const float* A = (seg == 1) ? c_cur : l_cur;
    bf16* outp = (seg == 0) ? l_msg : (seg == 1) ? c_msg : l2lb;
    const float* invsq = (seg == 0) ? invsq_l : (seg == 1) ? invsq_c : nullptr;
    const unsigned short* W1h = wt_hi + seg * 32768;
    const unsigned short* W1l = wt_lo + seg * 32768;
    const unsigned short* W2h = W1h + 16384;
    const unsigned short* W2l = W1l + 16384;
    const float* b1v = bb + seg * 256;
    const float* b2v = b1v + 128;
    const int swap = (seg == 2);

    const int t = threadIdx.x;
    const int br0 = tile * 128;
    const int w = t >> 6, lane = t & 63;
    const int wr = w >> 1, wc = w & 1;
    const int quad = lane >> 4, cl = lane & 15;

    if (t < 128) scv[t] = invsq ? invsq[br0 + t] : 1.0f;

    f32x4 acc[4][4];
#pragma unroll
    for (int i = 0; i < 4; i++)
#pragma unroll
        for (int j = 0; j < 4; j++) acc[i][j] = (f32x4){0.f, 0.f, 0.f, 0.f};

    // ---- phase 1: h = A @ W1 ----
    for (int kt = 0; kt < 128; kt += 32) {
#pragma unroll
        for (int i = 0; i < 4; i++) {
            int f = t + 256 * i;
            int r = f >> 3, kq = f & 7;
            int gr = br0 + r;
            if (swap) gr ^= 1;
            const float4 v = *(const float4*)&A[(size_t)gr * D_ + kt + 4 * kq];
            unsigned short h0, l0, h1, l1, h2, l2, h3, l3;
            split2(v.x, h0, l0); split2(v.y, h1, l1);
            split2(v.z, h2, l2); split2(v.w, h3, l3);
            *(ushort4*)&a_hi[r][4 * kq] = make_ushort4(h0, h1, h2, h3);
            *(ushort4*)&a_lo[r][4 * kq] = make_ushort4(l0, l1, l2, l3);
            *(ushort4*)&b_hi[r][4 * kq] = *(const ushort4*)&W1h[(size_t)r * 128 + kt + 4 * kq];
            *(ushort4*)&b_lo[r][4 * kq] = *(const ushort4*)&W1l[(size_t)r * 128 + kt + 4 * kq];
        }
        __syncthreads();
        short8 af_h[4], af_l[4];
#pragma unroll
        for (int i = 0; i < 4; i++) {
            int row = 64 * wr + 16 * i + cl;
            af_h[i] = *(const short8*)&a_hi[row][quad * 8];
            af_l[i] = *(const short8*)&a_lo[row][quad * 8];
        }
#pragma unroll
        for (int j = 0; j < 4; j++) {
            int col = 64 * wc + 16 * j + cl;
            short8 bf_h = *(const short8*)&b_hi[col][quad * 8];
            short8 bf_l = *(const short8*)&b_lo[col][quad * 8];
#pragma unroll
            for (int i = 0; i < 4; i++) {
                acc[i][j] = __builtin_amdgcn_mfma_f32_16x16x32_bf16(af_h[i], bf_h, acc[i][j], 0, 0, 0);
                acc[i][j] = __builtin_amdgcn_mfma_f32_16x16x32_bf16(af_h[i], bf_l, acc[i][j], 0, 0, 0);
                acc[i][j] = __builtin_amdgcn_mfma_f32_16x16x32_bf16(af_l[i], bf_h, acc[i][j], 0, 0, 0);
            }
        }
        __syncthreads();
    }
    // h epilogue: bias + relu + split -> swizzled LDS. C/D: col=cl, row=quad*4+reg.
#pragma unroll
    for (int j = 0; j < 4; j++) {
        int col = 64 * wc + 16 * j + cl;
        float bv = b1v[col];
        int g = col >> 3, go = col & 7;
#pragma unroll
        for (int i = 0; i < 4; i++) {
            int rloc = 64 * wr + 16 * i + quad * 4;
#pragma unroll
            for (int rg = 0; rg < 4; rg++) {
                float v = fmaxf(acc[i][j][rg] + bv, 0.0f);
                unsigned short hh, ll;
                split2(v, hh, ll);
                int r = rloc + rg;
                int off = r * 128 + ((g ^ (r & 15)) << 3) + go;
                h_hi[off] = hh;
                h_lo[off] = ll;
            }
        }
    }
    __syncthreads();
    // ---- phase 2: out = (h @ W2 + b2) * scv -> bf16 ----
#pragma unroll
    for (int i = 0; i < 4; i++)
#pragma unroll
        for (int j = 0; j < 4; j++) acc[i][j] = (f32x4){0.f, 0.f, 0.f, 0.f};

    for (int kt = 0; kt < 128; kt += 32) {
        short8 af_h[4], af_l[4];
        int gbase = (kt >> 3) + quad;
#pragma unroll
        for (int i = 0; i < 4; i++) {
            int r = 64 * wr + 16 * i + cl;
            int off = r * 128 + ((gbase ^ cl) << 3);
            af_h[i] = *(const short8*)&h_hi[off];
            af_l[i] = *(const short8*)&h_lo[off];
        }
#pragma unroll
        for (int j = 0; j < 4; j++) {
            int col = 64 * wc + 16 * j + cl;
            const short8 bf_h = *(const short8*)&W2h[(size_t)col * 128 + kt + quad * 8];
            const short8 bf_l = *(const short8*)&W2l[(size_t)col * 128 + kt + quad * 8];
#pragma unroll
            for (int i = 0; i < 4; i++) {
                acc[i][j] = __builtin_amdgcn_mfma_f32_16x16x32_bf16(af_h[i], bf_h, acc[i][j], 0, 0, 0);
                acc[i][j] = __builtin_amdgcn_mfma_f32_16x16x32_bf16(af_h[i], bf_l, acc[i][j], 0, 0, 0);
                acc[i][j] = __builtin_amdgcn_mfma_f32_16x16x32_bf16(af_l[i], bf_h, acc[i][j], 0, 0, 0);
            }
        }
    }
#pragma unroll
    for (int j = 0; j < 4; j++) {
        int col = 64 * wc + 16 * j + cl;
        float bv = b2v[col];
#pragma unroll
        for (int i = 0; i < 4; i++) {
            int rloc = 64 * wr + 16 * i + quad * 4;
#pragma unroll
            for (int rg = 0; rg < 4; rg++)
                outp[(size_t)(br0 + rloc + rg) * D_ + col] =
                    __float2bfloat16((acc[i][j][rg] + bv) * scv[rloc + rg]);
        }
    }
}

// ---------- fused update GEMMs; 128-row tiles (EXACT round-0 structure) ----------
// FINAL=0: blocks [0,256) c-update K=256 -> c_nxt; [256,768) l-update K=384 -> l_nxt.
// FINAL=1: all blocks l-update K=384 -> d_out (fp32 or bf16 per flags[0]).
// A2 (l2l messages) is bf16 -> a_lo==0 for kt>=256: skip the Al*Bh MFMA there.
template <int FINAL>
__global__ __launch_bounds__(256, 2) void update_k(
    const float* __restrict__ l_cur, const float* __restrict__ c_cur,
    const float* __restrict__ laggr, const float* __restrict__ caggr,
    const bf16* __restrict__ l2lb,
    const unsigned short* __restrict__ wt_hi, const unsigned short* __restrict__ wt_lo,
    const float* __restrict__ bb,
    float* __restrict__ c_nxt, float* __restrict__ l_nxt,
    void* __restrict__ dout, const int* __restrict__ flags) {
    __shared__ unsigned short a_hi[128][40], a_lo[128][40];
    __shared__ unsigned short b_hi[128][40], b_lo[128][40];
    const int t = threadIdx.x;
    int b = blockIdx.x;
    const bool cseg = (!FINAL) && (b < 256);
    const int tile = (FINAL || cseg) ? b : b - 256;
    const int K = cseg ? 256 : 384;
    const float* A0 = cseg ? c_cur : l_cur;
    const float* A1 = cseg ? caggr : laggr;
    const unsigned short* Wh = wt_hi + (cseg ? 98304 : 131072);
    const unsigned short* Wl = wt_lo + (cseg ? 98304 : 131072);
    const float* bias = bb + (cseg ? 768 : 896);
    const int br0 = tile * 128;
    const int w = t >> 6, lane = t & 63;
    const int wr = w >> 1, wc = w & 1;
    const int quad = lane >> 4, cl = lane & 15;

    f32x4 acc[4][4];
#pragma unroll
    for (int i = 0; i < 4; i++)
#pragma unroll
        for (int j = 0; j < 4; j++) acc[i][j] = (f32x4){0.f, 0.f, 0.f, 0.f};

    for (int kt = 0; kt < K; kt += 32) {
        const bool haslo = (kt < 256);
        const int koff = kt & 127;
#pragma unroll
        for (int i = 0; i < 4; i++) {
            int f = t + 256 * i;
            int r = f >> 3, kq = f & 7;
            if (haslo) {
                const float* As = (kt < 128) ? A0 : A1;
                const float4 v = *(const float4*)&As[(size_t)(br0 + r) * D_ + koff + 4 * kq];
                unsigned short h0, l0, h1, l1, h2, l2, h3, l3;
                split2(v.x, h0, l0); split2(v.y, h1, l1);
                split2(v.z, h2, l2); split2(v.w, h3, l3);
                *(ushort4*)&a_hi[r][4 * kq] = make_ushort4(h0, h1, h2, h3);
                *(ushort4*)&a_lo[r][4 * kq] = make_ushort4(l0, l1, l2, l3);
            } else {
                *(ushort4*)&a_hi[r][4 * kq] =
                    *(const ushort4*)&l2lb[(size_t)(br0 + r) * D_ + koff + 4 * kq];
            }
            *(ushort4*)&b_hi[r][4 * kq] = *(const ushort4*)&Wh[(size_t)r * K + kt + 4 * kq];
            *(ushort4*)&b_lo[r][4 * kq] = *(const ushort4*)&Wl[(size_t)r * K + kt + 4 * kq];
        }
        __syncthreads();
        short8 af_h[4], af_l[4];
#pragma unroll
        for (int i = 0; i < 4; i++) {
            int row = 64 * wr + 16 * i + cl;
            af_h[i] = *(const short8*)&a_hi[row][quad * 8];
            if (haslo) af_l[i] = *(const short8*)&a_lo[row][quad * 8];
        }
#pragma unroll
        for (int j = 0; j < 4; j++) {
            int col = 64 * wc + 16 * j + cl;
            short8 bf_h = *(const short8*)&b_hi[col][quad * 8];
            short8 bf_l = *(const short8*)&b_lo[col][quad * 8];
#pragma unroll
            for (int i = 0; i < 4; i++) {
                acc[i][j] = __builtin_amdgcn_mfma_f32_16x16x32_bf16(af_h[i], bf_h, acc[i][j], 0, 0, 0);
                acc[i][j] = __builtin_amdgcn_mfma_f32_16x16x32_bf16(af_h[i], bf_l, acc[i][j], 0, 0, 0);
                if (haslo)
                    acc[i][j] = __builtin_amdgcn_mfma_f32_16x16x32_bf16(af_l[i], bf_h, acc[i][j], 0, 0, 0);
            }
        }
        __syncthreads();
    }
    const int f32out = FINAL ? flags[0] : 1;
#pragma unroll
    for (int j = 0; j < 4; j++) {
        int col = 64 * wc + 16 * j + cl;
        float bv = bias[col];
#pragma unroll
        for (int i = 0; i < 4; i++) {
            int rbase = br0 + 64 * wr + 16 * i + quad * 4;
#pragma unroll
            for (int rg = 0; rg < 4; rg++) {
                float v = acc[i][j][rg] + bv;
                size_t idx = (size_t)(rbase + rg) * D_ + col;
                if (FINAL) {
                    if (f32out) ((float*)dout)[idx] = v;
                    else        ((bf16*)dout)[idx] = __float2bfloat16(v);
                } else {
                    (cseg ? c_nxt : l_nxt)[idx] = v;
                }
            }
        }
    }
}

extern "C" void kernel_launch(void* const* d_in, const int* in_sizes, int n_in,
                              void* d_out, int out_size, void* d_ws, size_t ws_size,
                              hipStream_t stream) {
    const int* li_raw = (const int*)d_in[0];
    const int* ci_raw = (const int*)d_in[1];

    // ---- workspace layout (flags placed after cdegi -> ONE zeroing memset) ----
    float* ws = (float*)d_ws;
    float* lbuf0 = ws;                               // L*D
    float* lbuf1 = lbuf0 + (size_t)L_ * D_;          // L*D  (doubles as bf16 l_msg)
    float* l2lb  = lbuf1 + (size_t)L_ * D_;          // L*D  (bf16 l2l messages)
    float* laggr = l2lb + (size_t)L_ * D_;           // L*D
    float* cbuf0 = laggr + (size_t)L_ * D_;          // C*D
    float* cbuf1 = cbuf0 + (size_t)C_ * D_;          // C*D  (doubles as bf16 c_msg)
    float* caggr = cbuf1 + (size_t)C_ * D_;          // C*D
    float* invsq_l = caggr + (size_t)C_ * D_;        // L
    float* invsq_c = invsq_l + L_;                   // C
    float* bb    = invsq_c + C_;                     // 1024 bias floats
    unsigned short* wt_hi = (unsigned short*)(bb + 1024);   // 180224 ushorts
    unsigned short* wt_lo = wt_hi + 180224;                 // 180224 ushorts
    int*   li    = (int*)(wt_lo + 180224);           // E
    int*   ci    = li + E_;                          // E
    int*   l_other = ci + E_;                        // E
    int*   c_other = l_other + E_;                   // E
    int*   ldegi = c_other + E_;                     // L
    int*   cdegi = ldegi + L_;                       // C
    int*   flags = cdegi + C_;                       // 2  (contiguous with deg arrays)
    int*   lptr  = flags + 2;                        // L
    int*   cptr  = lptr + L_;                        // C
    int*   lcur  = cptr + C_;                        // L
    int*   ccur  = lcur + L_;                        // C
    int*   bsumL = ccur + C_;                        // 256
    int*   bsumC = bsumL + 256;                      // 128

    // --- one memset zeroes degrees + flags; then dtype detection ---
    hipMemsetAsync(ldegi, 0, ((size_t)(L_ + C_) + 2) * sizeof(int), stream);
    detect_k<<<16, 512, 0, stream>>>((const unsigned short*)d_in[4], li_raw, flags);

    // --- fused preamble: fixdeg + weight-split + embedding-init (one launch) ---
    prep_k<<<15044, 256, 0, stream>>>(
        li_raw, ci_raw, li, ci, ldegi, cdegi,
        d_in[4], d_in[6], d_in[8], d_in[10], d_in[12], d_in[14], d_in[16], d_in[18],
        d_in[5], d_in[7], d_in[9], d_in[11], d_in[13], d_in[15], d_in[17], d_in[19],
        wt_hi, wt_lo, bb,
        d_in[2], d_in[3], lbuf0, cbuf0, flags);

    // --- CSR build (scan2b folded into scan3b via redundant in-block prefix) ---
    scan1b_k<<<384, 256, 0, stream>>>(ldegi, cdegi, lptr, cptr, bsumL, bsumC);
    scan3b_k<<<384, 256, 0, stream>>>(lptr, cptr, bsumL, bsumC, lcur, ccur,
                                      ldegi, cdegi, invsq_l, invsq_c);
    place_k<<<E_ / 256, 256, 0, stream>>>(li, ci, lcur, ccur, l_other, c_other);

    float* l_cur = lbuf0; float* l_nxt = lbuf1;
    float* c_cur = cbuf0; float* c_nxt = cbuf1;

    const int nL = L_ / 128, nC = C_ / 128;
    for (int it = 0; it < 3; it++) {
        mlp3_k<<<2 * nL + nC, 256, 0, stream>>>(
            l_cur, c_cur, wt_hi, wt_lo, bb, invsq_l, invsq_c,
            (bf16*)l_nxt, (bf16*)c_nxt, (bf16*)l2lb, nL, nC);
        gather2_k<<<(C_ + L_) / 16, 256, 0, stream>>>(
            cptr, cdegi, c_other, (const unsigned int*)l_nxt, invsq_c, caggr,
            lptr, ldegi, l_other, (const unsigned int*)c_nxt, invsq_l, laggr, C_);
        update_k<0><<<768, 256, 0, stream>>>(
            l_cur, c_cur, laggr, caggr, (const bf16*)l2lb, wt_hi, wt_lo, bb,
            c_nxt, l_nxt, nullptr, flags);
        float* tmp = l_cur; l_cur = l_nxt; l_nxt = tmp;
        tmp = c_cur; c_cur = c_nxt; c_nxt = tmp;
    }
    // --- final iteration: c-update dead -> skip l2c MLP, c-gather, c-update;
    //     fuse output dtype conversion into the l-update epilogue ---
    mlp3_k<<<nC + nL, 256, 0, stream>>>(
        l_cur, c_cur, wt_hi, wt_lo, bb, invsq_l, invsq_c,
        (bf16*)l_nxt, (bf16*)c_nxt, (bf16*)l2lb, 0, nC);
    gather2_k<<<L_ / 16, 256, 0, stream>>>(
        cptr, cdegi, c_other, (const unsigned int*)l_nxt, invsq_c, caggr,
        lptr, ldegi, l_other, (const unsigned int*)c_nxt, invsq_l, laggr, 0);
    update_k<1><<<512, 256, 0, stream>>>(
        l_cur, c_cur, laggr, caggr, (const bf16*)l2lb, wt_hi, wt_lo, bb,
        nullptr, nullptr, d_out, flags);
}

// Round 11
// 633.907 us; speedup vs baseline: 1.8066x; 1.0460x over previous
//
#include <hip/hip_runtime.h>
#include <hip/hip_bf16.h>

#define D_ 128
#define L_ 65536
#define C_ 32768
#define E_ 262144

typedef __hip_bfloat16 bf16;
typedef __attribute__((ext_vector_type(8))) short short8;
typedef __attribute__((ext_vector_type(4))) float f32x4;

// flags[0] = 1 if float inputs are fp32 (else bf16); flags[1] = 1 if edge idx int32 (else int64)
__global__ void detect_k(const unsigned short* __restrict__ wmem,
                         const int* __restrict__ li, int* __restrict__ flags) {
    int t = blockIdx.x * 512 + threadIdx.x;
    if (t < 8192) {
        unsigned short h = wmem[2 * t];
        float v = __bfloat162float(*(const bf16*)&h);
        if (!(fabsf(v) < 0.5f)) atomicOr(&flags[0], 1);
    }
    if (t < 2048) {
        if (li[2 * t + 1] != 0) atomicOr(&flags[1], 1);
    }
}

__device__ __forceinline__ void split2(float v, unsigned short& h, unsigned short& l) {
    bf16 bh = __float2bfloat16(v);
    float fh = __bfloat162float(bh);
    bf16 bl = __float2bfloat16(v - fh);
    h = *(unsigned short*)&bh;
    l = *(unsigned short*)&bl;
}

__device__ __forceinline__ float ldf(const void* s, int i, int isf32) {
    return isf32 ? ((const float*)s)[i] : __bfloat162float(((const bf16*)s)[i]);
}

// ---- fused preamble: fixdeg (2048 blocks) + cvtwb (708) + init2 (12288) ----
__global__ void prep_k(const int* __restrict__ ls, const int* __restrict__ cs,
                       int* __restrict__ ld_idx, int* __restrict__ cd_idx,
                       int* __restrict__ ldeg, int* __restrict__ cdeg,
                       const void* s0, const void* s1, const void* s2, const void* s3,
                       const void* s4, const void* s5, const void* s6, const void* s7,
                       const void* t0, const void* t1, const void* t2, const void* t3,
                       const void* t4, const void* t5, const void* t6, const void* t7,
                       unsigned short* __restrict__ hi, unsigned short* __restrict__ lo,
                       float* __restrict__ bb,
                       const void* __restrict__ lv, const void* __restrict__ cv,
                       float* __restrict__ lemb, float* __restrict__ cemb,
                       const int* __restrict__ flags) {
    const int blk = blockIdx.x;
    const int isf = flags[0];
    if (blk < 2048) {
        int i = blk * 256 + threadIdx.x;
        int is32 = flags[1];
        if (i < E_) {
            int v = is32 ? ls[i] : ls[2 * i];
            v = min(max(v, 0), L_ - 1);
            ld_idx[i] = v;
            atomicAdd(&ldeg[v], 1);
        } else {
            int j = i - E_;
            int v = is32 ? cs[j] : cs[2 * j];
            v = min(max(v, 0), C_ - 1);
            cd_idx[j] = v;
            atomicAdd(&cdeg[v], 1);
        }
        return;
    }
    if (blk < 2756) {
        int i = (blk - 2048) * 256 + threadIdx.x;  // 181248 total
        if (i >= 180224) {
            int j = i - 180224;  // 0..1023
            const void* src;
            switch (j >> 7) {
                case 0: src = t0; break; case 1: src = t1; break;
                case 2: src = t2; break; case 3: src = t3; break;
                case 4: src = t4; break; case 5: src = t5; break;
                case 6: src = t6; break; default: src = t7; break;
            }
            bb[j] = ldf(src, j & 127, isf);
            return;
        }
        const void* src; int K, base;
        if      (i <  16384) { src = s0; K = 128; base = 0; }
        else if (i <  32768) { src = s1; K = 128; base = 16384; }
        else if (i <  49152) { src = s2; K = 128; base = 32768; }
        else if (i <  65536) { src = s3; K = 128; base = 49152; }
        else if (i <  81920) { src = s4; K = 128; base = 65536; }
        else if (i <  98304) { src = s5; K = 128; base = 81920; }
        else if (i < 131072) { src = s6; K = 256; base = 98304; }
        else                 { src = s7; K = 384; base = 131072; }
        int e = i - base;
        int k = e >> 7, n = e & 127;
        float v = ldf(src, e, isf);
        unsigned short h, l;
        split2(v, h, l);
        hi[base + n * K + k] = h;
        lo[base + n * K + k] = l;
        return;
    }
    int i4 = (blk - 2756) * 256 + threadIdx.x;  // float4 id, total (L+C)*32
    const void* src; float* dst; int o;
    if (i4 < L_ * 32) { src = lv; dst = lemb; o = i4; }
    else              { src = cv; dst = cemb; o = i4 - L_ * 32; }
    int j = (o & 31) * 4;
    float4 v;
    v.x = ldf(src, j + 0, isf);
    v.y = ldf(src, j + 1, isf);
    v.z = ldf(src, j + 2, isf);
    v.w = ldf(src, j + 3, isf);
    ((float4*)dst)[o] = v;
}

// --- per-tile exclusive scan (stage 1), both sides fused ---
__global__ void scan1b_k(const int* __restrict__ ldeg, const int* __restrict__ cdeg,
                         int* __restrict__ lout, int* __restrict__ cout,
                         int* __restrict__ bsumL, int* __restrict__ bsumC) {
    __shared__ int s[256];
    const int* in; int* out; int* bs; int tile;
    if (blockIdx.x < 256) { in = ldeg; out = lout; bs = bsumL; tile = blockIdx.x; }
    else                  { in = cdeg; out = cout; bs = bsumC; tile = blockIdx.x - 256; }
    int i = tile * 256 + threadIdx.x;
    int v = in[i];
    s[threadIdx.x] = v;
    __syncthreads();
#pragma unroll
    for (int off = 1; off < 256; off <<= 1) {
        int t = (threadIdx.x >= off) ? s[threadIdx.x - off] : 0;
        __syncthreads();
        s[threadIdx.x] += t;
        __syncthreads();
    }
    out[i] = s[threadIdx.x] - v;
    if (threadIdx.x == 255) bs[tile] = s[255];
}

// stage 2+3 fused: each block redundantly computes its own bsum prefix.
__global__ void scan3b_k(int* __restrict__ lptr, int* __restrict__ cptr,
                         const int* __restrict__ bsumL, const int* __restrict__ bsumC,
                         int* __restrict__ lcur, int* __restrict__ ccur,
                         const int* __restrict__ ldeg, const int* __restrict__ cdeg,
                         float* __restrict__ invsq_l, float* __restrict__ invsq_c) {
    __shared__ int sh[256];
    int b = blockIdx.x, t = threadIdx.x;
    const bool lside = (b < 256);
    const int tile = lside ? b : b - 256;
    const int* bs = lside ? bsumL : bsumC;
    sh[t] = (t < tile) ? bs[t] : 0;
    __syncthreads();
#pragma unroll
    for (int off = 128; off > 0; off >>= 1) {
        if (t < off) sh[t] += sh[t + off];
        __syncthreads();
    }
    const int pref = sh[0];
    int i = tile * 256 + t;
    if (lside) {
        int v = lptr[i] + pref;
        lptr[i] = v; lcur[i] = v;
        int d = ldeg[i];
        invsq_l[i] = d ? rsqrtf((float)d) : 0.0f;
    } else {
        int v = cptr[i] + pref;
        cptr[i] = v; ccur[i] = v;
        int d = cdeg[i];
        invsq_c[i] = d ? rsqrtf((float)d) : 0.0f;
    }
}

// CSR placement (other endpoint only; norm is separable)
__global__ void place_k(const int* __restrict__ li, const int* __restrict__ ci,
                        int* __restrict__ lcur, int* __restrict__ ccur,
                        int* __restrict__ l_other, int* __restrict__ c_other) {
    int e = blockIdx.x * 256 + threadIdx.x;
    if (e >= E_) return;
    int l = li[e], c = ci[e];
    int p = atomicAdd(&ccur[c], 1);
    c_other[p] = l;
    int q = atomicAdd(&lcur[l], 1);
    l_other[q] = c;
}

// it=0 message broadcast: embeddings are row-uniform at it=0, so messages are
// bf16(base[col] * invsq[row]) with base = the single fp32 MLP output row
// captured by the 3-block mlp3 launch. Bitwise identical to the full mlp3 path.
__global__ void bcast_k(const float* __restrict__ baseb,
                        const float* __restrict__ invsq_l, const float* __restrict__ invsq_c,
                        bf16* __restrict__ l_msg, bf16* __restrict__ c_msg,
                        bf16* __restrict__ l2lb) {
    int id = blockIdx.x * 256 + threadIdx.x;   // each id writes 8 bf16 (16B)
    const int LCH = L_ * 16;
    const int CCH = C_ * 16;
    const float* base; bf16* out; int row, c8; float sc;
    if (id < LCH)            { base = baseb;       out = l_msg; row = id >> 4;
                               c8 = (id & 15) * 8; sc = invsq_l[row]; }
    else if (id < LCH + CCH) { int k = id - LCH;   base = baseb + 128; out = c_msg;
                               row = k >> 4; c8 = (k & 15) * 8; sc = invsq_c[row]; }
    else                     { int k = id - LCH - CCH; base = baseb + 256; out = l2lb;
                               row = k >> 4; c8 = (k & 15) * 8; sc = 1.0f; }
    union { short8 v; unsigned short u[8]; } o;
#pragma unroll
    for (int k = 0; k < 8; k++) {
        bf16 b = __float2bfloat16(base[c8 + k] * sc);
        o.u[k] = *(unsigned short*)&b;
    }
    *(short8*)&out[(size_t)row * D_ + c8] = o.v;
}

// Fused pull-aggregation, both directions (r9 4-node/2-deep structure, kept).
__global__ __launch_bounds__(256) void gather2_k(
    const int* __restrict__ cptr, const int* __restrict__ cdeg, const int* __restrict__ c_other,
    const unsigned int* __restrict__ lmsg, const float* __restrict__ invsq_c, float* __restrict__ caggr,
    const int* __restrict__ lptr, const int* __restrict__ ldeg, const int* __restrict__ l_other,
    const unsigned int* __restrict__ cmsg, const float* __restrict__ invsq_l, float* __restrict__ laggr,
    int nC) {
    int wid = (blockIdx.x * 256 + threadIdx.x) >> 6;
    int lane = threadIdx.x & 63;
    int n0 = 4 * wid;
    bool cside = n0 < nC;
    int j0 = cside ? n0 : n0 - nC;
    const int* ptr = cside ? cptr : lptr;
    const int* dg  = cside ? cdeg : ldeg;
    const int* oth = cside ? c_other : l_other;
    const unsigned int* msg = cside ? lmsg : cmsg;
    const float* invsq = cside ? invsq_c : invsq_l;
    float* out = cside ? caggr : laggr;

    int s0 = ptr[j0],     c0 = dg[j0];
    int s1 = ptr[j0 + 1], c1 = dg[j0 + 1];
    int s2 = ptr[j0 + 2], c2 = dg[j0 + 2];
    int s3 = ptr[j0 + 3], c3 = dg[j0 + 3];
    float2 A0 = {0.f, 0.f}, B0 = {0.f, 0.f};
    float2 A1 = {0.f, 0.f}, B1 = {0.f, 0.f};
    float2 A2 = {0.f, 0.f}, B2 = {0.f, 0.f};
    float2 A3 = {0.f, 0.f}, B3 = {0.f, 0.f};
    int k0 = 0, k1 = 0, k2 = 0, k3 = 0;

#define GLD_(s, k) msg[(size_t)oth[(s) + (k)] * 64 + lane]
#define GACC_(a, u) { (a).x += __uint_as_float((u) << 16); \
                      (a).y += __uint_as_float((u) & 0xffff0000u); }

    for (; k0 + 2 <= c0 && k1 + 2 <= c1 && k2 + 2 <= c2 && k3 + 2 <= c3;
         k0 += 2, k1 += 2, k2 += 2, k3 += 2) {
        unsigned int u00 = GLD_(s0, k0), u01 = GLD_(s0, k0 + 1);
        unsigned int u10 = GLD_(s1, k1), u11 = GLD_(s1, k1 + 1);
        unsigned int u20 = GLD_(s2, k2), u21 = GLD_(s2, k2 + 1);
        unsigned int u30 = GLD_(s3, k3), u31 = GLD_(s3, k3 + 1);
        GACC_(A0, u00); GACC_(B0, u01);
        GACC_(A1, u10); GACC_(B1, u11);
        GACC_(A2, u20); GACC_(B2, u21);
        GACC_(A3, u30); GACC_(B3, u31);
    }
    for (; k0 + 2 <= c0 && k1 + 2 <= c1; k0 += 2, k1 += 2) {
        unsigned int u00 = GLD_(s0, k0), u01 = GLD_(s0, k0 + 1);
        unsigned int u10 = GLD_(s1, k1), u11 = GLD_(s1, k1 + 1);
        GACC_(A0, u00); GACC_(B0, u01);
        GACC_(A1, u10); GACC_(B1, u11);
    }
    for (; k2 + 2 <= c2 && k3 + 2 <= c3; k2 += 2, k3 += 2) {
        unsigned int u20 = GLD_(s2, k2), u21 = GLD_(s2, k2 + 1);
        unsigned int u30 = GLD_(s3, k3), u31 = GLD_(s3, k3 + 1);
        GACC_(A2, u20); GACC_(B2, u21);
        GACC_(A3, u30); GACC_(B3, u31);
    }
    for (; k0 + 2 <= c0; k0 += 2) {
        unsigned int ua = GLD_(s0, k0), ub = GLD_(s0, k0 + 1);
        GACC_(A0, ua); GACC_(B0, ub);
    }
    for (; k1 + 2 <= c1; k1 += 2) {
        unsigned int ua = GLD_(s1, k1), ub = GLD_(s1, k1 + 1);
        GACC_(A1, ua); GACC_(B1, ub);
    }
    for (; k2 + 2 <= c2; k2 += 2) {
        unsigned int ua = GLD_(s2, k2), ub = GLD_(s2, k2 + 1);
        GACC_(A2, ua); GACC_(B2, ub);
    }
    for (; k3 + 2 <= c3; k3 += 2) {
        unsigned int ua = GLD_(s3, k3), ub = GLD_(s3, k3 + 1);
        GACC_(A3, ua); GACC_(B3, ub);
    }
    if (k0 < c0) { unsigned int u = GLD_(s0, k0); GACC_(A0, u); }
    if (k1 < c1) { unsigned int u = GLD_(s1, k1); GACC_(A1, u); }
    if (k2 < c2) { unsigned int u = GLD_(s2, k2); GACC_(A2, u); }
    if (k3 < c3) { unsigned int u = GLD_(s3, k3); GACC_(A3, u); }
#undef GLD_
#undef GACC_

    float sc0 = invsq[j0], sc1 = invsq[j0 + 1];
    float sc2 = invsq[j0 + 2], sc3 = invsq[j0 + 3];
    float2 r;
    r.x = (A0.x + B0.x) * sc0; r.y = (A0.y + B0.y) * sc0;
    *(float2*)&out[(size_t)j0 * D_ + 2 * lane] = r;
    r.x = (A1.x + B1.x) * sc1; r.y = (A1.y + B1.y) * sc1;
    *(float2*)&out[(size_t)(j0 + 1) * D_ + 2 * lane] = r;
    r.x = (A2.x + B2.x) * sc2; r.y = (A2.y + B2.y) * sc2;
    *(float2*)&out[(size_t)(j0 + 2) * D_ + 2 * lane] = r;
    r.x = (A3.x + B3.x) * sc3; r.y = (A3.y + B3.y) * sc3;
    *(float2*)&out[(size_t)(j0 + 3) * D_ + 2 * lane] = r;
}

// ---------- fused 2-layer MLPs, all three in one launch; 128-row tiles ----------
// (EXACT round-0 structure.) base_out != nullptr: ALSO store the pre-scale fp32
// output row (acc+bias for row 0) to base_out[seg*128 + col] -- used by the it=0
// uniform-embedding shortcut (3-block launch + bcast_k).
__global__ __launch_bounds__(256, 2) void mlp3_k(
    const float* __restrict__ l_cur, const float* __restrict__ c_cur,
    const unsigned short* __restrict__ wt_hi, const unsigned short* __restrict__ wt_lo,
    const float* __restrict__ bb,
    const float* __restrict__ invsq_l, const float* __restrict__ invsq_c,
    bf16* __restrict__ l_msg, bf16* __restrict__ c_msg, bf16* __restrict__ l2lb,
    int nL, int nC, float* __restrict__ base_out) {
    __shared__ char smem[66048];
    unsigned short (*a_hi)[40] = (unsigned short(*)[40])(smem);
    unsigned short (*a_lo)[40] = (unsigned short(*)[40])(smem + 10240);
    unsigned short (*b_hi)[40] = (unsigned short(*)[40])(smem + 20480);
    unsigned short (*b_lo)[40] = (unsigned short(*)[40])(smem + 30720);
    unsigned short* h_hi = (unsigned short*)(smem);          // phase 2 aliases tiles
    unsigned short* h_lo = (unsigned short*)(smem + 32768);
    float* scv = (float*)(smem + 65536);                     // 128 floats, non-aliased

    int b = blockIdx.x, seg, tile;
    if (b < nL)           { seg = 0; tile = b; }
    else if (b < nL + nC) { seg = 1; tile = b - nL; }
    else                  { seg = 2; tile = b - nL - nC; }
    const float* A = (seg == 1) ? c_cur : l_cur;
    bf16* outp = (seg == 0) ? l_msg : (seg == 1) ? c_msg : l2lb;
    const float* invsq = (seg == 0) ? invsq_l : (seg == 1) ? invsq_c : nullptr;
    const unsigned short* W1h = wt_hi + seg * 32768;
    const unsigned short* W1l = wt_lo + seg * 32768;
    const unsigned short* W2h = W1h + 16384;
    const unsigned short* W2l = W1l + 16384;
    const float* b1v = bb + seg * 256;
    const float* b2v = b1v + 128;
    const int swap = (seg == 2);

    const int t = threadIdx.x;
    const int br0 = tile * 128;
    const int w = t >> 6, lane = t & 63;
    const int wr = w >> 1, wc = w & 1;
    const int quad = lane >> 4, cl = lane & 15;

    if (t < 128) scv[t] = invsq ? invsq[br0 + t] : 1.0f;

    f32x4 acc[4][4];
#pragma unroll
    for (int i = 0; i < 4; i++)
#pragma unroll
        for (int j = 0; j < 4; j++) acc[i][j] = (f32x4){0.f, 0.f, 0.f, 0.f};

    // ---- phase 1: h = A @ W1 ----
    for (int kt = 0; kt < 128; kt += 32) {
#pragma unroll
        for (int i = 0; i < 4; i++) {
            int f = t + 256 * i;
            int r = f >> 3, kq = f & 7;
            int gr = br0 + r;
            if (swap) gr ^= 1;
            const float4 v = *(const float4*)&A[(size_t)gr * D_ + kt + 4 * kq];
            unsigned short h0, l0, h1, l1, h2, l2, h3, l3;
            split2(v.x, h0, l0); split2(v.y, h1, l1);
            split2(v.z, h2, l2); split2(v.w, h3, l3);
            *(ushort4*)&a_hi[r][4 * kq] = make_ushort4(h0, h1, h2, h3);
            *(ushort4*)&a_lo[r][4 * kq] = make_ushort4(l0, l1, l2, l3);
            *(ushort4*)&b_hi[r][4 * kq] = *(const ushort4*)&W1h[(size_t)r * 128 + kt + 4 * kq];
            *(ushort4*)&b_lo[r][4 * kq] = *(const ushort4*)&W1l[(size_t)r * 128 + kt + 4 * kq];
        }
        __syncthreads();
        short8 af_h[4], af_l[4];
#pragma unroll
        for (int i = 0; i < 4; i++) {
            int row = 64 * wr + 16 * i + cl;
            af_h[i] = *(const short8*)&a_hi[row][quad * 8];
            af_l[i] = *(const short8*)&a_lo[row][quad * 8];
        }
#pragma unroll
        for (int j = 0; j < 4; j++) {
            int col = 64 * wc + 16 * j + cl;
            short8 bf_h = *(const short8*)&b_hi[col][quad * 8];
            short8 bf_l = *(const short8*)&b_lo[col][quad * 8];
#pragma unroll
            for (int i = 0; i < 4; i++) {
                acc[i][j] = __builtin_amdgcn_mfma_f32_16x16x32_bf16(af_h[i], bf_h, acc[i][j], 0, 0, 0);
                acc[i][j] = __builtin_amdgcn_mfma_f32_16x16x32_bf16(af_h[i], bf_l, acc[i][j], 0, 0, 0);
                acc[i][j] = __builtin_amdgcn_mfma_f32_16x16x32_bf16(af_l[i], bf_h, acc[i][j], 0, 0, 0);
            }
        }
        __syncthreads();
    }
    // h epilogue: bias + relu + split -> swizzled LDS. C/D: col=cl, row=quad*4+reg.
#pragma unroll
    for (int j = 0; j < 4; j++) {
        int col = 64 * wc + 16 * j + cl;
        float bv = b1v[col];
        int g = col >> 3, go = col & 7;
#pragma unroll
        for (int i = 0; i < 4; i++) {
            int rloc = 64 * wr + 16 * i + quad * 4;
#pragma unroll
            for (int rg = 0; rg < 4; rg++) {
                float v = fmaxf(acc[i][j][rg] + bv, 0.0f);
                unsigned short hh, ll;
                split2(v, hh, ll);
                int r = rloc + rg;
                int off = r * 128 + ((g ^ (r & 15)) << 3) + go;
                h_hi[off] = hh;
                h_lo[off] = ll;
            }
        }
    }
    __syncthreads();
    // ---- phase 2: out = (h @ W2 + b2) * scv -> bf16 ----
#pragma unroll
    for (int i = 0; i < 4; i++)
#pragma unroll
        for (int j = 0; j < 4; j++) acc[i][j] = (f32x4){0.f, 0.f, 0.f, 0.f};

    for (int kt = 0; kt < 128; kt += 32) {
        short8 af_h[4], af_l[4];
        int gbase = (kt >> 3) + quad;
#pragma unroll
        for (int i = 0; i < 4; i++) {
            int r = 64 * wr + 16 * i + cl;
            int off = r * 128 + ((gbase ^ cl) << 3);
            af_h[i] = *(const short8*)&h_hi[off];
            af_l[i] = *(const short8*)&h_lo[off];
        }
#pragma unroll
        for (int j = 0; j < 4; j++) {
            int col = 64 * wc + 16 * j + cl;
            const short8 bf_h = *(const short8*)&W2h[(size_t)col * 128 + kt + quad * 8];
            const short8 bf_l = *(const short8*)&W2l[(size_t)col * 128 + kt + quad * 8];
#pragma unroll
            for (int i = 0; i < 4; i++) {
                acc[i][j] = __builtin_amdgcn_mfma_f32_16x16x32_bf16(af_h[i], bf_h, acc[i][j], 0, 0, 0);
                acc[i][j] = __builtin_amdgcn_mfma_f32_16x16x32_bf16(af_h[i], bf_l, acc[i][j], 0, 0, 0);
                acc[i][j] = __builtin_amdgcn_mfma_f32_16x16x32_bf16(af_l[i], bf_h, acc[i][j], 0, 0, 0);
            }
        }
    }
#pragma unroll
    for (int j = 0; j < 4; j++) {
        int col = 64 * wc + 16 * j + cl;
        float bv = b2v[col];
        if (base_out && w < 2 && lane < 16)
            base_out[seg * 128 + col] = acc[0][j][0] + bv;   // row 0, pre-scale fp32
#pragma unroll
        for (int i = 0; i < 4; i++) {
            int rloc = 64 * wr + 16 * i + quad * 4;
#pragma unroll
            for (int rg = 0; rg < 4; rg++)
                outp[(size_t)(br0 + rloc + rg) * D_ + col] =
                    __float2bfloat16((acc[i][j][rg] + bv) * scv[rloc + rg]);
        }
    }
}

// ---------- fused update GEMMs; 128-row tiles (EXACT round-0 structure) ----------
template <int FINAL>
__global__ __launch_bounds__(256, 2) void update_k(
    const float* __restrict__ l_cur, const float* __restrict__ c_cur,
    const float* __restrict__ laggr, const float* __restrict__ caggr,
    const bf16* __restrict__ l2lb,
    const unsigned short* __restrict__ wt_hi, const unsigned short* __restrict__ wt_lo,
    const float* __restrict__ bb,
    float* __restrict__ c_nxt, float* __restrict__ l_nxt,
    void* __restrict__ dout, const int* __restrict__ flags) {
    __shared__ unsigned short a_hi[128][40], a_lo[128][40];
    __shared__ unsigned short b_hi[128][40], b_lo[128][40];
    const int t = threadIdx.x;
    int b = blockIdx.x;
    const bool cseg = (!FINAL) && (b < 256);
    const int tile = (FINAL || cseg) ? b : b - 256;
    const int K = cseg ? 256 : 384;
    const float* A0 = cseg ? c_cur : l_cur;
    const float* A1 = cseg ? caggr : laggr;
    const unsigned short* Wh = wt_hi + (cseg ? 98304 : 131072);
    const unsigned short* Wl = wt_lo + (cseg ? 98304 : 131072);
    const float* bias = bb + (cseg ? 768 : 896);
    const int br0 = tile * 128;
    const int w = t >> 6, lane = t & 63;
    const int wr = w >> 1, wc = w & 1;
    const int quad = lane >> 4, cl = lane & 15;

    f32x4 acc[4][4];
#pragma unroll
    for (int i = 0; i < 4; i++)
#pragma unroll
        for (int j = 0; j < 4; j++) acc[i][j] = (f32x4){0.f, 0.f, 0.f, 0.f};

    for (int kt = 0; kt < K; kt += 32) {
        const bool haslo = (kt < 256);
        const int koff = kt & 127;
#pragma unroll
        for (int i = 0; i < 4; i++) {
            int f = t + 256 * i;
            int r = f >> 3, kq = f & 7;
            if (haslo) {
                const float* As = (kt < 128) ? A0 : A1;
                const float4 v = *(const float4*)&As[(size_t)(br0 + r) * D_ + koff + 4 * kq];
                unsigned short h0, l0, h1, l1, h2, l2, h3, l3;
                split2(v.x, h0, l0); split2(v.y, h1, l1);
                split2(v.z, h2, l2); split2(v.w, h3, l3);
                *(ushort4*)&a_hi[r][4 * kq] = make_ushort4(h0, h1, h2, h3);
                *(ushort4*)&a_lo[r][4 * kq] = make_ushort4(l0, l1, l2, l3);
            } else {
                *(ushort4*)&a_hi[r][4 * kq] =
                    *(const ushort4*)&l2lb[(size_t)(br0 + r) * D_ + koff + 4 * kq];
            }
            *(ushort4*)&b_hi[r][4 * kq] = *(const ushort4*)&Wh[(size_t)r * K + kt + 4 * kq];
            *(ushort4*)&b_lo[r][4 * kq] = *(const ushort4*)&Wl[(size_t)r * K + kt + 4 * kq];
        }
        __syncthreads();
        short8 af_h[4], af_l[4];
#pragma unroll
        for (int i = 0; i < 4; i++) {
            int row = 64 * wr + 16 * i + cl;
            af_h[i] = *(const short8*)&a_hi[row][quad * 8];
            if (haslo) af_l[i] = *(const short8*)&a_lo[row][quad * 8];
        }
#pragma unroll
        for (int j = 0; j < 4; j++) {
            int col = 64 * wc + 16 * j + cl;
            short8 bf_h = *(const short8*)&b_hi[col][quad * 8];
            short8 bf_l = *(const short8*)&b_lo[col][quad * 8];
#pragma unroll
            for (int i = 0; i < 4; i++) {
                acc[i][j] = __builtin_amdgcn_mfma_f32_16x16x32_bf16(af_h[i], bf_h, acc[i][j], 0, 0, 0);
                acc[i][j] = __builtin_amdgcn_mfma_f32_16x16x32_bf16(af_h[i], bf_l, acc[i][j], 0, 0, 0);
                if (haslo)
                    acc[i][j] = __builtin_amdgcn_mfma_f32_16x16x32_bf16(af_l[i], bf_h, acc[i][j], 0, 0, 0);
            }
        }
        __syncthreads();
    }
    const int f32out = FINAL ? flags[0] : 1;
#pragma unroll
    for (int j = 0; j < 4; j++) {
        int col = 64 * wc + 16 * j + cl;
        float bv = bias[col];
#pragma unroll
        for (int i = 0; i < 4; i++) {
            int rbase = br0 + 64 * wr + 16 * i + quad * 4;
#pragma unroll
            for (int rg = 0; rg < 4; rg++) {
                float v = acc[i][j][rg] + bv;
                size_t idx = (size_t)(rbase + rg) * D_ + col;
                if (FINAL) {
                    if (f32out) ((float*)dout)[idx] = v;
                    else        ((bf16*)dout)[idx] = __float2bfloat16(v);
                } else {
                    (cseg ? c_nxt : l_nxt)[idx] = v;
                }
            }
        }
    }
}

extern "C" void kernel_launch(void* const* d_in, const int* in_sizes, int n_in,
                              void* d_out, int out_size, void* d_ws, size_t ws_size,
                              hipStream_t stream) {
    const int* li_raw = (const int*)d_in[0];
    const int* ci_raw = (const int*)d_in[1];

    // ---- workspace layout (flags after cdegi -> one zeroing memset) ----
    float* ws = (float*)d_ws;
    float* lbuf0 = ws;                               // L*D
    float* lbuf1 = lbuf0 + (size_t)L_ * D_;          // L*D  (doubles as bf16 l_msg)
    float* l2lb  = lbuf1 + (size_t)L_ * D_;          // L*D  (bf16 l2l messages)
    float* laggr = l2lb + (size_t)L_ * D_;           // L*D
    float* cbuf0 = laggr + (size_t)L_ * D_;          // C*D
    float* cbuf1 = cbuf0 + (size_t)C_ * D_;          // C*D  (doubles as bf16 c_msg)
    float* caggr = cbuf1 + (size_t)C_ * D_;          // C*D
    float* invsq_l = caggr + (size_t)C_ * D_;        // L
    float* invsq_c = invsq_l + L_;                   // C
    float* bb    = invsq_c + C_;                     // 1024 bias floats
    unsigned short* wt_hi = (unsigned short*)(bb + 1024);   // 180224 ushorts
    unsigned short* wt_lo = wt_hi + 180224;                 // 180224 ushorts
    int*   li    = (int*)(wt_lo + 180224);           // E
    int*   ci    = li + E_;                          // E
    int*   l_other = ci + E_;                        // E
    int*   c_other = l_other + E_;                   // E
    int*   ldegi = c_other + E_;                     // L
    int*   cdegi = ldegi + L_;                       // C
    int*   flags = cdegi + C_;                       // 2  (contiguous with deg arrays)
    int*   lptr  = flags + 2;                        // L
    int*   cptr  = lptr + L_;                        // C
    int*   lcur  = cptr + C_;                        // L
    int*   ccur  = lcur + L_;                        // C
    int*   bsumL = ccur + C_;                        // 256
    int*   bsumC = bsumL + 256;                      // 128
    float* baseb = (float*)(bsumC + 128);            // 384 fp32 (it=0 MLP base rows)

    // --- one memset zeroes degrees + flags; then dtype detection ---
    hipMemsetAsync(ldegi, 0, ((size_t)(L_ + C_) + 2) * sizeof(int), stream);
    detect_k<<<16, 512, 0, stream>>>((const unsigned short*)d_in[4], li_raw, flags);

    // --- fused preamble: fixdeg + weight-split + embedding-init (one launch) ---
    prep_k<<<15044, 256, 0, stream>>>(
        li_raw, ci_raw, li, ci, ldegi, cdegi,
        d_in[4], d_in[6], d_in[8], d_in[10], d_in[12], d_in[14], d_in[16], d_in[18],
        d_in[5], d_in[7], d_in[9], d_in[11], d_in[13], d_in[15], d_in[17], d_in[19],
        wt_hi, wt_lo, bb,
        d_in[2], d_in[3], lbuf0, cbuf0, flags);

    // --- CSR build ---
    scan1b_k<<<384, 256, 0, stream>>>(ldegi, cdegi, lptr, cptr, bsumL, bsumC);
    scan3b_k<<<384, 256, 0, stream>>>(lptr, cptr, bsumL, bsumC, lcur, ccur,
                                      ldegi, cdegi, invsq_l, invsq_c);
    place_k<<<E_ / 256, 256, 0, stream>>>(li, ci, lcur, ccur, l_other, c_other);

    float* l_cur = lbuf0; float* l_nxt = lbuf1;
    float* c_cur = cbuf0; float* c_nxt = cbuf1;

    const int nL = L_ / 128, nC = C_ / 128;

    // ---- it=0: embeddings are row-uniform -> 3-block mlp3 captures the fp32
    //      base rows; bcast_k writes all messages (bitwise identical) ----
    mlp3_k<<<3, 256, 0, stream>>>(
        l_cur, c_cur, wt_hi, wt_lo, bb, invsq_l, invsq_c,
        (bf16*)l_nxt, (bf16*)c_nxt, (bf16*)l2lb, 1, 1, baseb);
    bcast_k<<<(2 * L_ + C_) * 16 / 256, 256, 0, stream>>>(
        baseb, invsq_l, invsq_c,
        (bf16*)l_nxt, (bf16*)c_nxt, (bf16*)l2lb);
    gather2_k<<<(C_ + L_) / 16, 256, 0, stream>>>(
        cptr, cdegi, c_other, (const unsigned int*)l_nxt, invsq_c, caggr,
        lptr, ldegi, l_other, (const unsigned int*)c_nxt, invsq_l, laggr, C_);
    update_k<0><<<768, 256, 0, stream>>>(
        l_cur, c_cur, laggr, caggr, (const bf16*)l2lb, wt_hi, wt_lo, bb,
        c_nxt, l_nxt, nullptr, flags);
    { float* tmp = l_cur; l_cur = l_nxt; l_nxt = tmp;
      tmp = c_cur; c_cur = c_nxt; c_nxt = tmp; }

    // ---- it=1,2: full pipeline ----
    for (int it = 1; it < 3; it++) {
        mlp3_k<<<2 * nL + nC, 256, 0, stream>>>(
            l_cur, c_cur, wt_hi, wt_lo, bb, invsq_l, invsq_c,
            (bf16*)l_nxt, (bf16*)c_nxt, (bf16*)l2lb, nL, nC, nullptr);
        gather2_k<<<(C_ + L_) / 16, 256, 0, stream>>>(
            cptr, cdegi, c_other, (const unsigned int*)l_nxt, invsq_c, caggr,
            lptr, ldegi, l_other, (const unsigned int*)c_nxt, invsq_l, laggr, C_);
        update_k<0><<<768, 256, 0, stream>>>(
            l_cur, c_cur, laggr, caggr, (const bf16*)l2lb, wt_hi, wt_lo, bb,
            c_nxt, l_nxt, nullptr, flags);
        float* tmp = l_cur; l_cur = l_nxt; l_nxt = tmp;
        tmp = c_cur; c_cur = c_nxt; c_nxt = tmp;
    }
    // --- final iteration: c-update dead -> skip l2c MLP, c-gather, c-update;
    //     fuse output dtype conversion into the l-update epilogue ---
    mlp3_k<<<nC + nL, 256, 0, stream>>>(
        l_cur, c_cur, wt_hi, wt_lo, bb, invsq_l, invsq_c,
        (bf16*)l_nxt, (bf16*)c_nxt, (bf16*)l2lb, 0, nC, nullptr);
    gather2_k<<<L_ / 16, 256, 0, stream>>>(
        cptr, cdegi, c_other, (const unsigned int*)l_nxt, invsq_c, caggr,
        lptr, ldegi, l_other, (const unsigned int*)c_nxt, invsq_l, laggr, 0);
    update_k<1><<<512, 256, 0, stream>>>(
        l_cur, c_cur, laggr, caggr, (const bf16*)l2lb, wt_hi, wt_lo, bb,
        nullptr, nullptr, d_out, flags);
}

// Round 12
// 626.001 us; speedup vs baseline: 1.8294x; 1.0126x over previous
//
#include <hip/hip_runtime.h>
#include <hip/hip_bf16.h>

#define D_ 128
#define L_ 65536
#define C_ 32768
#define E_ 262144

typedef __hip_bfloat16 bf16;
typedef __attribute__((ext_vector_type(8))) short short8;
typedef __attribute__((ext_vector_type(4))) float f32x4;

// flags[0] = 1 if float inputs are fp32 (else bf16); flags[1] = 1 if edge idx int32 (else int64)
__global__ void detect_k(const unsigned short* __restrict__ wmem,
                         const int* __restrict__ li, int* __restrict__ flags) {
    int t = blockIdx.x * 512 + threadIdx.x;
    if (t < 8192) {
        unsigned short h = wmem[2 * t];
        float v = __bfloat162float(*(const bf16*)&h);
        if (!(fabsf(v) < 0.5f)) atomicOr(&flags[0], 1);
    }
    if (t < 2048) {
        if (li[2 * t + 1] != 0) atomicOr(&flags[1], 1);
    }
}

__device__ __forceinline__ void split2(float v, unsigned short& h, unsigned short& l) {
    bf16 bh = __float2bfloat16(v);
    float fh = __bfloat162float(bh);
    bf16 bl = __float2bfloat16(v - fh);
    h = *(unsigned short*)&bh;
    l = *(unsigned short*)&bl;
}

__device__ __forceinline__ float ldf(const void* s, int i, int isf32) {
    return isf32 ? ((const float*)s)[i] : __bfloat162float(((const bf16*)s)[i]);
}

// ---- fused preamble: fixdeg (2048 blocks) + cvtwb (708) + init2 (12288) ----
__global__ void prep_k(const int* __restrict__ ls, const int* __restrict__ cs,
                       int* __restrict__ ld_idx, int* __restrict__ cd_idx,
                       int* __restrict__ ldeg, int* __restrict__ cdeg,
                       const void* s0, const void* s1, const void* s2, const void* s3,
                       const void* s4, const void* s5, const void* s6, const void* s7,
                       const void* t0, const void* t1, const void* t2, const void* t3,
                       const void* t4, const void* t5, const void* t6, const void* t7,
                       unsigned short* __restrict__ hi, unsigned short* __restrict__ lo,
                       float* __restrict__ bb,
                       const void* __restrict__ lv, const void* __restrict__ cv,
                       float* __restrict__ lemb, float* __restrict__ cemb,
                       const int* __restrict__ flags) {
    const int blk = blockIdx.x;
    const int isf = flags[0];
    if (blk < 2048) {
        int i = blk * 256 + threadIdx.x;
        int is32 = flags[1];
        if (i < E_) {
            int v = is32 ? ls[i] : ls[2 * i];
            v = min(max(v, 0), L_ - 1);
            ld_idx[i] = v;
            atomicAdd(&ldeg[v], 1);
        } else {
            int j = i - E_;
            int v = is32 ? cs[j] : cs[2 * j];
            v = min(max(v, 0), C_ - 1);
            cd_idx[j] = v;
            atomicAdd(&cdeg[v], 1);
        }
        return;
    }
    if (blk < 2756) {
        int i = (blk - 2048) * 256 + threadIdx.x;  // 181248 total
        if (i >= 180224) {
            int j = i - 180224;  // 0..1023
            const void* src;
            switch (j >> 7) {
                case 0: src = t0; break; case 1: src = t1; break;
                case 2: src = t2; break; case 3: src = t3; break;
                case 4: src = t4; break; case 5: src = t5; break;
                case 6: src = t6; break; default: src = t7; break;
            }
            bb[j] = ldf(src, j & 127, isf);
            return;
        }
        const void* src; int K, base;
        if      (i <  16384) { src = s0; K = 128; base = 0; }
        else if (i <  32768) { src = s1; K = 128; base = 16384; }
        else if (i <  49152) { src = s2; K = 128; base = 32768; }
        else if (i <  65536) { src = s3; K = 128; base = 49152; }
        else if (i <  81920) { src = s4; K = 128; base = 65536; }
        else if (i <  98304) { src = s5; K = 128; base = 81920; }
        else if (i < 131072) { src = s6; K = 256; base = 98304; }
        else                 { src = s7; K = 384; base = 131072; }
        int e = i - base;
        int k = e >> 7, n = e & 127;
        float v = ldf(src, e, isf);
        unsigned short h, l;
        split2(v, h, l);
        hi[base + n * K + k] = h;
        lo[base + n * K + k] = l;
        return;
    }
    int i4 = (blk - 2756) * 256 + threadIdx.x;  // float4 id, total (L+C)*32
    const void* src; float* dst; int o;
    if (i4 < L_ * 32) { src = lv; dst = lemb; o = i4; }
    else              { src = cv; dst = cemb; o = i4 - L_ * 32; }
    int j = (o & 31) * 4;
    float4 v;
    v.x = ldf(src, j + 0, isf);
    v.y = ldf(src, j + 1, isf);
    v.z = ldf(src, j + 2, isf);
    v.w = ldf(src, j + 3, isf);
    ((float4*)dst)[o] = v;
}

// --- per-tile exclusive scan (stage 1), both sides fused ---
__global__ void scan1b_k(const int* __restrict__ ldeg, const int* __restrict__ cdeg,
                         int* __restrict__ lout, int* __restrict__ cout,
                         int* __restrict__ bsumL, int* __restrict__ bsumC) {
    __shared__ int s[256];
    const int* in; int* out; int* bs; int tile;
    if (blockIdx.x < 256) { in = ldeg; out = lout; bs = bsumL; tile = blockIdx.x; }
    else                  { in = cdeg; out = cout; bs = bsumC; tile = blockIdx.x - 256; }
    int i = tile * 256 + threadIdx.x;
    int v = in[i];
    s[threadIdx.x] = v;
    __syncthreads();
#pragma unroll
    for (int off = 1; off < 256; off <<= 1) {
        int t = (threadIdx.x >= off) ? s[threadIdx.x - off] : 0;
        __syncthreads();
        s[threadIdx.x] += t;
        __syncthreads();
    }
    out[i] = s[threadIdx.x] - v;
    if (threadIdx.x == 255) bs[tile] = s[255];
}

// stage 2+3 fused: each block redundantly computes its own bsum prefix.
__global__ void scan3b_k(int* __restrict__ lptr, int* __restrict__ cptr,
                         const int* __restrict__ bsumL, const int* __restrict__ bsumC,
                         int* __restrict__ lcur, int* __restrict__ ccur,
                         const int* __restrict__ ldeg, const int* __restrict__ cdeg,
                         float* __restrict__ invsq_l, float* __restrict__ invsq_c) {
    __shared__ int sh[256];
    int b = blockIdx.x, t = threadIdx.x;
    const bool lside = (b < 256);
    const int tile = lside ? b : b - 256;
    const int* bs = lside ? bsumL : bsumC;
    sh[t] = (t < tile) ? bs[t] : 0;
    __syncthreads();
#pragma unroll
    for (int off = 128; off > 0; off >>= 1) {
        if (t < off) sh[t] += sh[t + off];
        __syncthreads();
    }
    const int pref = sh[0];
    int i = tile * 256 + t;
    if (lside) {
        int v = lptr[i] + pref;
        lptr[i] = v; lcur[i] = v;
        int d = ldeg[i];
        invsq_l[i] = d ? rsqrtf((float)d) : 0.0f;
    } else {
        int v = cptr[i] + pref;
        cptr[i] = v; ccur[i] = v;
        int d = cdeg[i];
        invsq_c[i] = d ? rsqrtf((float)d) : 0.0f;
    }
}

// CSR placement (other endpoint only; norm is separable)
__global__ void place_k(const int* __restrict__ li, const int* __restrict__ ci,
                        int* __restrict__ lcur, int* __restrict__ ccur,
                        int* __restrict__ l_other, int* __restrict__ c_other) {
    int e = blockIdx.x * 256 + threadIdx.x;
    if (e >= E_) return;
    int l = li[e], c = ci[e];
    int p = atomicAdd(&ccur[c], 1);
    c_other[p] = l;
    int q = atomicAdd(&lcur[l], 1);
    l_other[q] = c;
}

// it=0 message broadcast: embeddings are row-uniform at it=0, so messages are
// bf16(base[col] * invsq[row]) -- bitwise identical to the full mlp3 path.
__global__ void bcast_k(const float* __restrict__ baseb,
                        const float* __restrict__ invsq_l, const float* __restrict__ invsq_c,
                        bf16* __restrict__ l_msg, bf16* __restrict__ c_msg,
                        bf16* __restrict__ l2lb) {
    int id = blockIdx.x * 256 + threadIdx.x;   // each id writes 8 bf16 (16B)
    const int LCH = L_ * 16;
    const int CCH = C_ * 16;
    const float* base; bf16* out; int row, c8; float sc;
    if (id < LCH)            { base = baseb;       out = l_msg; row = id >> 4;
                               c8 = (id & 15) * 8; sc = invsq_l[row]; }
    else if (id < LCH + CCH) { int k = id - LCH;   base = baseb + 128; out = c_msg;
                               row = k >> 4; c8 = (k & 15) * 8; sc = invsq_c[row]; }
    else                     { int k = id - LCH - CCH; base = baseb + 256; out = l2lb;
                               row = k >> 4; c8 = (k & 15) * 8; sc = 1.0f; }
    union { short8 v; unsigned short u[8]; } o;
#pragma unroll
    for (int k = 0; k < 8; k++) {
        bf16 b = __float2bfloat16(base[c8 + k] * sc);
        o.u[k] = *(unsigned short*)&b;
    }
    *(short8*)&out[(size_t)row * D_ + c8] = o.v;
}

// it=0 uniform-range constants for update: runs the EXACT update_k staging+MFMA
// sequence on tile 0 for the row-uniform K ranges and stores row 0's acc.
// block 0: c-seg emb part (kt 0..127, K=256)      -> uc[0..127]
// block 1: l-seg emb part (kt 0..127, K=384)      -> uc[128..255]
//          l-seg l2l part (kt 256..383, from zero) -> uc[256..383]
__global__ __launch_bounds__(256, 2) void uconst_k(
    const float* __restrict__ l_cur, const float* __restrict__ c_cur,
    const bf16* __restrict__ l2lb,
    const unsigned short* __restrict__ wt_hi, const unsigned short* __restrict__ wt_lo,
    float* __restrict__ uc) {
    __shared__ unsigned short a_hi[128][40], a_lo[128][40];
    __shared__ unsigned short b_hi[128][40], b_lo[128][40];
    const int t = threadIdx.x;
    const bool cseg = (blockIdx.x == 0);
    const int K = cseg ? 256 : 384;
    const float* A0 = cseg ? c_cur : l_cur;
    const unsigned short* Wh = wt_hi + (cseg ? 98304 : 131072);
    const unsigned short* Wl = wt_lo + (cseg ? 98304 : 131072);
    const int w = t >> 6, lane = t & 63;
    const int wr = w >> 1, wc = w & 1;
    const int quad = lane >> 4, cl = lane & 15;

    f32x4 acc[4][4];
#pragma unroll
    for (int i = 0; i < 4; i++)
#pragma unroll
        for (int j = 0; j < 4; j++) acc[i][j] = (f32x4){0.f, 0.f, 0.f, 0.f};

    // pass 1: emb tiles kt=0..127 (identical op sequence to update_k's first 4 tiles)
    for (int kt = 0; kt < 128; kt += 32) {
#pragma unroll
        for (int i = 0; i < 4; i++) {
            int f = t + 256 * i;
            int r = f >> 3, kq = f & 7;
            const float4 v = *(const float4*)&A0[(size_t)r * D_ + kt + 4 * kq];
            unsigned short h0, l0, h1, l1, h2, l2, h3, l3;
            split2(v.x, h0, l0); split2(v.y, h1, l1);
            split2(v.z, h2, l2); split2(v.w, h3, l3);
            *(ushort4*)&a_hi[r][4 * kq] = make_ushort4(h0, h1, h2, h3);
            *(ushort4*)&a_lo[r][4 * kq] = make_ushort4(l0, l1, l2, l3);
            *(ushort4*)&b_hi[r][4 * kq] = *(const ushort4*)&Wh[(size_t)r * K + kt + 4 * kq];
            *(ushort4*)&b_lo[r][4 * kq] = *(const ushort4*)&Wl[(size_t)r * K + kt + 4 * kq];
        }
        __syncthreads();
        short8 af_h[4], af_l[4];
#pragma unroll
        for (int i = 0; i < 4; i++) {
            int row = 64 * wr + 16 * i + cl;
            af_h[i] = *(const short8*)&a_hi[row][quad * 8];
            af_l[i] = *(const short8*)&a_lo[row][quad * 8];
        }
#pragma unroll
        for (int j = 0; j < 4; j++) {
            int col = 64 * wc + 16 * j + cl;
            short8 bf_h = *(const short8*)&b_hi[col][quad * 8];
            short8 bf_l = *(const short8*)&b_lo[col][quad * 8];
#pragma unroll
            for (int i = 0; i < 4; i++) {
                acc[i][j] = __builtin_amdgcn_mfma_f32_16x16x32_bf16(af_h[i], bf_h, acc[i][j], 0, 0, 0);
                acc[i][j] = __builtin_amdgcn_mfma_f32_16x16x32_bf16(af_h[i], bf_l, acc[i][j], 0, 0, 0);
                acc[i][j] = __builtin_amdgcn_mfma_f32_16x16x32_bf16(af_l[i], bf_h, acc[i][j], 0, 0, 0);
            }
        }
        __syncthreads();
    }
#pragma unroll
    for (int j = 0; j < 4; j++) {
        int col = 64 * wc + 16 * j + cl;
        if (w < 2 && lane < 16) uc[(cseg ? 0 : 128) + col] = acc[0][j][0];
    }
    if (cseg) return;

    // pass 2: l2l tiles kt=256..383 accumulated from zero (bf16 hi-plane only)
#pragma unroll
    for (int i = 0; i < 4; i++)
#pragma unroll
        for (int j = 0; j < 4; j++) acc[i][j] = (f32x4){0.f, 0.f, 0.f, 0.f};
    for (int kt = 256; kt < 384; kt += 32) {
        const int koff = kt & 127;
#pragma unroll
        for (int i = 0; i < 4; i++) {
            int f = t + 256 * i;
            int r = f >> 3, kq = f & 7;
            *(ushort4*)&a_hi[r][4 * kq] =
                *(const ushort4*)&l2lb[(size_t)r * D_ + koff + 4 * kq];
            *(ushort4*)&b_hi[r][4 * kq] = *(const ushort4*)&Wh[(size_t)r * K + kt + 4 * kq];
            *(ushort4*)&b_lo[r][4 * kq] = *(const ushort4*)&Wl[(size_t)r * K + kt + 4 * kq];
        }
        __syncthreads();
        short8 af_h[4];
#pragma unroll
        for (int i = 0; i < 4; i++) {
            int row = 64 * wr + 16 * i + cl;
            af_h[i] = *(const short8*)&a_hi[row][quad * 8];
        }
#pragma unroll
        for (int j = 0; j < 4; j++) {
            int col = 64 * wc + 16 * j + cl;
            short8 bf_h = *(const short8*)&b_hi[col][quad * 8];
            short8 bf_l = *(const short8*)&b_lo[col][quad * 8];
#pragma unroll
            for (int i = 0; i < 4; i++) {
                acc[i][j] = __builtin_amdgcn_mfma_f32_16x16x32_bf16(af_h[i], bf_h, acc[i][j], 0, 0, 0);
                acc[i][j] = __builtin_amdgcn_mfma_f32_16x16x32_bf16(af_h[i], bf_l, acc[i][j], 0, 0, 0);
            }
        }
        __syncthreads();
    }
#pragma unroll
    for (int j = 0; j < 4; j++) {
        int col = 64 * wc + 16 * j + cl;
        if (w < 2 && lane < 16) uc[256 + col] = acc[0][j][0];
    }
}

// it=0 update: acc initialized from the uniform-range constants; only the 4
// aggregate K-tiles (kt 128..255) are staged+MFMA'd. c-path is bitwise identical
// to the full update_k; l-path adds the l2l sub-sum as one fp32 add (~ulp).
__global__ __launch_bounds__(256, 2) void update0_k(
    const float* __restrict__ laggr, const float* __restrict__ caggr,
    const unsigned short* __restrict__ wt_hi, const unsigned short* __restrict__ wt_lo,
    const float* __restrict__ bb, const float* __restrict__ uc,
    float* __restrict__ c_nxt, float* __restrict__ l_nxt) {
    __shared__ unsigned short a_hi[128][40], a_lo[128][40];
    __shared__ unsigned short b_hi[128][40], b_lo[128][40];
    const int t = threadIdx.x;
    int b = blockIdx.x;
    const bool cseg = (b < 256);
    const int tile = cseg ? b : b - 256;
    const int K = cseg ? 256 : 384;
    const float* A1 = cseg ? caggr : laggr;
    const unsigned short* Wh = wt_hi + (cseg ? 98304 : 131072);
    const unsigned short* Wl = wt_lo + (cseg ? 98304 : 131072);
    const float* bias = bb + (cseg ? 768 : 896);
    const float* uc0 = uc + (cseg ? 0 : 128);
    const int br0 = tile * 128;
    const int w = t >> 6, lane = t & 63;
    const int wr = w >> 1, wc = w & 1;
    const int quad = lane >> 4, cl = lane & 15;

    f32x4 acc[4][4];
#pragma unroll
    for (int j = 0; j < 4; j++) {
        int col = 64 * wc + 16 * j + cl;
        float cv = uc0[col];
#pragma unroll
        for (int i = 0; i < 4; i++) acc[i][j] = (f32x4){cv, cv, cv, cv};
    }

    for (int kt = 128; kt < 256; kt += 32) {
        const int koff = kt & 127;
#pragma unroll
        for (int i = 0; i < 4; i++) {
            int f = t + 256 * i;
            int r = f >> 3, kq = f & 7;
            const float4 v = *(const float4*)&A1[(size_t)(br0 + r) * D_ + koff + 4 * kq];
            unsigned short h0, l0, h1, l1, h2, l2, h3, l3;
            split2(v.x, h0, l0); split2(v.y, h1, l1);
            split2(v.z, h2, l2); split2(v.w, h3, l3);
            *(ushort4*)&a_hi[r][4 * kq] = make_ushort4(h0, h1, h2, h3);
            *(ushort4*)&a_lo[r][4 * kq] = make_ushort4(l0, l1, l2, l3);
            *(ushort4*)&b_hi[r][4 * kq] = *(const ushort4*)&Wh[(size_t)r * K + kt + 4 * kq];
            *(ushort4*)&b_lo[r][4 * kq] = *(const ushort4*)&Wl[(size_t)r * K + kt + 4 * kq];
        }
        __syncthreads();
        short8 af_h[4], af_l[4];
#pragma unroll
        for (int i = 0; i < 4; i++) {
            int row = 64 * wr + 16 * i + cl;
            af_h[i] = *(const short8*)&a_hi[row][quad * 8];
            af_l[i] = *(const short8*)&a_lo[row][quad * 8];
        }
#pragma unroll
        for (int j = 0; j < 4; j++) {
            int col = 64 * wc + 16 * j + cl;
            short8 bf_h = *(const short8*)&b_hi[col][quad * 8];
            short8 bf_l = *(const short8*)&b_lo[col][quad * 8];
#pragma unroll
            for (int i = 0; i < 4; i++) {
                acc[i][j] = __builtin_amdgcn_mfma_f32_16x16x32_bf16(af_h[i], bf_h, acc[i][j], 0, 0, 0);
                acc[i][j] = __builtin_amdgcn_mfma_f32_16x16x32_bf16(af_h[i], bf_l, acc[i][j], 0, 0, 0);
                acc[i][j] = __builtin_amdgcn_mfma_f32_16x16x32_bf16(af_l[i], bf_h, acc[i][j], 0, 0, 0);
            }
        }
        __syncthreads();
    }
    float* outp = cseg ? c_nxt : l_nxt;
#pragma unroll
    for (int j = 0; j < 4; j++) {
        int col = 64 * wc + 16 * j + cl;
        float bv = bias[col];
        float l2lc = cseg ? 0.0f : uc[256 + col];
#pragma unroll
        for (int i = 0; i < 4; i++) {
            int rbase = br0 + 64 * wr + 16 * i + quad * 4;
#pragma unroll
            for (int rg = 0; rg < 4; rg++) {
                float v = (acc[i][j][rg] + l2lc) + bv;
                outp[(size_t)(rbase + rg) * D_ + col] = v;
            }
        }
    }
}

// Fused pull-aggregation, both directions (r9 4-node/2-deep structure, kept).
__global__ __launch_bounds__(256) void gather2_k(
    const int* __restrict__ cptr, const int* __restrict__ cdeg, const int* __restrict__ c_other,
    const unsigned int* __restrict__ lmsg, const float* __restrict__ invsq_c, float* __restrict__ caggr,
    const int* __restrict__ lptr, const int* __restrict__ ldeg, const int* __restrict__ l_other,
    const unsigned int* __restrict__ cmsg, const float* __restrict__ invsq_l, float* __restrict__ laggr,
    int nC) {
    int wid = (blockIdx.x * 256 + threadIdx.x) >> 6;
    int lane = threadIdx.x & 63;
    int n0 = 4 * wid;
    bool cside = n0 < nC;
    int j0 = cside ? n0 : n0 - nC;
    const int* ptr = cside ? cptr : lptr;
    const int* dg  = cside ? cdeg : ldeg;
    const int* oth = cside ? c_other : l_other;
    const unsigned int* msg = cside ? lmsg : cmsg;
    const float* invsq = cside ? invsq_c : invsq_l;
    float* out = cside ? caggr : laggr;

    int s0 = ptr[j0],     c0 = dg[j0];
    int s1 = ptr[j0 + 1], c1 = dg[j0 + 1];
    int s2 = ptr[j0 + 2], c2 = dg[j0 + 2];
    int s3 = ptr[j0 + 3], c3 = dg[j0 + 3];
    float2 A0 = {0.f, 0.f}, B0 = {0.f, 0.f};
    float2 A1 = {0.f, 0.f}, B1 = {0.f, 0.f};
    float2 A2 = {0.f, 0.f}, B2 = {0.f, 0.f};
    float2 A3 = {0.f, 0.f}, B3 = {0.f, 0.f};
    int k0 = 0, k1 = 0, k2 = 0, k3 = 0;

#define GLD_(s, k) msg[(size_t)oth[(s) + (k)] * 64 + lane]
#define GACC_(a, u) { (a).x += __uint_as_float((u) << 16); \
                      (a).y += __uint_as_float((u) & 0xffff0000u); }

    for (; k0 + 2 <= c0 && k1 + 2 <= c1 && k2 + 2 <= c2 && k3 + 2 <= c3;
         k0 += 2, k1 += 2, k2 += 2, k3 += 2) {
        unsigned int u00 = GLD_(s0, k0), u01 = GLD_(s0, k0 + 1);
        unsigned int u10 = GLD_(s1, k1), u11 = GLD_(s1, k1 + 1);
        unsigned int u20 = GLD_(s2, k2), u21 = GLD_(s2, k2 + 1);
        unsigned int u30 = GLD_(s3, k3), u31 = GLD_(s3, k3 + 1);
        GACC_(A0, u00); GACC_(B0, u01);
        GACC_(A1, u10); GACC_(B1, u11);
        GACC_(A2, u20); GACC_(B2, u21);
        GACC_(A3, u30); GACC_(B3, u31);
    }
    for (; k0 + 2 <= c0 && k1 + 2 <= c1; k0 += 2, k1 += 2) {
        unsigned int u00 = GLD_(s0, k0), u01 = GLD_(s0, k0 + 1);
        unsigned int u10 = GLD_(s1, k1), u11 = GLD_(s1, k1 + 1);
        GACC_(A0, u00); GACC_(B0, u01);
        GACC_(A1, u10); GACC_(B1, u11);
    }
    for (; k2 + 2 <= c2 && k3 + 2 <= c3; k2 += 2, k3 += 2) {
        unsigned int u20 = GLD_(s2, k2), u21 = GLD_(s2, k2 + 1);
        unsigned int u30 = GLD_(s3, k3), u31 = GLD_(s3, k3 + 1);
        GACC_(A2, u20); GACC_(B2, u21);
        GACC_(A3, u30); GACC_(B3, u31);
    }
    for (; k0 + 2 <= c0; k0 += 2) {
        unsigned int ua = GLD_(s0, k0), ub = GLD_(s0, k0 + 1);
        GACC_(A0, ua); GACC_(B0, ub);
    }
    for (; k1 + 2 <= c1; k1 += 2) {
        unsigned int ua = GLD_(s1, k1), ub = GLD_(s1, k1 + 1);
        GACC_(A1, ua); GACC_(B1, ub);
    }
    for (; k2 + 2 <= c2; k2 += 2) {
        unsigned int ua = GLD_(s2, k2), ub = GLD_(s2, k2 + 1);
        GACC_(A2, ua); GACC_(B2, ub);
    }
    for (; k3 + 2 <= c3; k3 += 2) {
        unsigned int ua = GLD_(s3, k3), ub = GLD_(s3, k3 + 1);
        GACC_(A3, ua); GACC_(B3, ub);
    }
    if (k0 < c0) { unsigned int u = GLD_(s0, k0); GACC_(A0, u); }
    if (k1 < c1) { unsigned int u = GLD_(s1, k1); GACC_(A1, u); }
    if (k2 < c2) { unsigned int u = GLD_(s2, k2); GACC_(A2, u); }
    if (k3 < c3) { unsigned int u = GLD_(s3, k3); GACC_(A3, u); }
#undef GLD_
#undef GACC_

    float sc0 = invsq[j0], sc1 = invsq[j0 + 1];
    float sc2 = invsq[j0 + 2], sc3 = invsq[j0 + 3];
    float2 r;
    r.x = (A0.x + B0.x) * sc0; r.y = (A0.y + B0.y) * sc0;
    *(float2*)&out[(size_t)j0 * D_ + 2 * lane] = r;
    r.x = (A1.x + B1.x) * sc1; r.y = (A1.y + B1.y) * sc1;
    *(float2*)&out[(size_t)(j0 + 1) * D_ + 2 * lane] = r;
    r.x = (A2.x + B2.x) * sc2; r.y = (A2.y + B2.y) * sc2;
    *(float2*)&out[(size_t)(j0 + 2) * D_ + 2 * lane] = r;
    r.x = (A3.x + B3.x) * sc3; r.y = (A3.y + B3.y) * sc3;
    *(float2*)&out[(size_t)(j0 + 3) * D_ + 2 * lane] = r;
}

// ---------- fused 2-layer MLPs, all three in one launch; 128-row tiles ----------
// (EXACT round-0 structure.) base_out != nullptr: ALSO store the pre-scale fp32
// output row (acc+bias for row 0) to base_out[seg*128 + col].
__global__ __launch_bounds__(256, 2) void mlp3_k(
    const float* __restrict__ l_cur, const float* __restrict__ c_cur,
    const unsigned short* __restrict__ wt_hi, const unsigned short* __restrict__ wt_lo,
    const float* __restrict__ bb,
    const float* __restrict__ invsq_l, const float* __restrict__ invsq_c,
    bf16* __restrict__ l_msg, bf16* __restrict__ c_msg, bf16* __restrict__ l2lb,
    int nL, int nC, float* __restrict__ base_out) {
    __shared__ char smem[66048];
    unsigned short (*a_hi)[40] = (unsigned short(*)[40])(smem);
    unsigned short (*a_lo)[40] = (unsigned short(*)[40])(smem + 10240);
    unsigned short (*b_hi)[40] = (unsigned short(*)[40])(smem + 20480);
    unsigned short (*b_lo)[40] = (unsigned short(*)[40])(smem + 30720);
    unsigned short* h_hi = (unsigned short*)(smem);          // phase 2 aliases tiles
    unsigned short* h_lo = (unsigned short*)(smem + 32768);
    float* scv = (float*)(smem + 65536);                     // 128 floats, non-aliased

    int b = blockIdx.x, seg, tile;
    if (b < nL)           { seg = 0; tile = b; }
    else if (b < nL + nC) { seg = 1; tile = b - nL; }
    else                  { seg = 2; tile = b - nL - nC; }
    const float* A = (seg == 1) ? c_cur : l_cur;
    bf16* outp = (seg == 0) ? l_msg : (seg == 1) ? c_msg : l2lb;
    const float* invsq = (seg == 0) ? invsq_l : (seg == 1) ? invsq_c : nullptr;
    const unsigned short* W1h = wt_hi + seg * 32768;
    const unsigned short* W1l = wt_lo + seg * 32768;
    const unsigned short* W2h = W1h + 16384;
    const unsigned short* W2l = W1l + 16384;
    const float* b1v = bb + seg * 256;
    const float* b2v = b1v + 128;
    const int swap = (seg == 2);

    const int t = threadIdx.x;
    const int br0 = tile * 128;
    const int w = t >> 6, lane = t & 63;
    const int wr = w >> 1, wc = w & 1;
    const int quad = lane >> 4, cl = lane & 15;

    if (t < 128) scv[t] = invsq ? invsq[br0 + t] : 1.0f;

    f32x4 acc[4][4];
#pragma unroll
    for (int i = 0; i < 4; i++)
#pragma unroll
        for (int j = 0; j < 4; j++) acc[i][j] = (f32x4){0.f, 0.f, 0.f, 0.f};

    // ---- phase 1: h = A @ W1 ----
    for (int kt = 0; kt < 128; kt += 32) {
#pragma unroll
        for (int i = 0; i < 4; i++) {
            int f = t + 256 * i;
            int r = f >> 3, kq = f & 7;
            int gr = br0 + r;
            if (swap) gr ^= 1;
            const float4 v = *(const float4*)&A[(size_t)gr * D_ + kt + 4 * kq];
            unsigned short h0, l0, h1, l1, h2, l2, h3, l3;
            split2(v.x, h0, l0); split2(v.y, h1, l1);
            split2(v.z, h2, l2); split2(v.w, h3, l3);
            *(ushort4*)&a_hi[r][4 * kq] = make_ushort4(h0, h1, h2, h3);
            *(ushort4*)&a_lo[r][4 * kq] = make_ushort4(l0, l1, l2, l3);
            *(ushort4*)&b_hi[r][4 * kq] = *(const ushort4*)&W1h[(size_t)r * 128 + kt + 4 * kq];
            *(ushort4*)&b_lo[r][4 * kq] = *(const ushort4*)&W1l[(size_t)r * 128 + kt + 4 * kq];
        }
        __syncthreads();
        short8 af_h[4], af_l[4];
#pragma unroll
        for (int i = 0; i < 4; i++) {
            int row = 64 * wr + 16 * i + cl;
            af_h[i] = *(const short8*)&a_hi[row][quad * 8];
            af_l[i] = *(const short8*)&a_lo[row][quad * 8];
        }
#pragma unroll
        for (int j = 0; j < 4; j++) {
            int col = 64 * wc + 16 * j + cl;
            short8 bf_h = *(const short8*)&b_hi[col][quad * 8];
            short8 bf_l = *(const short8*)&b_lo[col][quad * 8];
#pragma unroll
            for (int i = 0; i < 4; i++) {
                acc[i][j] = __builtin_amdgcn_mfma_f32_16x16x32_bf16(af_h[i], bf_h, acc[i][j], 0, 0, 0);
                acc[i][j] = __builtin_amdgcn_mfma_f32_16x16x32_bf16(af_h[i], bf_l, acc[i][j], 0, 0, 0);
                acc[i][j] = __builtin_amdgcn_mfma_f32_16x16x32_bf16(af_l[i], bf_h, acc[i][j], 0, 0, 0);
            }
        }
        __syncthreads();
    }
    // h epilogue: bias + relu + split -> swizzled LDS. C/D: col=cl, row=quad*4+reg.
#pragma unroll
    for (int j = 0; j < 4; j++) {
        int col = 64 * wc + 16 * j + cl;
        float bv = b1v[col];
        int g = col >> 3, go = col & 7;
#pragma unroll
        for (int i = 0; i < 4; i++) {
            int rloc = 64 * wr + 16 * i + quad * 4;
#pragma unroll
            for (int rg = 0; rg < 4; rg++) {
                float v = fmaxf(acc[i][j][rg] + bv, 0.0f);
                unsigned short hh, ll;
                split2(v, hh, ll);
                int r = rloc + rg;
                int off = r * 128 + ((g ^ (r & 15)) << 3) + go;
                h_hi[off] = hh;
                h_lo[off] = ll;
            }
        }
    }
    __syncthreads();
    // ---- phase 2: out = (h @ W2 + b2) * scv -> bf16 ----
#pragma unroll
    for (int i = 0; i < 4; i++)
#pragma unroll
        for (int j = 0; j < 4; j++) acc[i][j] = (f32x4){0.f, 0.f, 0.f, 0.f};

    for (int kt = 0; kt < 128; kt += 32) {
        short8 af_h[4], af_l[4];
        int gbase = (kt >> 3) + quad;
#pragma unroll
        for (int i = 0; i < 4; i++) {
            int r = 64 * wr + 16 * i + cl;
            int off = r * 128 + ((gbase ^ cl) << 3);
            af_h[i] = *(const short8*)&h_hi[off];
            af_l[i] = *(const short8*)&h_lo[off];
        }
#pragma unroll
        for (int j = 0; j < 4; j++) {
            int col = 64 * wc + 16 * j + cl;
            const short8 bf_h = *(const short8*)&W2h[(size_t)col * 128 + kt + quad * 8];
            const short8 bf_l = *(const short8*)&W2l[(size_t)col * 128 + kt + quad * 8];
#pragma unroll
            for (int i = 0; i < 4; i++) {
                acc[i][j] = __builtin_amdgcn_mfma_f32_16x16x32_bf16(af_h[i], bf_h, acc[i][j], 0, 0, 0);
                acc[i][j] = __builtin_amdgcn_mfma_f32_16x16x32_bf16(af_h[i], bf_l, acc[i][j], 0, 0, 0);
                acc[i][j] = __builtin_amdgcn_mfma_f32_16x16x32_bf16(af_l[i], bf_h, acc[i][j], 0, 0, 0);
            }
        }
    }
#pragma unroll
    for (int j = 0; j < 4; j++) {
        int col = 64 * wc + 16 * j + cl;
        float bv = b2v[col];
        if (base_out && w < 2 && lane < 16)
            base_out[seg * 128 + col] = acc[0][j][0] + bv;   // row 0, pre-scale fp32
#pragma unroll
        for (int i = 0; i < 4; i++) {
            int rloc = 64 * wr + 16 * i + quad * 4;
#pragma unroll
            for (int rg = 0; rg < 4; rg++)
                outp[(size_t)(br0 + rloc + rg) * D_ + col] =
                    __float2bfloat16((acc[i][j][rg] + bv) * scv[rloc + rg]);
        }
    }
}

// ---------- fused update GEMMs; 128-row tiles (EXACT round-0 structure) ----------
template <int FINAL>
__global__ __launch_bounds__(256, 2) void update_k(
    const float* __restrict__ l_cur, const float* __restrict__ c_cur,
    const float* __restrict__ laggr, const float* __restrict__ caggr,
    const bf16* __restrict__ l2lb,
    const unsigned short* __restrict__ wt_hi, const unsigned short* __restrict__ wt_lo,
    const float* __restrict__ bb,
    float* __restrict__ c_nxt, float* __restrict__ l_nxt,
    void* __restrict__ dout, const int* __restrict__ flags) {
    __shared__ unsigned short a_hi[128][40], a_lo[128][40];
    __shared__ unsigned short b_hi[128][40], b_lo[128][40];
    const int t = threadIdx.x;
    int b = blockIdx.x;
    const bool cseg = (!FINAL) && (b < 256);
    const int tile = (FINAL || cseg) ? b : b - 256;
    const int K = cseg ? 256 : 384;
    const float* A0 = cseg ? c_cur : l_cur;
    const float* A1 = cseg ? caggr : laggr;
    const unsigned short* Wh = wt_hi + (cseg ? 98304 : 131072);
    const unsigned short* Wl = wt_lo + (cseg ? 98304 : 131072);
    const float* bias = bb + (cseg ? 768 : 896);
    const int br0 = tile * 128;
    const int w = t >> 6, lane = t & 63;
    const int wr = w >> 1, wc = w & 1;
    const int quad = lane >> 4, cl = lane & 15;

    f32x4 acc[4][4];
#pragma unroll
    for (int i = 0; i < 4; i++)
#pragma unroll
        for (int j = 0; j < 4; j++) acc[i][j] = (f32x4){0.f, 0.f, 0.f, 0.f};

    for (int kt = 0; kt < K; kt += 32) {
        const bool haslo = (kt < 256);
        const int koff = kt & 127;
#pragma unroll
        for (int i = 0; i < 4; i++) {
            int f = t + 256 * i;
            int r = f >> 3, kq = f & 7;
            if (haslo) {
                const float* As = (kt < 128) ? A0 : A1;
                const float4 v = *(const float4*)&As[(size_t)(br0 + r) * D_ + koff + 4 * kq];
                unsigned short h0, l0, h1, l1, h2, l2, h3, l3;
                split2(v.x, h0, l0); split2(v.y, h1, l1);
                split2(v.z, h2, l2); split2(v.w, h3, l3);
                *(ushort4*)&a_hi[r][4 * kq] = make_ushort4(h0, h1, h2, h3);
                *(ushort4*)&a_lo[r][4 * kq] = make_ushort4(l0, l1, l2, l3);
            } else {
                *(ushort4*)&a_hi[r][4 * kq] =
                    *(const ushort4*)&l2lb[(size_t)(br0 + r) * D_ + koff + 4 * kq];
            }
            *(ushort4*)&b_hi[r][4 * kq] = *(const ushort4*)&Wh[(size_t)r * K + kt + 4 * kq];
            *(ushort4*)&b_lo[r][4 * kq] = *(const ushort4*)&Wl[(size_t)r * K + kt + 4 * kq];
        }
        __syncthreads();
        short8 af_h[4], af_l[4];
#pragma unroll
        for (int i = 0; i < 4; i++) {
            int row = 64 * wr + 16 * i + cl;
            af_h[i] = *(const short8*)&a_hi[row][quad * 8];
            if (haslo) af_l[i] = *(const short8*)&a_lo[row][quad * 8];
        }
#pragma unroll
        for (int j = 0; j < 4; j++) {
            int col = 64 * wc + 16 * j + cl;
            short8 bf_h = *(const short8*)&b_hi[col][quad * 8];
            short8 bf_l = *(const short8*)&b_lo[col][quad * 8];
#pragma unroll
            for (int i = 0; i < 4; i++) {
                acc[i][j] = __builtin_amdgcn_mfma_f32_16x16x32_bf16(af_h[i], bf_h, acc[i][j], 0, 0, 0);
                acc[i][j] = __builtin_amdgcn_mfma_f32_16x16x32_bf16(af_h[i], bf_l, acc[i][j], 0, 0, 0);
                if (haslo)
                    acc[i][j] = __builtin_amdgcn_mfma_f32_16x16x32_bf16(af_l[i], bf_h, acc[i][j], 0, 0, 0);
            }
        }
        __syncthreads();
    }
    const int f32out = FINAL ? flags[0] : 1;
#pragma unroll
    for (int j = 0; j < 4; j++) {
        int col = 64 * wc + 16 * j + cl;
        float bv = bias[col];
#pragma unroll
        for (int i = 0; i < 4; i++) {
            int rbase = br0 + 64 * wr + 16 * i + quad * 4;
#pragma unroll
            for (int rg = 0; rg < 4; rg++) {
                float v = acc[i][j][rg] + bv;
                size_t idx = (size_t)(rbase + rg) * D_ + col;
                if (FINAL) {
                    if (f32out) ((float*)dout)[idx] = v;
                    else        ((bf16*)dout)[idx] = __float2bfloat16(v);
                } else {
                    (cseg ? c_nxt : l_nxt)[idx] = v;
                }
            }
        }
    }
}

extern "C" void kernel_launch(void* const* d_in, const int* in_sizes, int n_in,
                              void* d_out, int out_size, void* d_ws, size_t ws_size,
                              hipStream_t stream) {
    const int* li_raw = (const int*)d_in[0];
    const int* ci_raw = (const int*)d_in[1];

    // ---- workspace layout (flags after cdegi -> one zeroing memset) ----
    float* ws = (float*)d_ws;
    float* lbuf0 = ws;                               // L*D
    float* lbuf1 = lbuf0 + (size_t)L_ * D_;          // L*D  (doubles as bf16 l_msg)
    float* l2lb  = lbuf1 + (size_t)L_ * D_;          // L*D  (bf16 l2l messages)
    float* laggr = l2lb + (size_t)L_ * D_;           // L*D
    float* cbuf0 = laggr + (size_t)L_ * D_;          // C*D
    float* cbuf1 = cbuf0 + (size_t)C_ * D_;          // C*D  (doubles as bf16 c_msg)
    float* caggr = cbuf1 + (size_t)C_ * D_;          // C*D
    float* invsq_l = caggr + (size_t)C_ * D_;        // L
    float* invsq_c = invsq_l + L_;                   // C
    float* bb    = invsq_c + C_;                     // 1024 bias floats
    unsigned short* wt_hi = (unsigned short*)(bb + 1024);   // 180224 ushorts
    unsigned short* wt_lo = wt_hi + 180224;                 // 180224 ushorts
    int*   li    = (int*)(wt_lo + 180224);           // E
    int*   ci    = li + E_;                          // E
    int*   l_other = ci + E_;                        // E
    int*   c_other = l_other + E_;                   // E
    int*   ldegi = c_other + E_;                     // L
    int*   cdegi = ldegi + L_;                       // C
    int*   flags = cdegi + C_;                       // 2  (contiguous with deg arrays)
    int*   lptr  = flags + 2;                        // L
    int*   cptr  = lptr + L_;                        // C
    int*   lcur  = cptr + C_;                        // L
    int*   ccur  = lcur + L_;                        // C
    int*   bsumL = ccur + C_;                        // 256
    int*   bsumC = bsumL + 256;                      // 128
    float* baseb = (float*)(bsumC + 128);            // 384 fp32 (it=0 MLP base rows)
    float* ucbuf = baseb + 384;                      // 384 fp32 (it=0 update consts)

    // --- one memset zeroes degrees + flags; then dtype detection ---
    hipMemsetAsync(ldegi, 0, ((size_t)(L_ + C_) + 2) * sizeof(int), stream);
    detect_k<<<16, 512, 0, stream>>>((const unsigned short*)d_in[4], li_raw, flags);

    // --- fused preamble: fixdeg + weight-split + embedding-init (one launch) ---
    prep_k<<<15044, 256, 0, stream>>>(
        li_raw, ci_raw, li, ci, ldegi, cdegi,
        d_in[4], d_in[6], d_in[8], d_in[10], d_in[12], d_in[14], d_in[16], d_in[18],
        d_in[5], d_in[7], d_in[9], d_in[11], d_in[13], d_in[15], d_in[17], d_in[19],
        wt_hi, wt_lo, bb,
        d_in[2], d_in[3], lbuf0, cbuf0, flags);

    // --- CSR build ---
    scan1b_k<<<384, 256, 0, stream>>>(ldegi, cdegi, lptr, cptr, bsumL, bsumC);
    scan3b_k<<<384, 256, 0, stream>>>(lptr, cptr, bsumL, bsumC, lcur, ccur,
                                      ldegi, cdegi, invsq_l, invsq_c);
    place_k<<<E_ / 256, 256, 0, stream>>>(li, ci, lcur, ccur, l_other, c_other);

    float* l_cur = lbuf0; float* l_nxt = lbuf1;
    float* c_cur = cbuf0; float* c_nxt = cbuf1;

    const int nL = L_ / 128, nC = C_ / 128;

    // ---- it=0: embeddings row-uniform -> 3-block mlp3 + bcast (bitwise identical
    //      messages); uconst captures the uniform update contributions; update0
    //      runs only the aggregate K-range ----
    mlp3_k<<<3, 256, 0, stream>>>(
        l_cur, c_cur, wt_hi, wt_lo, bb, invsq_l, invsq_c,
        (bf16*)l_nxt, (bf16*)c_nxt, (bf16*)l2lb, 1, 1, baseb);
    bcast_k<<<(2 * L_ + C_) * 16 / 256, 256, 0, stream>>>(
        baseb, invsq_l, invsq_c,
        (bf16*)l_nxt, (bf16*)c_nxt, (bf16*)l2lb);
    uconst_k<<<2, 256, 0, stream>>>(
        l_cur, c_cur, (const bf16*)l2lb, wt_hi, wt_lo, ucbuf);
    gather2_k<<<(C_ + L_) / 16, 256, 0, stream>>>(
        cptr, cdegi, c_other, (const unsigned int*)l_nxt, invsq_c, caggr,
        lptr, ldegi, l_other, (const unsigned int*)c_nxt, invsq_l, laggr, C_);
    update0_k<<<768, 256, 0, stream>>>(
        laggr, caggr, wt_hi, wt_lo, bb, ucbuf, c_nxt, l_nxt);
    { float* tmp = l_cur; l_cur = l_nxt; l_nxt = tmp;
      tmp = c_cur; c_cur = c_nxt; c_nxt = tmp; }

    // ---- it=1,2: full pipeline ----
    for (int it = 1; it < 3; it++) {
        mlp3_k<<<2 * nL + nC, 256, 0, stream>>>(
            l_cur, c_cur, wt_hi, wt_lo, bb, invsq_l, invsq_c,
            (bf16*)l_nxt, (bf16*)c_nxt, (bf16*)l2lb, nL, nC, nullptr);
        gather2_k<<<(C_ + L_) / 16, 256, 0, stream>>>(
            cptr, cdegi, c_other, (const unsigned int*)l_nxt, invsq_c, caggr,
            lptr, ldegi, l_other, (const unsigned int*)c_nxt, invsq_l, laggr, C_);
        update_k<0><<<768, 256, 0, stream>>>(
            l_cur, c_cur, laggr, caggr, (const bf16*)l2lb, wt_hi, wt_lo, bb,
            c_nxt, l_nxt, nullptr, flags);
        float* tmp = l_cur; l_cur = l_nxt; l_nxt = tmp;
        tmp = c_cur; c_cur = c_nxt; c_nxt = tmp;
    }
    // --- final iteration: c-update dead -> skip l2c MLP, c-gather, c-update;
    //     fuse output dtype conversion into the l-update epilogue ---
    mlp3_k<<<nC + nL, 256, 0, stream>>>(
        l_cur, c_cur, wt_hi, wt_lo, bb, invsq_l, invsq_c,
        (bf16*)l_nxt, (bf16*)c_nxt, (bf16*)l2lb, 0, nC, nullptr);
    gather2_k<<<L_ / 16, 256, 0, stream>>>(
        cptr, cdegi, c_other, (const unsigned int*)l_nxt, invsq_c, caggr,
        lptr, ldegi, l_other, (const unsigned int*)c_nxt, invsq_l, laggr, 0);
    update_k<1><<<512, 256, 0, stream>>>(
        l_cur, c_cur, laggr, caggr, (const bf16*)l2lb, wt_hi, wt_lo, bb,
        nullptr, nullptr, d_out, flags);
}

// Round 13
// 596.301 us; speedup vs baseline: 1.9206x; 1.0498x over previous
//
#include <hip/hip_runtime.h>
#include <hip/hip_bf16.h>

#define D_ 128
#define L_ 65536
#define C_ 32768
#define E_ 262144

typedef __hip_bfloat16 bf16;
typedef __attribute__((ext_vector_type(8))) short short8;
typedef __attribute__((ext_vector_type(4))) float f32x4;

// flags[0] = 1 if float inputs are fp32 (else bf16); flags[1] = 1 if edge idx int32 (else int64)
__global__ void detect_k(const unsigned short* __restrict__ wmem,
                         const int* __restrict__ li, int* __restrict__ flags) {
    int t = blockIdx.x * 512 + threadIdx.x;
    if (t < 8192) {
        unsigned short h = wmem[2 * t];
        float v = __bfloat162float(*(const bf16*)&h);
        if (!(fabsf(v) < 0.5f)) atomicOr(&flags[0], 1);
    }
    if (t < 2048) {
        if (li[2 * t + 1] != 0) atomicOr(&flags[1], 1);
    }
}

__device__ __forceinline__ void split2(float v, unsigned short& h, unsigned short& l) {
    bf16 bh = __float2bfloat16(v);
    float fh = __bfloat162float(bh);
    bf16 bl = __float2bfloat16(v - fh);
    h = *(unsigned short*)&bh;
    l = *(unsigned short*)&bl;
}

__device__ __forceinline__ float ldf(const void* s, int i, int isf32) {
    return isf32 ? ((const float*)s)[i] : __bfloat162float(((const bf16*)s)[i]);
}

// ---- fused preamble: fixdeg (2048 blocks) + cvtwb (708) + init2 (32 blocks) ----
// init2 now writes ONLY rows 0..127 of each embedding buffer: at it=0 the only
// readers of the uniform embeddings are tile-0 kernels (3-block mlp3, uconst);
// lbuf0/cbuf0 are fully overwritten by update_k<0> before any it=1 read.
__global__ void prep_k(const int* __restrict__ ls, const int* __restrict__ cs,
                       int* __restrict__ ld_idx, int* __restrict__ cd_idx,
                       int* __restrict__ ldeg, int* __restrict__ cdeg,
                       const void* s0, const void* s1, const void* s2, const void* s3,
                       const void* s4, const void* s5, const void* s6, const void* s7,
                       const void* t0, const void* t1, const void* t2, const void* t3,
                       const void* t4, const void* t5, const void* t6, const void* t7,
                       unsigned short* __restrict__ hi, unsigned short* __restrict__ lo,
                       float* __restrict__ bb,
                       const void* __restrict__ lv, const void* __restrict__ cv,
                       float* __restrict__ lemb, float* __restrict__ cemb,
                       const int* __restrict__ flags) {
    const int blk = blockIdx.x;
    const int isf = flags[0];
    if (blk < 2048) {
        int i = blk * 256 + threadIdx.x;
        int is32 = flags[1];
        if (i < E_) {
            int v = is32 ? ls[i] : ls[2 * i];
            v = min(max(v, 0), L_ - 1);
            ld_idx[i] = v;
            atomicAdd(&ldeg[v], 1);
        } else {
            int j = i - E_;
            int v = is32 ? cs[j] : cs[2 * j];
            v = min(max(v, 0), C_ - 1);
            cd_idx[j] = v;
            atomicAdd(&cdeg[v], 1);
        }
        return;
    }
    if (blk < 2756) {
        int i = (blk - 2048) * 256 + threadIdx.x;  // 181248 total
        if (i >= 180224) {
            int j = i - 180224;  // 0..1023
            const void* src;
            switch (j >> 7) {
                case 0: src = t0; break; case 1: src = t1; break;
                case 2: src = t2; break; case 3: src = t3; break;
                case 4: src = t4; break; case 5: src = t5; break;
                case 6: src = t6; break; default: src = t7; break;
            }
            bb[j] = ldf(src, j & 127, isf);
            return;
        }
        const void* src; int K, base;
        if      (i <  16384) { src = s0; K = 128; base = 0; }
        else if (i <  32768) { src = s1; K = 128; base = 16384; }
        else if (i <  49152) { src = s2; K = 128; base = 32768; }
        else if (i <  65536) { src = s3; K = 128; base = 49152; }
        else if (i <  81920) { src = s4; K = 128; base = 65536; }
        else if (i <  98304) { src = s5; K = 128; base = 81920; }
        else if (i < 131072) { src = s6; K = 256; base = 98304; }
        else                 { src = s7; K = 384; base = 131072; }
        int e = i - base;
        int k = e >> 7, n = e & 127;
        float v = ldf(src, e, isf);
        unsigned short h, l;
        split2(v, h, l);
        hi[base + n * K + k] = h;
        lo[base + n * K + k] = l;
        return;
    }
    // ---- init2 (tile 0 only): blocks [2756, 2788) -> 8192 float4 writes ----
    int i4 = (blk - 2756) * 256 + threadIdx.x;  // 0..8191
    const void* src; float* dst; int o;
    if (i4 < 4096) { src = lv; dst = lemb; o = i4; }       // l rows 0..127
    else           { src = cv; dst = cemb; o = i4 - 4096; } // c rows 0..127
    int j = (o & 31) * 4;
    float4 v;
    v.x = ldf(src, j + 0, isf);
    v.y = ldf(src, j + 1, isf);
    v.z = ldf(src, j + 2, isf);
    v.w = ldf(src, j + 3, isf);
    ((float4*)dst)[o] = v;
}

// --- per-tile exclusive scan (stage 1), both sides fused ---
__global__ void scan1b_k(const int* __restrict__ ldeg, const int* __restrict__ cdeg,
                         int* __restrict__ lout, int* __restrict__ cout,
                         int* __restrict__ bsumL, int* __restrict__ bsumC) {
    __shared__ int s[256];
    const int* in; int* out; int* bs; int tile;
    if (blockIdx.x < 256) { in = ldeg; out = lout; bs = bsumL; tile = blockIdx.x; }
    else                  { in = cdeg; out = cout; bs = bsumC; tile = blockIdx.x - 256; }
    int i = tile * 256 + threadIdx.x;
    int v = in[i];
    s[threadIdx.x] = v;
    __syncthreads();
#pragma unroll
    for (int off = 1; off < 256; off <<= 1) {
        int t = (threadIdx.x >= off) ? s[threadIdx.x - off] : 0;
        __syncthreads();
        s[threadIdx.x] += t;
        __syncthreads();
    }
    out[i] = s[threadIdx.x] - v;
    if (threadIdx.x == 255) bs[tile] = s[255];
}

// stage 2+3 fused: each block redundantly computes its own bsum prefix.
__global__ void scan3b_k(int* __restrict__ lptr, int* __restrict__ cptr,
                         const int* __restrict__ bsumL, const int* __restrict__ bsumC,
                         int* __restrict__ lcur, int* __restrict__ ccur,
                         const int* __restrict__ ldeg, const int* __restrict__ cdeg,
                         float* __restrict__ invsq_l, float* __restrict__ invsq_c) {
    __shared__ int sh[256];
    int b = blockIdx.x, t = threadIdx.x;
    const bool lside = (b < 256);
    const int tile = lside ? b : b - 256;
    const int* bs = lside ? bsumL : bsumC;
    sh[t] = (t < tile) ? bs[t] : 0;
    __syncthreads();
#pragma unroll
    for (int off = 128; off > 0; off >>= 1) {
        if (t < off) sh[t] += sh[t + off];
        __syncthreads();
    }
    const int pref = sh[0];
    int i = tile * 256 + t;
    if (lside) {
        int v = lptr[i] + pref;
        lptr[i] = v; lcur[i] = v;
        int d = ldeg[i];
        invsq_l[i] = d ? rsqrtf((float)d) : 0.0f;
    } else {
        int v = cptr[i] + pref;
        cptr[i] = v; ccur[i] = v;
        int d = cdeg[i];
        invsq_c[i] = d ? rsqrtf((float)d) : 0.0f;
    }
}

// CSR placement (other endpoint only; norm is separable)
__global__ void place_k(const int* __restrict__ li, const int* __restrict__ ci,
                        int* __restrict__ lcur, int* __restrict__ ccur,
                        int* __restrict__ l_other, int* __restrict__ c_other) {
    int e = blockIdx.x * 256 + threadIdx.x;
    if (e >= E_) return;
    int l = li[e], c = ci[e];
    int p = atomicAdd(&ccur[c], 1);
    c_other[p] = l;
    int q = atomicAdd(&lcur[l], 1);
    l_other[q] = c;
}

// it=0 message broadcast: messages are bf16(base[col] * invsq[row]) -- bitwise
// identical to the full mlp3 path. l2lb segment: ONLY rows 0..127 (sole reader
// is uconst_k pass 2; update0 uses the uc constant instead).
__global__ void bcast_k(const float* __restrict__ baseb,
                        const float* __restrict__ invsq_l, const float* __restrict__ invsq_c,
                        bf16* __restrict__ l_msg, bf16* __restrict__ c_msg,
                        bf16* __restrict__ l2lb) {
    int id = blockIdx.x * 256 + threadIdx.x;   // each id writes 8 bf16 (16B)
    const int LCH = L_ * 16;
    const int CCH = C_ * 16;
    const float* base; bf16* out; int row, c8; float sc;
    if (id < LCH)            { base = baseb;       out = l_msg; row = id >> 4;
                               c8 = (id & 15) * 8; sc = invsq_l[row]; }
    else if (id < LCH + CCH) { int k = id - LCH;   base = baseb + 128; out = c_msg;
                               row = k >> 4; c8 = (k & 15) * 8; sc = invsq_c[row]; }
    else                     { int k = id - LCH - CCH; base = baseb + 256; out = l2lb;
                               row = k >> 4; c8 = (k & 15) * 8; sc = 1.0f; }
    union { short8 v; unsigned short u[8]; } o;
#pragma unroll
    for (int k = 0; k < 8; k++) {
        bf16 b = __float2bfloat16(base[c8 + k] * sc);
        o.u[k] = *(unsigned short*)&b;
    }
    *(short8*)&out[(size_t)row * D_ + c8] = o.v;
}

// it=0 uniform-range constants for update (runs EXACT update_k staging+MFMA
// sequence on tile 0 for the row-uniform K ranges; stores row 0's acc).
__global__ __launch_bounds__(256, 2) void uconst_k(
    const float* __restrict__ l_cur, const float* __restrict__ c_cur,
    const bf16* __restrict__ l2lb,
    const unsigned short* __restrict__ wt_hi, const unsigned short* __restrict__ wt_lo,
    float* __restrict__ uc) {
    __shared__ unsigned short a_hi[128][40], a_lo[128][40];
    __shared__ unsigned short b_hi[128][40], b_lo[128][40];
    const int t = threadIdx.x;
    const bool cseg = (blockIdx.x == 0);
    const int K = cseg ? 256 : 384;
    const float* A0 = cseg ? c_cur : l_cur;
    const unsigned short* Wh = wt_hi + (cseg ? 98304 : 131072);
    const unsigned short* Wl = wt_lo + (cseg ? 98304 : 131072);
    const int w = t >> 6, lane = t & 63;
    const int wr = w >> 1, wc = w & 1;
    const int quad = lane >> 4, cl = lane & 15;

    f32x4 acc[4][4];
#pragma unroll
    for (int i = 0; i < 4; i++)
#pragma unroll
        for (int j = 0; j < 4; j++) acc[i][j] = (f32x4){0.f, 0.f, 0.f, 0.f};

    for (int kt = 0; kt < 128; kt += 32) {
#pragma unroll
        for (int i = 0; i < 4; i++) {
            int f = t + 256 * i;
            int r = f >> 3, kq = f & 7;
            const float4 v = *(const float4*)&A0[(size_t)r * D_ + kt + 4 * kq];
            unsigned short h0, l0, h1, l1, h2, l2, h3, l3;
            split2(v.x, h0, l0); split2(v.y, h1, l1);
            split2(v.z, h2, l2); split2(v.w, h3, l3);
            *(ushort4*)&a_hi[r][4 * kq] = make_ushort4(h0, h1, h2, h3);
            *(ushort4*)&a_lo[r][4 * kq] = make_ushort4(l0, l1, l2, l3);
            *(ushort4*)&b_hi[r][4 * kq] = *(const ushort4*)&Wh[(size_t)r * K + kt + 4 * kq];
            *(ushort4*)&b_lo[r][4 * kq] = *(const ushort4*)&Wl[(size_t)r * K + kt + 4 * kq];
        }
        __syncthreads();
        short8 af_h[4], af_l[4];
#pragma unroll
        for (int i = 0; i < 4; i++) {
            int row = 64 * wr + 16 * i + cl;
            af_h[i] = *(const short8*)&a_hi[row][quad * 8];
            af_l[i] = *(const short8*)&a_lo[row][quad * 8];
        }
#pragma unroll
        for (int j = 0; j < 4; j++) {
            int col = 64 * wc + 16 * j + cl;
            short8 bf_h = *(const short8*)&b_hi[col][quad * 8];
            short8 bf_l = *(const short8*)&b_lo[col][quad * 8];
#pragma unroll
            for (int i = 0; i < 4; i++) {
                acc[i][j] = __builtin_amdgcn_mfma_f32_16x16x32_bf16(af_h[i], bf_h, acc[i][j], 0, 0, 0);
                acc[i][j] = __builtin_amdgcn_mfma_f32_16x16x32_bf16(af_h[i], bf_l, acc[i][j], 0, 0, 0);
                acc[i][j] = __builtin_amdgcn_mfma_f32_16x16x32_bf16(af_l[i], bf_h, acc[i][j], 0, 0, 0);
            }
        }
        __syncthreads();
    }
#pragma unroll
    for (int j = 0; j < 4; j++) {
        int col = 64 * wc + 16 * j + cl;
        if (w < 2 && lane < 16) uc[(cseg ? 0 : 128) + col] = acc[0][j][0];
    }
    if (cseg) return;

    // pass 2: l2l tiles kt=256..383 accumulated from zero (bf16 hi-plane only)
#pragma unroll
    for (int i = 0; i < 4; i++)
#pragma unroll
        for (int j = 0; j < 4; j++) acc[i][j] = (f32x4){0.f, 0.f, 0.f, 0.f};
    for (int kt = 256; kt < 384; kt += 32) {
        const int koff = kt & 127;
#pragma unroll
        for (int i = 0; i < 4; i++) {
            int f = t + 256 * i;
            int r = f >> 3, kq = f & 7;
            *(ushort4*)&a_hi[r][4 * kq] =
                *(const ushort4*)&l2lb[(size_t)r * D_ + koff + 4 * kq];
            *(ushort4*)&b_hi[r][4 * kq] = *(const ushort4*)&Wh[(size_t)r * K + kt + 4 * kq];
            *(ushort4*)&b_lo[r][4 * kq] = *(const ushort4*)&Wl[(size_t)r * K + kt + 4 * kq];
        }
        __syncthreads();
        short8 af_h[4];
#pragma unroll
        for (int i = 0; i < 4; i++) {
            int row = 64 * wr + 16 * i + cl;
            af_h[i] = *(const short8*)&a_hi[row][quad * 8];
        }
#pragma unroll
        for (int j = 0; j < 4; j++) {
            int col = 64 * wc + 16 * j + cl;
            short8 bf_h = *(const short8*)&b_hi[col][quad * 8];
            short8 bf_l = *(const short8*)&b_lo[col][quad * 8];
#pragma unroll
            for (int i = 0; i < 4; i++) {
                acc[i][j] = __builtin_amdgcn_mfma_f32_16x16x32_bf16(af_h[i], bf_h, acc[i][j], 0, 0, 0);
                acc[i][j] = __builtin_amdgcn_mfma_f32_16x16x32_bf16(af_h[i], bf_l, acc[i][j], 0, 0, 0);
            }
        }
        __syncthreads();
    }
#pragma unroll
    for (int j = 0; j < 4; j++) {
        int col = 64 * wc + 16 * j + cl;
        if (w < 2 && lane < 16) uc[256 + col] = acc[0][j][0];
    }
}

// it=0 update: acc from uniform-range constants; only the 4 aggregate K-tiles.
__global__ __launch_bounds__(256, 2) void update0_k(
    const float* __restrict__ laggr, const float* __restrict__ caggr,
    const unsigned short* __restrict__ wt_hi, const unsigned short* __restrict__ wt_lo,
    const float* __restrict__ bb, const float* __restrict__ uc,
    float* __restrict__ c_nxt, float* __restrict__ l_nxt) {
    __shared__ unsigned short a_hi[128][40], a_lo[128][40];
    __shared__ unsigned short b_hi[128][40], b_lo[128][40];
    const int t = threadIdx.x;
    int b = blockIdx.x;
    const bool cseg = (b < 256);
    const int tile = cseg ? b : b - 256;
    const int K = cseg ? 256 : 384;
    const float* A1 = cseg ? caggr : laggr;
    const unsigned short* Wh = wt_hi + (cseg ? 98304 : 131072);
    const unsigned short* Wl = wt_lo + (cseg ? 98304 : 131072);
    const float* bias = bb + (cseg ? 768 : 896);
    const float* uc0 = uc + (cseg ? 0 : 128);
    const int br0 = tile * 128;
    const int w = t >> 6, lane = t & 63;
    const int wr = w >> 1, wc = w & 1;
    const int quad = lane >> 4, cl = lane & 15;

    f32x4 acc[4][4];
#pragma unroll
    for (int j = 0; j < 4; j++) {
        int col = 64 * wc + 16 * j + cl;
        float cv = uc0[col];
#pragma unroll
        for (int i = 0; i < 4; i++) acc[i][j] = (f32x4){cv, cv, cv, cv};
    }

    for (int kt = 128; kt < 256; kt += 32) {
        const int koff = kt & 127;
#pragma unroll
        for (int i = 0; i < 4; i++) {
            int f = t + 256 * i;
            int r = f >> 3, kq = f & 7;
            const float4 v = *(const float4*)&A1[(size_t)(br0 + r) * D_ + koff + 4 * kq];
            unsigned short h0, l0, h1, l1, h2, l2, h3, l3;
            split2(v.x, h0, l0); split2(v.y, h1, l1);
            split2(v.z, h2, l2); split2(v.w, h3, l3);
            *(ushort4*)&a_hi[r][4 * kq] = make_ushort4(h0, h1, h2, h3);
            *(ushort4*)&a_lo[r][4 * kq] = make_ushort4(l0, l1, l2, l3);
            *(ushort4*)&b_hi[r][4 * kq] = *(const ushort4*)&Wh[(size_t)r * K + kt + 4 * kq];
            *(ushort4*)&b_lo[r][4 * kq] = *(const ushort4*)&Wl[(size_t)r * K + kt + 4 * kq];
        }
        __syncthreads();
        short8 af_h[4], af_l[4];
#pragma unroll
        for (int i = 0; i < 4; i++) {
            int row = 64 * wr + 16 * i + cl;
            af_h[i] = *(const short8*)&a_hi[row][quad * 8];
            af_l[i] = *(const short8*)&a_lo[row][quad * 8];
        }
#pragma unroll
        for (int j = 0; j < 4; j++) {
            int col = 64 * wc + 16 * j + cl;
            short8 bf_h = *(const short8*)&b_hi[col][quad * 8];
            short8 bf_l = *(const short8*)&b_lo[col][quad * 8];
#pragma unroll
            for (int i = 0; i < 4; i++) {
                acc[i][j] = __builtin_amdgcn_mfma_f32_16x16x32_bf16(af_h[i], bf_h, acc[i][j], 0, 0, 0);
                acc[i][j] = __builtin_amdgcn_mfma_f32_16x16x32_bf16(af_h[i], bf_l, acc[i][j], 0, 0, 0);
                acc[i][j] = __builtin_amdgcn_mfma_f32_16x16x32_bf16(af_l[i], bf_h, acc[i][j], 0, 0, 0);
            }
        }
        __syncthreads();
    }
    float* outp = cseg ? c_nxt : l_nxt;
#pragma unroll
    for (int j = 0; j < 4; j++) {
        int col = 64 * wc + 16 * j + cl;
        float bv = bias[col];
        float l2lc = cseg ? 0.0f : uc[256 + col];
#pragma unroll
        for (int i = 0; i < 4; i++) {
            int rbase = br0 + 64 * wr + 16 * i + quad * 4;
#pragma unroll
            for (int rg = 0; rg < 4; rg++) {
                float v = (acc[i][j][rg] + l2lc) + bv;
                outp[(size_t)(rbase + rg) * D_ + col] = v;
            }
        }
    }
}

// Fused pull-aggregation, both directions (r9 4-node/2-deep structure, kept).
__global__ __launch_bounds__(256) void gather2_k(
    const int* __restrict__ cptr, const int* __restrict__ cdeg, const int* __restrict__ c_other,
    const unsigned int* __restrict__ lmsg, const float* __restrict__ invsq_c, float* __restrict__ caggr,
    const int* __restrict__ lptr, const int* __restrict__ ldeg, const int* __restrict__ l_other,
    const unsigned int* __restrict__ cmsg, const float* __restrict__ invsq_l, float* __restrict__ laggr,
    int nC) {
    int wid = (blockIdx.x * 256 + threadIdx.x) >> 6;
    int lane = threadIdx.x & 63;
    int n0 = 4 * wid;
    bool cside = n0 < nC;
    int j0 = cside ? n0 : n0 - nC;
    const int* ptr = cside ? cptr : lptr;
    const int* dg  = cside ? cdeg : ldeg;
    const int* oth = cside ? c_other : l_other;
    const unsigned int* msg = cside ? lmsg : cmsg;
    const float* invsq = cside ? invsq_c : invsq_l;
    float* out = cside ? caggr : laggr;

    int s0 = ptr[j0],     c0 = dg[j0];
    int s1 = ptr[j0 + 1], c1 = dg[j0 + 1];
    int s2 = ptr[j0 + 2], c2 = dg[j0 + 2];
    int s3 = ptr[j0 + 3], c3 = dg[j0 + 3];
    float2 A0 = {0.f, 0.f}, B0 = {0.f, 0.f};
    float2 A1 = {0.f, 0.f}, B1 = {0.f, 0.f};
    float2 A2 = {0.f, 0.f}, B2 = {0.f, 0.f};
    float2 A3 = {0.f, 0.f}, B3 = {0.f, 0.f};
    int k0 = 0, k1 = 0, k2 = 0, k3 = 0;

#define GLD_(s, k) msg[(size_t)oth[(s) + (k)] * 64 + lane]
#define GACC_(a, u) { (a).x += __uint_as_float((u) << 16); \
                      (a).y += __uint_as_float((u) & 0xffff0000u); }

    for (; k0 + 2 <= c0 && k1 + 2 <= c1 && k2 + 2 <= c2 && k3 + 2 <= c3;
         k0 += 2, k1 += 2, k2 += 2, k3 += 2) {
        unsigned int u00 = GLD_(s0, k0), u01 = GLD_(s0, k0 + 1);
        unsigned int u10 = GLD_(s1, k1), u11 = GLD_(s1, k1 + 1);
        unsigned int u20 = GLD_(s2, k2), u21 = GLD_(s2, k2 + 1);
        unsigned int u30 = GLD_(s3, k3), u31 = GLD_(s3, k3 + 1);
        GACC_(A0, u00); GACC_(B0, u01);
        GACC_(A1, u10); GACC_(B1, u11);
        GACC_(A2, u20); GACC_(B2, u21);
        GACC_(A3, u30); GACC_(B3, u31);
    }
    for (; k0 + 2 <= c0 && k1 + 2 <= c1; k0 += 2, k1 += 2) {
        unsigned int u00 = GLD_(s0, k0), u01 = GLD_(s0, k0 + 1);
        unsigned int u10 = GLD_(s1, k1), u11 = GLD_(s1, k1 + 1);
        GACC_(A0, u00); GACC_(B0, u01);
        GACC_(A1, u10); GACC_(B1, u11);
    }
    for (; k2 + 2 <= c2 && k3 + 2 <= c3; k2 += 2, k3 += 2) {
        unsigned int u20 = GLD_(s2, k2), u21 = GLD_(s2, k2 + 1);
        unsigned int u30 = GLD_(s3, k3), u31 = GLD_(s3, k3 + 1);
        GACC_(A2, u20); GACC_(B2, u21);
        GACC_(A3, u30); GACC_(B3, u31);
    }
    for (; k0 + 2 <= c0; k0 += 2) {
        unsigned int ua = GLD_(s0, k0), ub = GLD_(s0, k0 + 1);
        GACC_(A0, ua); GACC_(B0, ub);
    }
    for (; k1 + 2 <= c1; k1 += 2) {
        unsigned int ua = GLD_(s1, k1), ub = GLD_(s1, k1 + 1);
        GACC_(A1, ua); GACC_(B1, ub);
    }
    for (; k2 + 2 <= c2; k2 += 2) {
        unsigned int ua = GLD_(s2, k2), ub = GLD_(s2, k2 + 1);
        GACC_(A2, ua); GACC_(B2, ub);
    }
    for (; k3 + 2 <= c3; k3 += 2) {
        unsigned int ua = GLD_(s3, k3), ub = GLD_(s3, k3 + 1);
        GACC_(A3, ua); GACC_(B3, ub);
    }
    if (k0 < c0) { unsigned int u = GLD_(s0, k0); GACC_(A0, u); }
    if (k1 < c1) { unsigned int u = GLD_(s1, k1); GACC_(A1, u); }
    if (k2 < c2) { unsigned int u = GLD_(s2, k2); GACC_(A2, u); }
    if (k3 < c3) { unsigned int u = GLD_(s3, k3); GACC_(A3, u); }
#undef GLD_
#undef GACC_

    float sc0 = invsq[j0], sc1 = invsq[j0 + 1];
    float sc2 = invsq[j0 + 2], sc3 = invsq[j0 + 3];
    float2 r;
    r.x = (A0.x + B0.x) * sc0; r.y = (A0.y + B0.y) * sc0;
    *(float2*)&out[(size_t)j0 * D_ + 2 * lane] = r;
    r.x = (A1.x + B1.x) * sc1; r.y = (A1.y + B1.y) * sc1;
    *(float2*)&out[(size_t)(j0 + 1) * D_ + 2 * lane] = r;
    r.x = (A2.x + B2.x) * sc2; r.y = (A2.y + B2.y) * sc2;
    *(float2*)&out[(size_t)(j0 + 2) * D_ + 2 * lane] = r;
    r.x = (A3.x + B3.x) * sc3; r.y = (A3.y + B3.y) * sc3;
    *(float2*)&out[(size_t)(j0 + 3) * D_ + 2 * lane] = r;
}

// ---------- fused 2-layer MLPs, all three in one launch; 128-row tiles ----------
// (EXACT round-0 structure.) base_out != nullptr: ALSO store the pre-scale fp32
// output row (acc+bias for row 0) to base_out[seg*128 + col].
__global__ __launch_bounds__(256, 2) void mlp3_k(
    const float* __restrict__ l_cur, const float* __restrict__ c_cur,
    const unsigned short* __restrict__ wt_hi, const unsigned short* __restrict__ wt_lo,
    const float* __restrict__ bb,
    const float* __restrict__ invsq_l, const float* __restrict__ invsq_c,
    bf16* __restrict__ l_msg, bf16* __restrict__ c_msg, bf16* __restrict__ l2lb,
    int nL, int nC, float* __restrict__ base_out) {
    __shared__ char smem[66048];
    unsigned short (*a_hi)[40] = (unsigned short(*)[40])(smem);
    unsigned short (*a_lo)[40] = (unsigned short(*)[40])(smem + 10240);
    unsigned short (*b_hi)[40] = (unsigned short(*)[40])(smem + 20480);
    unsigned short (*b_lo)[40] = (unsigned short(*)[40])(smem + 30720);
    unsigned short* h_hi = (unsigned short*)(smem);          // phase 2 aliases tiles
    unsigned short* h_lo = (unsigned short*)(smem + 32768);
    float* scv = (float*)(smem + 65536);                     // 128 floats, non-aliased

    int b = blockIdx.x, seg, tile;
    if (b < nL)           { seg = 0; tile = b; }
    else if (b < nL + nC) { seg = 1; tile = b - nL; }
    else                  { seg = 2; tile = b - nL - nC; }
    const float* A = (seg == 1) ? c_cur : l_cur;
    bf16* outp = (seg == 0) ? l_msg : (seg == 1) ? c_msg : l2lb;
    const float* invsq = (seg == 0) ? invsq_l : (seg == 1) ? invsq_c : nullptr;
    const unsigned short* W1h = wt_hi + seg * 32768;
    const unsigned short* W1l = wt_lo + seg * 32768;
    const unsigned short* W2h = W1h + 16384;
    const unsigned short* W2l = W1l + 16384;
    const float* b1v = bb + seg * 256;
    const float* b2v = b1v + 128;
    const int swap = (seg == 2);

    const int t = threadIdx.x;
    const int br0 = tile * 128;
    const int w = t >> 6, lane = t & 63;
    const int wr = w >> 1, wc = w & 1;
    const int quad = lane >> 4, cl = lane & 15;

    if (t < 128) scv[t] = invsq ? invsq[br0 + t] : 1.0f;

    f32x4 acc[4][4];
#pragma unroll
    for (int i = 0; i < 4; i++)
#pragma unroll
        for (int j = 0; j < 4; j++) acc[i][j] = (f32x4){0.f, 0.f, 0.f, 0.f};

    // ---- phase 1: h = A @ W1 ----
    for (int kt = 0; kt < 128; kt += 32) {
#pragma unroll
        for (int i = 0; i < 4; i++) {
            int f = t + 256 * i;
            int r = f >> 3, kq = f & 7;
            int gr = br0 + r;
            if (swap) gr ^= 1;
            const float4 v = *(const float4*)&A[(size_t)gr * D_ + kt + 4 * kq];
            unsigned short h0, l0, h1, l1, h2, l2, h3, l3;
            split2(v.x, h0, l0); split2(v.y, h1, l1);
            split2(v.z, h2, l2); split2(v.w, h3, l3);
            *(ushort4*)&a_hi[r][4 * kq] = make_ushort4(h0, h1, h2, h3);
            *(ushort4*)&a_lo[r][4 * kq] = make_ushort4(l0, l1, l2, l3);
            *(ushort4*)&b_hi[r][4 * kq] = *(const ushort4*)&W1h[(size_t)r * 128 + kt + 4 * kq];
            *(ushort4*)&b_lo[r][4 * kq] = *(const ushort4*)&W1l[(size_t)r * 128 + kt + 4 * kq];
        }
        __syncthreads();
        short8 af_h[4], af_l[4];
#pragma unroll
        for (int i = 0; i < 4; i++) {
            int row = 64 * wr + 16 * i + cl;
            af_h[i] = *(const short8*)&a_hi[row][quad * 8];
            af_l[i] = *(const short8*)&a_lo[row][quad * 8];
        }
#pragma unroll
        for (int j = 0; j < 4; j++) {
            int col = 64 * wc + 16 * j + cl;
            short8 bf_h = *(const short8*)&b_hi[col][quad * 8];
            short8 bf_l = *(const short8*)&b_lo[col][quad * 8];
#pragma unroll
            for (int i = 0; i < 4; i++) {
                acc[i][j] = __builtin_amdgcn_mfma_f32_16x16x32_bf16(af_h[i], bf_h, acc[i][j], 0, 0, 0);
                acc[i][j] = __builtin_amdgcn_mfma_f32_16x16x32_bf16(af_h[i], bf_l, acc[i][j], 0, 0, 0);
                acc[i][j] = __builtin_amdgcn_mfma_f32_16x16x32_bf16(af_l[i], bf_h, acc[i][j], 0, 0, 0);
            }
        }
        __syncthreads();
    }
    // h epilogue: bias + relu + split -> swizzled LDS. C/D: col=cl, row=quad*4+reg.
#pragma unroll
    for (int j = 0; j < 4; j++) {
        int col = 64 * wc + 16 * j + cl;
        float bv = b1v[col];
        int g = col >> 3, go = col & 7;
#pragma unroll
        for (int i = 0; i < 4; i++) {
            int rloc = 64 * wr + 16 * i + quad * 4;
#pragma unroll
            for (int rg = 0; rg < 4; rg++) {
                float v = fmaxf(acc[i][j][rg] + bv, 0.0f);
                unsigned short hh, ll;
                split2(v, hh, ll);
                int r = rloc + rg;
                int off = r * 128 + ((g ^ (r & 15)) << 3) + go;
                h_hi[off] = hh;
                h_lo[off] = ll;
            }
        }
    }
    __syncthreads();
    // ---- phase 2: out = (h @ W2 + b2) * scv -> bf16 ----
#pragma unroll
    for (int i = 0; i < 4; i++)
#pragma unroll
        for (int j = 0; j < 4; j++) acc[i][j] = (f32x4){0.f, 0.f, 0.f, 0.f};

    for (int kt = 0; kt < 128; kt += 32) {
        short8 af_h[4], af_l[4];
        int gbase = (kt >> 3) + quad;
#pragma unroll
        for (int i = 0; i < 4; i++) {
            int r = 64 * wr + 16 * i + cl;
            int off = r * 128 + ((gbase ^ cl) << 3);
            af_h[i] = *(const short8*)&h_hi[off];
            af_l[i] = *(const short8*)&h_lo[off];
        }
#pragma unroll
        for (int j = 0; j < 4; j++) {
            int col = 64 * wc + 16 * j + cl;
            const short8 bf_h = *(const short8*)&W2h[(size_t)col * 128 + kt + quad * 8];
            const short8 bf_l = *(const short8*)&W2l[(size_t)col * 128 + kt + quad * 8];
#pragma unroll
            for (int i = 0; i < 4; i++) {
                acc[i][j] = __builtin_amdgcn_mfma_f32_16x16x32_bf16(af_h[i], bf_h, acc[i][j], 0, 0, 0);
                acc[i][j] = __builtin_amdgcn_mfma_f32_16x16x32_bf16(af_h[i], bf_l, acc[i][j], 0, 0, 0);
                acc[i][j] = __builtin_amdgcn_mfma_f32_16x16x32_bf16(af_l[i], bf_h, acc[i][j], 0, 0, 0);
            }
        }
    }
#pragma unroll
    for (int j = 0; j < 4; j++) {
        int col = 64 * wc + 16 * j + cl;
        float bv = b2v[col];
        if (base_out && w < 2 && lane < 16)
            base_out[seg * 128 + col] = acc[0][j][0] + bv;   // row 0, pre-scale fp32
#pragma unroll
        for (int i = 0; i < 4; i++) {
            int rloc = 64 * wr + 16 * i + quad * 4;
#pragma unroll
            for (int rg = 0; rg < 4; rg++)
                outp[(size_t)(br0 + rloc + rg) * D_ + col] =
                    __float2bfloat16((acc[i][j][rg] + bv) * scv[rloc + rg]);
        }
    }
}

// ---------- fused update GEMMs; 128-row tiles (EXACT round-0 structure) ----------
template <int FINAL>
__global__ __launch_bounds__(256, 2) void update_k(
    const float* __restrict__ l_cur, const float* __restrict__ c_cur,
    const float* __restrict__ laggr, const float* __restrict__ caggr,
    const bf16* __restrict__ l2lb,
    const unsigned short* __restrict__ wt_hi, const unsigned short* __restrict__ wt_lo,
    const float* __restrict__ bb,
    float* __restrict__ c_nxt, float* __restrict__ l_nxt,
    void* __restrict__ dout, const int* __restrict__ flags) {
    __shared__ unsigned short a_hi[128][40], a_lo[128][40];
    __shared__ unsigned short b_hi[128][40], b_lo[128][40];
    const int t = threadIdx.x;
    int b = blockIdx.x;
    const bool cseg = (!FINAL) && (b < 256);
    const int tile = (FINAL || cseg) ? b : b - 256;
    const int K = cseg ? 256 : 384;
    const float* A0 = cseg ? c_cur : l_cur;
    const float* A1 = cseg ? caggr : laggr;
    const unsigned short* Wh = wt_hi + (cseg ? 98304 : 131072);
    const unsigned short* Wl = wt_lo + (cseg ? 98304 : 131072);
    const float* bias = bb + (cseg ? 768 : 896);
    const int br0 = tile * 128;
    const int w = t >> 6, lane = t & 63;
    const int wr = w >> 1, wc = w & 1;
    const int quad = lane >> 4, cl = lane & 15;

    f32x4 acc[4][4];
#pragma unroll
    for (int i = 0; i < 4; i++)
#pragma unroll
        for (int j = 0; j < 4; j++) acc[i][j] = (f32x4){0.f, 0.f, 0.f, 0.f};

    for (int kt = 0; kt < K; kt += 32) {
        const bool haslo = (kt < 256);
        const int koff = kt & 127;
#pragma unroll
        for (int i = 0; i < 4; i++) {
            int f = t + 256 * i;
            int r = f >> 3, kq = f & 7;
            if (haslo) {
                const float* As = (kt < 128) ? A0 : A1;
                const float4 v = *(const float4*)&As[(size_t)(br0 + r) * D_ + koff + 4 * kq];
                unsigned short h0, l0, h1, l1, h2, l2, h3, l3;
                split2(v.x, h0, l0); split2(v.y, h1, l1);
                split2(v.z, h2, l2); split2(v.w, h3, l3);
                *(ushort4*)&a_hi[r][4 * kq] = make_ushort4(h0, h1, h2, h3);
                *(ushort4*)&a_lo[r][4 * kq] = make_ushort4(l0, l1, l2, l3);
            } else {
                *(ushort4*)&a_hi[r][4 * kq] =
                    *(const ushort4*)&l2lb[(size_t)(br0 + r) * D_ + koff + 4 * kq];
            }
            *(ushort4*)&b_hi[r][4 * kq] = *(const ushort4*)&Wh[(size_t)r * K + kt + 4 * kq];
            *(ushort4*)&b_lo[r][4 * kq] = *(const ushort4*)&Wl[(size_t)r * K + kt + 4 * kq];
        }
        __syncthreads();
        short8 af_h[4], af_l[4];
#pragma unroll
        for (int i = 0; i < 4; i++) {
            int row = 64 * wr + 16 * i + cl;
            af_h[i] = *(const short8*)&a_hi[row][quad * 8];
            if (haslo) af_l[i] = *(const short8*)&a_lo[row][quad * 8];
        }
#pragma unroll
        for (int j = 0; j < 4; j++) {
            int col = 64 * wc + 16 * j + cl;
            short8 bf_h = *(const short8*)&b_hi[col][quad * 8];
            short8 bf_l = *(const short8*)&b_lo[col][quad * 8];
#pragma unroll
            for (int i = 0; i < 4; i++) {
                acc[i][j] = __builtin_amdgcn_mfma_f32_16x16x32_bf16(af_h[i], bf_h, acc[i][j], 0, 0, 0);
                acc[i][j] = __builtin_amdgcn_mfma_f32_16x16x32_bf16(af_h[i], bf_l, acc[i][j], 0, 0, 0);
                if (haslo)
                    acc[i][j] = __builtin_amdgcn_mfma_f32_16x16x32_bf16(af_l[i], bf_h, acc[i][j], 0, 0, 0);
            }
        }
        __syncthreads();
    }
    const int f32out = FINAL ? flags[0] : 1;
#pragma unroll
    for (int j = 0; j < 4; j++) {
        int col = 64 * wc + 16 * j + cl;
        float bv = bias[col];
#pragma unroll
        for (int i = 0; i < 4; i++) {
            int rbase = br0 + 64 * wr + 16 * i + quad * 4;
#pragma unroll
            for (int rg = 0; rg < 4; rg++) {
                float v = acc[i][j][rg] + bv;
                size_t idx = (size_t)(rbase + rg) * D_ + col;
                if (FINAL) {
                    if (f32out) ((float*)dout)[idx] = v;
                    else        ((bf16*)dout)[idx] = __float2bfloat16(v);
                } else {
                    (cseg ? c_nxt : l_nxt)[idx] = v;
                }
            }
        }
    }
}

extern "C" void kernel_launch(void* const* d_in, const int* in_sizes, int n_in,
                              void* d_out, int out_size, void* d_ws, size_t ws_size,
                              hipStream_t stream) {
    const int* li_raw = (const int*)d_in[0];
    const int* ci_raw = (const int*)d_in[1];

    // ---- workspace layout (flags after cdegi -> one zeroing memset) ----
    float* ws = (float*)d_ws;
    float* lbuf0 = ws;                               // L*D
    float* lbuf1 = lbuf0 + (size_t)L_ * D_;          // L*D  (doubles as bf16 l_msg)
    float* l2lb  = lbuf1 + (size_t)L_ * D_;          // L*D  (bf16 l2l messages)
    float* laggr = l2lb + (size_t)L_ * D_;           // L*D
    float* cbuf0 = laggr + (size_t)L_ * D_;          // C*D
    float* cbuf1 = cbuf0 + (size_t)C_ * D_;          // C*D  (doubles as bf16 c_msg)
    float* caggr = cbuf1 + (size_t)C_ * D_;          // C*D
    float* invsq_l = caggr + (size_t)C_ * D_;        // L
    float* invsq_c = invsq_l + L_;                   // C
    float* bb    = invsq_c + C_;                     // 1024 bias floats
    unsigned short* wt_hi = (unsigned short*)(bb + 1024);   // 180224 ushorts
    unsigned short* wt_lo = wt_hi + 180224;                 // 180224 ushorts
    int*   li    = (int*)(wt_lo + 180224);           // E
    int*   ci    = li + E_;                          // E
    int*   l_other = ci + E_;                        // E
    int*   c_other = l_other + E_;                   // E
    int*   ldegi = c_other + E_;                     // L
    int*   cdegi = ldegi + L_;                       // C
    int*   flags = cdegi + C_;                       // 2  (contiguous with deg arrays)
    int*   lptr  = flags + 2;                        // L
    int*   cptr  = lptr + L_;                        // C
    int*   lcur  = cptr + C_;                        // L
    int*   ccur  = lcur + L_;                        // C
    int*   bsumL = ccur + C_;                        // 256
    int*   bsumC = bsumL + 256;                      // 128
    float* baseb = (float*)(bsumC + 128);            // 384 fp32 (it=0 MLP base rows)
    float* ucbuf = baseb + 384;                      // 384 fp32 (it=0 update consts)

    // --- one memset zeroes degrees + flags; then dtype detection ---
    hipMemsetAsync(ldegi, 0, ((size_t)(L_ + C_) + 2) * sizeof(int), stream);
    detect_k<<<16, 512, 0, stream>>>((const unsigned short*)d_in[4], li_raw, flags);

    // --- fused preamble: fixdeg + weight-split + tile-0 embedding-init ---
    prep_k<<<2788, 256, 0, stream>>>(
        li_raw, ci_raw, li, ci, ldegi, cdegi,
        d_in[4], d_in[6], d_in[8], d_in[10], d_in[12], d_in[14], d_in[16], d_in[18],
        d_in[5], d_in[7], d_in[9], d_in[11], d_in[13], d_in[15], d_in[17], d_in[19],
        wt_hi, wt_lo, bb,
        d_in[2], d_in[3], lbuf0, cbuf0, flags);

    // --- CSR build ---
    scan1b_k<<<384, 256, 0, stream>>>(ldegi, cdegi, lptr, cptr, bsumL, bsumC);
    scan3b_k<<<384, 256, 0, stream>>>(lptr, cptr, bsumL, bsumC, lcur, ccur,
                                      ldegi, cdegi, invsq_l, invsq_c);
    place_k<<<E_ / 256, 256, 0, stream>>>(li, ci, lcur, ccur, l_other, c_other);

    float* l_cur = lbuf0; float* l_nxt = lbuf1;
    float* c_cur = cbuf0; float* c_nxt = cbuf1;

    const int nL = L_ / 128, nC = C_ / 128;

    // ---- it=0: embeddings row-uniform -> 3-block mlp3 + bcast (bitwise identical
    //      messages; l2lb only rows 0..127 -- sole reader is uconst); uconst
    //      captures uniform update contributions; update0 runs only the
    //      aggregate K-range ----
    mlp3_k<<<3, 256, 0, stream>>>(
        l_cur, c_cur, wt_hi, wt_lo, bb, invsq_l, invsq_c,
        (bf16*)l_nxt, (bf16*)c_nxt, (bf16*)l2lb, 1, 1, baseb);
    bcast_k<<<((L_ + C_) * 16 + 128 * 16) / 256, 256, 0, stream>>>(
        baseb, invsq_l, invsq_c,
        (bf16*)l_nxt, (bf16*)c_nxt, (bf16*)l2lb);
    uconst_k<<<2, 256, 0, stream>>>(
        l_cur, c_cur, (const bf16*)l2lb, wt_hi, wt_lo, ucbuf);
    gather2_k<<<(C_ + L_) / 16, 256, 0, stream>>>(
        cptr, cdegi, c_other, (const unsigned int*)l_nxt, invsq_c, caggr,
        lptr, ldegi, l_other, (const unsigned int*)c_nxt, invsq_l, laggr, C_);
    update0_k<<<768, 256, 0, stream>>>(
        laggr, caggr, wt_hi, wt_lo, bb, ucbuf, c_nxt, l_nxt);
    { float* tmp = l_cur; l_cur = l_nxt; l_nxt = tmp;
      tmp = c_cur; c_cur = c_nxt; c_nxt = tmp; }

    // ---- it=1,2: full pipeline ----
    for (int it = 1; it < 3; it++) {
        mlp3_k<<<2 * nL + nC, 256, 0, stream>>>(
            l_cur, c_cur, wt_hi, wt_lo, bb, invsq_l, invsq_c,
            (bf16*)l_nxt, (bf16*)c_nxt, (bf16*)l2lb, nL, nC, nullptr);
        gather2_k<<<(C_ + L_) / 16, 256, 0, stream>>>(
            cptr, cdegi, c_other, (const unsigned int*)l_nxt, invsq_c, caggr,
            lptr, ldegi, l_other, (const unsigned int*)c_nxt, invsq_l, laggr, C_);
        update_k<0><<<768, 256, 0, stream>>>(
            l_cur, c_cur, laggr, caggr, (const bf16*)l2lb, wt_hi, wt_lo, bb,
            c_nxt, l_nxt, nullptr, flags);
        float* tmp = l_cur; l_cur = l_nxt; l_nxt = tmp;
        tmp = c_cur; c_cur = c_nxt; c_nxt = tmp;
    }
    // --- final iteration: c-update dead -> skip l2c MLP, c-gather, c-update;
    //     fuse output dtype conversion into the l-update epilogue ---
    mlp3_k<<<nC + nL, 256, 0, stream>>>(
        l_cur, c_cur, wt_hi, wt_lo, bb, invsq_l, invsq_c,
        (bf16*)l_nxt, (bf16*)c_nxt, (bf16*)l2lb, 0, nC, nullptr);
    gather2_k<<<L_ / 16, 256, 0, stream>>>(
        cptr, cdegi, c_other, (const unsigned int*)l_nxt, invsq_c, caggr,
        lptr, ldegi, l_other, (const unsigned int*)c_nxt, invsq_l, laggr, 0);
    update_k<1><<<512, 256, 0, stream>>>(
        l_cur, c_cur, laggr, caggr, (const bf16*)l2lb, wt_hi, wt_lo, bb,
        nullptr, nullptr, d_out, flags);
}

// Round 14
// 595.855 us; speedup vs baseline: 1.9220x; 1.0007x over previous
//
#include <hip/hip_runtime.h>
#include <hip/hip_bf16.h>

#define D_ 128
#define L_ 65536
#define C_ 32768
#define E_ 262144

typedef __hip_bfloat16 bf16;
typedef __attribute__((ext_vector_type(8))) short short8;
typedef __attribute__((ext_vector_type(4))) float f32x4;

// flags[0] = 1 if float inputs are fp32 (else bf16); flags[1] = 1 if edge idx int32 (else int64)
__global__ void detect_k(const unsigned short* __restrict__ wmem,
                         const int* __restrict__ li, int* __restrict__ flags) {
    int t = blockIdx.x * 512 + threadIdx.x;
    if (t < 8192) {
        unsigned short h = wmem[2 * t];
        float v = __bfloat162float(*(const bf16*)&h);
        if (!(fabsf(v) < 0.5f)) atomicOr(&flags[0], 1);
    }
    if (t < 2048) {
        if (li[2 * t + 1] != 0) atomicOr(&flags[1], 1);
    }
}

__device__ __forceinline__ void split2(float v, unsigned short& h, unsigned short& l) {
    bf16 bh = __float2bfloat16(v);
    float fh = __bfloat162float(bh);
    bf16 bl = __float2bfloat16(v - fh);
    h = *(unsigned short*)&bh;
    l = *(unsigned short*)&bl;
}

__device__ __forceinline__ float ldf(const void* s, int i, int isf32) {
    return isf32 ? ((const float*)s)[i] : __bfloat162float(((const bf16*)s)[i]);
}

// ---- fused preamble: fixdeg (2048 blocks) + cvtwb (708) + tile-0 init2 (32) ----
__global__ void prep_k(const int* __restrict__ ls, const int* __restrict__ cs,
                       int* __restrict__ ld_idx, int* __restrict__ cd_idx,
                       int* __restrict__ ldeg, int* __restrict__ cdeg,
                       const void* s0, const void* s1, const void* s2, const void* s3,
                       const void* s4, const void* s5, const void* s6, const void* s7,
                       const void* t0, const void* t1, const void* t2, const void* t3,
                       const void* t4, const void* t5, const void* t6, const void* t7,
                       unsigned short* __restrict__ hi, unsigned short* __restrict__ lo,
                       float* __restrict__ bb,
                       const void* __restrict__ lv, const void* __restrict__ cv,
                       float* __restrict__ lemb, float* __restrict__ cemb,
                       const int* __restrict__ flags) {
    const int blk = blockIdx.x;
    const int isf = flags[0];
    if (blk < 2048) {
        int i = blk * 256 + threadIdx.x;
        int is32 = flags[1];
        if (i < E_) {
            int v = is32 ? ls[i] : ls[2 * i];
            v = min(max(v, 0), L_ - 1);
            ld_idx[i] = v;
            atomicAdd(&ldeg[v], 1);
        } else {
            int j = i - E_;
            int v = is32 ? cs[j] : cs[2 * j];
            v = min(max(v, 0), C_ - 1);
            cd_idx[j] = v;
            atomicAdd(&cdeg[v], 1);
        }
        return;
    }
    if (blk < 2756) {
        int i = (blk - 2048) * 256 + threadIdx.x;  // 181248 total
        if (i >= 180224) {
            int j = i - 180224;  // 0..1023
            const void* src;
            switch (j >> 7) {
                case 0: src = t0; break; case 1: src = t1; break;
                case 2: src = t2; break; case 3: src = t3; break;
                case 4: src = t4; break; case 5: src = t5; break;
                case 6: src = t6; break; default: src = t7; break;
            }
            bb[j] = ldf(src, j & 127, isf);
            return;
        }
        const void* src; int K, base;
        if      (i <  16384) { src = s0; K = 128; base = 0; }
        else if (i <  32768) { src = s1; K = 128; base = 16384; }
        else if (i <  49152) { src = s2; K = 128; base = 32768; }
        else if (i <  65536) { src = s3; K = 128; base = 49152; }
        else if (i <  81920) { src = s4; K = 128; base = 65536; }
        else if (i <  98304) { src = s5; K = 128; base = 81920; }
        else if (i < 131072) { src = s6; K = 256; base = 98304; }
        else                 { src = s7; K = 384; base = 131072; }
        int e = i - base;
        int k = e >> 7, n = e & 127;
        float v = ldf(src, e, isf);
        unsigned short h, l;
        split2(v, h, l);
        hi[base + n * K + k] = h;
        lo[base + n * K + k] = l;
        return;
    }
    // ---- init2 (tile 0 only): blocks [2756, 2788) -> 8192 float4 writes ----
    int i4 = (blk - 2756) * 256 + threadIdx.x;  // 0..8191
    const void* src; float* dst; int o;
    if (i4 < 4096) { src = lv; dst = lemb; o = i4; }       // l rows 0..127
    else           { src = cv; dst = cemb; o = i4 - 4096; } // c rows 0..127
    int j = (o & 31) * 4;
    float4 v;
    v.x = ldf(src, j + 0, isf);
    v.y = ldf(src, j + 1, isf);
    v.z = ldf(src, j + 2, isf);
    v.w = ldf(src, j + 3, isf);
    ((float4*)dst)[o] = v;
}

// --- per-tile exclusive scan (stage 1), both sides fused ---
__global__ void scan1b_k(const int* __restrict__ ldeg, const int* __restrict__ cdeg,
                         int* __restrict__ lout, int* __restrict__ cout,
                         int* __restrict__ bsumL, int* __restrict__ bsumC) {
    __shared__ int s[256];
    const int* in; int* out; int* bs; int tile;
    if (blockIdx.x < 256) { in = ldeg; out = lout; bs = bsumL; tile = blockIdx.x; }
    else                  { in = cdeg; out = cout; bs = bsumC; tile = blockIdx.x - 256; }
    int i = tile * 256 + threadIdx.x;
    int v = in[i];
    s[threadIdx.x] = v;
    __syncthreads();
#pragma unroll
    for (int off = 1; off < 256; off <<= 1) {
        int t = (threadIdx.x >= off) ? s[threadIdx.x - off] : 0;
        __syncthreads();
        s[threadIdx.x] += t;
        __syncthreads();
    }
    out[i] = s[threadIdx.x] - v;
    if (threadIdx.x == 255) bs[tile] = s[255];
}

// stage 2+3 fused: each block redundantly computes its own bsum prefix.
__global__ void scan3b_k(int* __restrict__ lptr, int* __restrict__ cptr,
                         const int* __restrict__ bsumL, const int* __restrict__ bsumC,
                         int* __restrict__ lcur, int* __restrict__ ccur,
                         const int* __restrict__ ldeg, const int* __restrict__ cdeg,
                         float* __restrict__ invsq_l, float* __restrict__ invsq_c) {
    __shared__ int sh[256];
    int b = blockIdx.x, t = threadIdx.x;
    const bool lside = (b < 256);
    const int tile = lside ? b : b - 256;
    const int* bs = lside ? bsumL : bsumC;
    sh[t] = (t < tile) ? bs[t] : 0;
    __syncthreads();
#pragma unroll
    for (int off = 128; off > 0; off >>= 1) {
        if (t < off) sh[t] += sh[t + off];
        __syncthreads();
    }
    const int pref = sh[0];
    int i = tile * 256 + t;
    if (lside) {
        int v = lptr[i] + pref;
        lptr[i] = v; lcur[i] = v;
        int d = ldeg[i];
        invsq_l[i] = d ? rsqrtf((float)d) : 0.0f;
    } else {
        int v = cptr[i] + pref;
        cptr[i] = v; ccur[i] = v;
        int d = cdeg[i];
        invsq_c[i] = d ? rsqrtf((float)d) : 0.0f;
    }
}

// CSR placement (other endpoint only; norm is separable)
__global__ void place_k(const int* __restrict__ li, const int* __restrict__ ci,
                        int* __restrict__ lcur, int* __restrict__ ccur,
                        int* __restrict__ l_other, int* __restrict__ c_other) {
    int e = blockIdx.x * 256 + threadIdx.x;
    if (e >= E_) return;
    int l = li[e], c = ci[e];
    int p = atomicAdd(&ccur[c], 1);
    c_other[p] = l;
    int q = atomicAdd(&lcur[l], 1);
    l_other[q] = c;
}

// it=0: l2l rows 0..127 only (sole reader is uconst_k pass 2). 8 blocks.
__global__ void bcast_k(const float* __restrict__ baseb, bf16* __restrict__ l2lb) {
    int id = blockIdx.x * 256 + threadIdx.x;   // 2048 ids, each writes 8 bf16
    const float* base = baseb + 256;
    int row = id >> 4, c8 = (id & 15) * 8;
    union { short8 v; unsigned short u[8]; } o;
#pragma unroll
    for (int k = 0; k < 8; k++) {
        bf16 b = __float2bfloat16(base[c8 + k]);
        o.u[k] = *(unsigned short*)&b;
    }
    *(short8*)&l2lb[(size_t)row * D_ + c8] = o.v;
}

// it=0 gather: messages are rank-1 (msg[o][col] = bf16(base[col]*invsq_src[o])),
// so synthesize them in-register: per edge load only invsq_src[o] (4B broadcast)
// instead of a 256B scattered message row. Accumulation structure/order is
// IDENTICAL to gather2_k (same 4-node 2-deep pairing, same tails) and the
// synthesized values are bitwise identical to what bcast would have written.
__global__ __launch_bounds__(256) void gather0_k(
    const int* __restrict__ cptr, const int* __restrict__ cdeg, const int* __restrict__ c_other,
    const float* __restrict__ baseb,
    const float* __restrict__ invsq_l, const float* __restrict__ invsq_c,
    float* __restrict__ caggr,
    const int* __restrict__ lptr, const int* __restrict__ ldeg, const int* __restrict__ l_other,
    float* __restrict__ laggr, int nC) {
    int wid = (blockIdx.x * 256 + threadIdx.x) >> 6;
    int lane = threadIdx.x & 63;
    int n0 = 4 * wid;
    bool cside = n0 < nC;
    int j0 = cside ? n0 : n0 - nC;
    const int* ptr = cside ? cptr : lptr;
    const int* dg  = cside ? cdeg : ldeg;
    const int* oth = cside ? c_other : l_other;
    const float* isrc = cside ? invsq_l : invsq_c;      // SOURCE-side scale
    const float* invsq = cside ? invsq_c : invsq_l;     // dest-side scale
    const float* base = baseb + (cside ? 0 : 128);      // l2c base / c2l base
    float* out = cside ? caggr : laggr;
    const float b0 = base[2 * lane], b1 = base[2 * lane + 1];

    int s0 = ptr[j0],     c0 = dg[j0];
    int s1 = ptr[j0 + 1], c1 = dg[j0 + 1];
    int s2 = ptr[j0 + 2], c2 = dg[j0 + 2];
    int s3 = ptr[j0 + 3], c3 = dg[j0 + 3];
    float2 A0 = {0.f, 0.f}, B0 = {0.f, 0.f};
    float2 A1 = {0.f, 0.f}, B1 = {0.f, 0.f};
    float2 A2 = {0.f, 0.f}, B2 = {0.f, 0.f};
    float2 A3 = {0.f, 0.f}, B3 = {0.f, 0.f};
    int k0 = 0, k1 = 0, k2 = 0, k3 = 0;

    // synth message pair for edge (s+k): identical bits to bcast+load path
#define GSC_(s, k) isrc[oth[(s) + (k)]]
#define GACCs_(a, sc) { (a).x += __bfloat162float(__float2bfloat16(b0 * (sc))); \
                        (a).y += __bfloat162float(__float2bfloat16(b1 * (sc))); }

    for (; k0 + 2 <= c0 && k1 + 2 <= c1 && k2 + 2 <= c2 && k3 + 2 <= c3;
         k0 += 2, k1 += 2, k2 += 2, k3 += 2) {
        float sc00 = GSC_(s0, k0), sc01 = GSC_(s0, k0 + 1);
        float sc10 = GSC_(s1, k1), sc11 = GSC_(s1, k1 + 1);
        float sc20 = GSC_(s2, k2), sc21 = GSC_(s2, k2 + 1);
        float sc30 = GSC_(s3, k3), sc31 = GSC_(s3, k3 + 1);
        GACCs_(A0, sc00); GACCs_(B0, sc01);
        GACCs_(A1, sc10); GACCs_(B1, sc11);
        GACCs_(A2, sc20); GACCs_(B2, sc21);
        GACCs_(A3, sc30); GACCs_(B3, sc31);
    }
    for (; k0 + 2 <= c0 && k1 + 2 <= c1; k0 += 2, k1 += 2) {
        float sc00 = GSC_(s0, k0), sc01 = GSC_(s0, k0 + 1);
        float sc10 = GSC_(s1, k1), sc11 = GSC_(s1, k1 + 1);
        GACCs_(A0, sc00); GACCs_(B0, sc01);
        GACCs_(A1, sc10); GACCs_(B1, sc11);
    }
    for (; k2 + 2 <= c2 && k3 + 2 <= c3; k2 += 2, k3 += 2) {
        float sc20 = GSC_(s2, k2), sc21 = GSC_(s2, k2 + 1);
        float sc30 = GSC_(s3, k3), sc31 = GSC_(s3, k3 + 1);
        GACCs_(A2, sc20); GACCs_(B2, sc21);
        GACCs_(A3, sc30); GACCs_(B3, sc31);
    }
    for (; k0 + 2 <= c0; k0 += 2) {
        float sa = GSC_(s0, k0), sb = GSC_(s0, k0 + 1);
        GACCs_(A0, sa); GACCs_(B0, sb);
    }
    for (; k1 + 2 <= c1; k1 += 2) {
        float sa = GSC_(s1, k1), sb = GSC_(s1, k1 + 1);
        GACCs_(A1, sa); GACCs_(B1, sb);
    }
    for (; k2 + 2 <= c2; k2 += 2) {
        float sa = GSC_(s2, k2), sb = GSC_(s2, k2 + 1);
        GACCs_(A2, sa); GACCs_(B2, sb);
    }
    for (; k3 + 2 <= c3; k3 += 2) {
        float sa = GSC_(s3, k3), sb = GSC_(s3, k3 + 1);
        GACCs_(A3, sa); GACCs_(B3, sb);
    }
    if (k0 < c0) { float sa = GSC_(s0, k0); GACCs_(A0, sa); }
    if (k1 < c1) { float sa = GSC_(s1, k1); GACCs_(A1, sa); }
    if (k2 < c2) { float sa = GSC_(s2, k2); GACCs_(A2, sa); }
    if (k3 < c3) { float sa = GSC_(s3, k3); GACCs_(A3, sa); }
#undef GSC_
#undef GACCs_

    float sc0 = invsq[j0], sc1 = invsq[j0 + 1];
    float sc2 = invsq[j0 + 2], sc3 = invsq[j0 + 3];
    float2 r;
    r.x = (A0.x + B0.x) * sc0; r.y = (A0.y + B0.y) * sc0;
    *(float2*)&out[(size_t)j0 * D_ + 2 * lane] = r;
    r.x = (A1.x + B1.x) * sc1; r.y = (A1.y + B1.y) * sc1;
    *(float2*)&out[(size_t)(j0 + 1) * D_ + 2 * lane] = r;
    r.x = (A2.x + B2.x) * sc2; r.y = (A2.y + B2.y) * sc2;
    *(float2*)&out[(size_t)(j0 + 2) * D_ + 2 * lane] = r;
    r.x = (A3.x + B3.x) * sc3; r.y = (A3.y + B3.y) * sc3;
    *(float2*)&out[(size_t)(j0 + 3) * D_ + 2 * lane] = r;
}

// it=0 uniform-range constants for update (runs EXACT update_k staging+MFMA
// sequence on tile 0 for the row-uniform K ranges; stores row 0's acc).
__global__ __launch_bounds__(256, 2) void uconst_k(
    const float* __restrict__ l_cur, const float* __restrict__ c_cur,
    const bf16* __restrict__ l2lb,
    const unsigned short* __restrict__ wt_hi, const unsigned short* __restrict__ wt_lo,
    float* __restrict__ uc) {
    __shared__ unsigned short a_hi[128][40], a_lo[128][40];
    __shared__ unsigned short b_hi[128][40], b_lo[128][40];
    const int t = threadIdx.x;
    const bool cseg = (blockIdx.x == 0);
    const int K = cseg ? 256 : 384;
    const float* A0 = cseg ? c_cur : l_cur;
    const unsigned short* Wh = wt_hi + (cseg ? 98304 : 131072);
    const unsigned short* Wl = wt_lo + (cseg ? 98304 : 131072);
    const int w = t >> 6, lane = t & 63;
    const int wr = w >> 1, wc = w & 1;
    const int quad = lane >> 4, cl = lane & 15;

    f32x4 acc[4][4];
#pragma unroll
    for (int i = 0; i < 4; i++)
#pragma unroll
        for (int j = 0; j < 4; j++) acc[i][j] = (f32x4){0.f, 0.f, 0.f, 0.f};

    for (int kt = 0; kt < 128; kt += 32) {
#pragma unroll
        for (int i = 0; i < 4; i++) {
            int f = t + 256 * i;
            int r = f >> 3, kq = f & 7;
            const float4 v = *(const float4*)&A0[(size_t)r * D_ + kt + 4 * kq];
            unsigned short h0, l0, h1, l1, h2, l2, h3, l3;
            split2(v.x, h0, l0); split2(v.y, h1, l1);
            split2(v.z, h2, l2); split2(v.w, h3, l3);
            *(ushort4*)&a_hi[r][4 * kq] = make_ushort4(h0, h1, h2, h3);
            *(ushort4*)&a_lo[r][4 * kq] = make_ushort4(l0, l1, l2, l3);
            *(ushort4*)&b_hi[r][4 * kq] = *(const ushort4*)&Wh[(size_t)r * K + kt + 4 * kq];
            *(ushort4*)&b_lo[r][4 * kq] = *(const ushort4*)&Wl[(size_t)r * K + kt + 4 * kq];
        }
        __syncthreads();
        short8 af_h[4], af_l[4];
#pragma unroll
        for (int i = 0; i < 4; i++) {
            int row = 64 * wr + 16 * i + cl;
            af_h[i] = *(const short8*)&a_hi[row][quad * 8];
            af_l[i] = *(const short8*)&a_lo[row][quad * 8];
        }
#pragma unroll
        for (int j = 0; j < 4; j++) {
            int col = 64 * wc + 16 * j + cl;
            short8 bf_h = *(const short8*)&b_hi[col][quad * 8];
            short8 bf_l = *(const short8*)&b_lo[col][quad * 8];
#pragma unroll
            for (int i = 0; i < 4; i++) {
                acc[i][j] = __builtin_amdgcn_mfma_f32_16x16x32_bf16(af_h[i], bf_h, acc[i][j], 0, 0, 0);
                acc[i][j] = __builtin_amdgcn_mfma_f32_16x16x32_bf16(af_h[i], bf_l, acc[i][j], 0, 0, 0);
                acc[i][j] = __builtin_amdgcn_mfma_f32_16x16x32_bf16(af_l[i], bf_h, acc[i][j], 0, 0, 0);
            }
        }
        __syncthreads();
    }
#pragma unroll
    for (int j = 0; j < 4; j++) {
        int col = 64 * wc + 16 * j + cl;
        if (w < 2 && lane < 16) uc[(cseg ? 0 : 128) + col] = acc[0][j][0];
    }
    if (cseg) return;

    // pass 2: l2l tiles kt=256..383 accumulated from zero (bf16 hi-plane only)
#pragma unroll
    for (int i = 0; i < 4; i++)
#pragma unroll
        for (int j = 0; j < 4; j++) acc[i][j] = (f32x4){0.f, 0.f, 0.f, 0.f};
    for (int kt = 256; kt < 384; kt += 32) {
        const int koff = kt & 127;
#pragma unroll
        for (int i = 0; i < 4; i++) {
            int f = t + 256 * i;
            int r = f >> 3, kq = f & 7;
            *(ushort4*)&a_hi[r][4 * kq] =
                *(const ushort4*)&l2lb[(size_t)r * D_ + koff + 4 * kq];
            *(ushort4*)&b_hi[r][4 * kq] = *(const ushort4*)&Wh[(size_t)r * K + kt + 4 * kq];
            *(ushort4*)&b_lo[r][4 * kq] = *(const ushort4*)&Wl[(size_t)r * K + kt + 4 * kq];
        }
        __syncthreads();
        short8 af_h[4];
#pragma unroll
        for (int i = 0; i < 4; i++) {
            int row = 64 * wr + 16 * i + cl;
            af_h[i] = *(const short8*)&a_hi[row][quad * 8];
        }
#pragma unroll
        for (int j = 0; j < 4; j++) {
            int col = 64 * wc + 16 * j + cl;
            short8 bf_h = *(const short8*)&b_hi[col][quad * 8];
            short8 bf_l = *(const short8*)&b_lo[col][quad * 8];
#pragma unroll
            for (int i = 0; i < 4; i++) {
                acc[i][j] = __builtin_amdgcn_mfma_f32_16x16x32_bf16(af_h[i], bf_h, acc[i][j], 0, 0, 0);
                acc[i][j] = __builtin_amdgcn_mfma_f32_16x16x32_bf16(af_h[i], bf_l, acc[i][j], 0, 0, 0);
            }
        }
        __syncthreads();
    }
#pragma unroll
    for (int j = 0; j < 4; j++) {
        int col = 64 * wc + 16 * j + cl;
        if (w < 2 && lane < 16) uc[256 + col] = acc[0][j][0];
    }
}

// it=0 update: acc from uniform-range constants; only the 4 aggregate K-tiles.
__global__ __launch_bounds__(256, 2) void update0_k(
    const float* __restrict__ laggr, const float* __restrict__ caggr,
    const unsigned short* __restrict__ wt_hi, const unsigned short* __restrict__ wt_lo,
    const float* __restrict__ bb, const float* __restrict__ uc,
    float* __restrict__ c_nxt, float* __restrict__ l_nxt) {
    __shared__ unsigned short a_hi[128][40], a_lo[128][40];
    __shared__ unsigned short b_hi[128][40], b_lo[128][40];
    const int t = threadIdx.x;
    int b = blockIdx.x;
    const bool cseg = (b < 256);
    const int tile = cseg ? b : b - 256;
    const int K = cseg ? 256 : 384;
    const float* A1 = cseg ? caggr : laggr;
    const unsigned short* Wh = wt_hi + (cseg ? 98304 : 131072);
    const unsigned short* Wl = wt_lo + (cseg ? 98304 : 131072);
    const float* bias = bb + (cseg ? 768 : 896);
    const float* uc0 = uc + (cseg ? 0 : 128);
    const int br0 = tile * 128;
    const int w = t >> 6, lane = t & 63;
    const int wr = w >> 1, wc = w & 1;
    const int quad = lane >> 4, cl = lane & 15;

    f32x4 acc[4][4];
#pragma unroll
    for (int j = 0; j < 4; j++) {
        int col = 64 * wc + 16 * j + cl;
        float cv = uc0[col];
#pragma unroll
        for (int i = 0; i < 4; i++) acc[i][j] = (f32x4){cv, cv, cv, cv};
    }

    for (int kt = 128; kt < 256; kt += 32) {
        const int koff = kt & 127;
#pragma unroll
        for (int i = 0; i < 4; i++) {
            int f = t + 256 * i;
            int r = f >> 3, kq = f & 7;
            const float4 v = *(const float4*)&A1[(size_t)(br0 + r) * D_ + koff + 4 * kq];
            unsigned short h0, l0, h1, l1, h2, l2, h3, l3;
            split2(v.x, h0, l0); split2(v.y, h1, l1);
            split2(v.z, h2, l2); split2(v.w, h3, l3);
            *(ushort4*)&a_hi[r][4 * kq] = make_ushort4(h0, h1, h2, h3);
            *(ushort4*)&a_lo[r][4 * kq] = make_ushort4(l0, l1, l2, l3);
            *(ushort4*)&b_hi[r][4 * kq] = *(const ushort4*)&Wh[(size_t)r * K + kt + 4 * kq];
            *(ushort4*)&b_lo[r][4 * kq] = *(const ushort4*)&Wl[(size_t)r * K + kt + 4 * kq];
        }
        __syncthreads();
        short8 af_h[4], af_l[4];
#pragma unroll
        for (int i = 0; i < 4; i++) {
            int row = 64 * wr + 16 * i + cl;
            af_h[i] = *(const short8*)&a_hi[row][quad * 8];
            af_l[i] = *(const short8*)&a_lo[row][quad * 8];
        }
#pragma unroll
        for (int j = 0; j < 4; j++) {
            int col = 64 * wc + 16 * j + cl;
            short8 bf_h = *(const short8*)&b_hi[col][quad * 8];
            short8 bf_l = *(const short8*)&b_lo[col][quad * 8];
#pragma unroll
            for (int i = 0; i < 4; i++) {
                acc[i][j] = __builtin_amdgcn_mfma_f32_16x16x32_bf16(af_h[i], bf_h, acc[i][j], 0, 0, 0);
                acc[i][j] = __builtin_amdgcn_mfma_f32_16x16x32_bf16(af_h[i], bf_l, acc[i][j], 0, 0, 0);
                acc[i][j] = __builtin_amdgcn_mfma_f32_16x16x32_bf16(af_l[i], bf_h, acc[i][j], 0, 0, 0);
            }
        }
        __syncthreads();
    }
    float* outp = cseg ? c_nxt : l_nxt;
#pragma unroll
    for (int j = 0; j < 4; j++) {
        int col = 64 * wc + 16 * j + cl;
        float bv = bias[col];
        float l2lc = cseg ? 0.0f : uc[256 + col];
#pragma unroll
        for (int i = 0; i < 4; i++) {
            int rbase = br0 + 64 * wr + 16 * i + quad * 4;
#pragma unroll
            for (int rg = 0; rg < 4; rg++) {
                float v = (acc[i][j][rg] + l2lc) + bv;
                outp[(size_t)(rbase + rg) * D_ + col] = v;
            }
        }
    }
}

// Fused pull-aggregation, both directions (r9 4-node/2-deep structure, kept).
__global__ __launch_bounds__(256) void gather2_k(
    const int* __restrict__ cptr, const int* __restrict__ cdeg, const int* __restrict__ c_other,
    const unsigned int* __restrict__ lmsg, const float* __restrict__ invsq_c, float* __restrict__ caggr,
    const int* __restrict__ lptr, const int* __restrict__ ldeg, const int* __restrict__ l_other,
    const unsigned int* __restrict__ cmsg, const float* __restrict__ invsq_l, float* __restrict__ laggr,
    int nC) {
    int wid = (blockIdx.x * 256 + threadIdx.x) >> 6;
    int lane = threadIdx.x & 63;
    int n0 = 4 * wid;
    bool cside = n0 < nC;
    int j0 = cside ? n0 : n0 - nC;
    const int* ptr = cside ? cptr : lptr;
    const int* dg  = cside ? cdeg : ldeg;
    const int* oth = cside ? c_other : l_other;
    const unsigned int* msg = cside ? lmsg : cmsg;
    const float* invsq = cside ? invsq_c : invsq_l;
    float* out = cside ? caggr : laggr;

    int s0 = ptr[j0],     c0 = dg[j0];
    int s1 = ptr[j0 + 1], c1 = dg[j0 + 1];
    int s2 = ptr[j0 + 2], c2 = dg[j0 + 2];
    int s3 = ptr[j0 + 3], c3 = dg[j0 + 3];
    float2 A0 = {0.f, 0.f}, B0 = {0.f, 0.f};
    float2 A1 = {0.f, 0.f}, B1 = {0.f, 0.f};
    float2 A2 = {0.f, 0.f}, B2 = {0.f, 0.f};
    float2 A3 = {0.f, 0.f}, B3 = {0.f, 0.f};
    int k0 = 0, k1 = 0, k2 = 0, k3 = 0;

#define GLD_(s, k) msg[(size_t)oth[(s) + (k)] * 64 + lane]
#define GACC_(a, u) { (a).x += __uint_as_float((u) << 16); \
                      (a).y += __uint_as_float((u) & 0xffff0000u); }

    for (; k0 + 2 <= c0 && k1 + 2 <= c1 && k2 + 2 <= c2 && k3 + 2 <= c3;
         k0 += 2, k1 += 2, k2 += 2, k3 += 2) {
        unsigned int u00 = GLD_(s0, k0), u01 = GLD_(s0, k0 + 1);
        unsigned int u10 = GLD_(s1, k1), u11 = GLD_(s1, k1 + 1);
        unsigned int u20 = GLD_(s2, k2), u21 = GLD_(s2, k2 + 1);
        unsigned int u30 = GLD_(s3, k3), u31 = GLD_(s3, k3 + 1);
        GACC_(A0, u00); GACC_(B0, u01);
        GACC_(A1, u10); GACC_(B1, u11);
        GACC_(A2, u20); GACC_(B2, u21);
        GACC_(A3, u30); GACC_(B3, u31);
    }
    for (; k0 + 2 <= c0 && k1 + 2 <= c1; k0 += 2, k1 += 2) {
        unsigned int u00 = GLD_(s0, k0), u01 = GLD_(s0, k0 + 1);
        unsigned int u10 = GLD_(s1, k1), u11 = GLD_(s1, k1 + 1);
        GACC_(A0, u00); GACC_(B0, u01);
        GACC_(A1, u10); GACC_(B1, u11);
    }
    for (; k2 + 2 <= c2 && k3 + 2 <= c3; k2 += 2, k3 += 2) {
        unsigned int u20 = GLD_(s2, k2), u21 = GLD_(s2, k2 + 1);
        unsigned int u30 = GLD_(s3, k3), u31 = GLD_(s3, k3 + 1);
        GACC_(A2, u20); GACC_(B2, u21);
        GACC_(A3, u30); GACC_(B3, u31);
    }
    for (; k0 + 2 <= c0; k0 += 2) {
        unsigned int ua = GLD_(s0, k0), ub = GLD_(s0, k0 + 1);
        GACC_(A0, ua); GACC_(B0, ub);
    }
    for (; k1 + 2 <= c1; k1 += 2) {
        unsigned int ua = GLD_(s1, k1), ub = GLD_(s1, k1 + 1);
        GACC_(A1, ua); GACC_(B1, ub);
    }
    for (; k2 + 2 <= c2; k2 += 2) {
        unsigned int ua = GLD_(s2, k2), ub = GLD_(s2, k2 + 1);
        GACC_(A2, ua); GACC_(B2, ub);
    }
    for (; k3 + 2 <= c3; k3 += 2) {
        unsigned int ua = GLD_(s3, k3), ub = GLD_(s3, k3 + 1);
        GACC_(A3, ua); GACC_(B3, ub);
    }
    if (k0 < c0) { unsigned int u = GLD_(s0, k0); GACC_(A0, u); }
    if (k1 < c1) { unsigned int u = GLD_(s1, k1); GACC_(A1, u); }
    if (k2 < c2) { unsigned int u = GLD_(s2, k2); GACC_(A2, u); }
    if (k3 < c3) { unsigned int u = GLD_(s3, k3); GACC_(A3, u); }
#undef GLD_
#undef GACC_

    float sc0 = invsq[j0], sc1 = invsq[j0 + 1];
    float sc2 = invsq[j0 + 2], sc3 = invsq[j0 + 3];
    float2 r;
    r.x = (A0.x + B0.x) * sc0; r.y = (A0.y + B0.y) * sc0;
    *(float2*)&out[(size_t)j0 * D_ + 2 * lane] = r;
    r.x = (A1.x + B1.x) * sc1; r.y = (A1.y + B1.y) * sc1;
    *(float2*)&out[(size_t)(j0 + 1) * D_ + 2 * lane] = r;
    r.x = (A2.x + B2.x) * sc2; r.y = (A2.y + B2.y) * sc2;
    *(float2*)&out[(size_t)(j0 + 2) * D_ + 2 * lane] = r;
    r.x = (A3.x + B3.x) * sc3; r.y = (A3.y + B3.y) * sc3;
    *(float2*)&out[(size_t)(j0 + 3) * D_ + 2 * lane] = r;
}

// ---------- fused 2-layer MLPs, all three in one launch; 128-row tiles ----------
// (EXACT round-0 structure.) base_out != nullptr: ALSO store the pre-scale fp32
// output row (acc+bias for row 0) to base_out[seg*128 + col].
__global__ __launch_bounds__(256, 2) void mlp3_k(
    const float* __restrict__ l_cur, const float* __restrict__ c_cur,
    const unsigned short* __restrict__ wt_hi, const unsigned short* __restrict__ wt_lo,
    const float* __restrict__ bb,
    const float* __restrict__ invsq_l, const float* __restrict__ invsq_c,
    bf16* __restrict__ l_msg, bf16* __restrict__ c_msg, bf16* __restrict__ l2lb,
    int nL, int nC, float* __restrict__ base_out) {
    __shared__ char smem[66048];
    unsigned short (*a_hi)[40] = (unsigned short(*)[40])(smem);
    unsigned short (*a_lo)[40] = (unsigned short(*)[40])(smem + 10240);
    unsigned short (*b_hi)[40] = (unsigned short(*)[40])(smem + 20480);
    unsigned short (*b_lo)[40] = (unsigned short(*)[40])(smem + 30720);
    unsigned short* h_hi = (unsigned short*)(smem);          // phase 2 aliases tiles
    unsigned short* h_lo = (unsigned short*)(smem + 32768);
    float* scv = (float*)(smem + 65536);                     // 128 floats, non-aliased

    int b = blockIdx.x, seg, tile;
    if (b < nL)           { seg = 0; tile = b; }
    else if (b < nL + nC) { seg = 1; tile = b - nL; }
    else                  { seg = 2; tile = b - nL - nC; }
    const float* A = (seg == 1) ? c_cur : l_cur;
    bf16* outp = (seg == 0) ? l_msg : (seg == 1) ? c_msg : l2lb;
    const float* invsq = (seg == 0) ? invsq_l : (seg == 1) ? invsq_c : nullptr;
    const unsigned short* W1h = wt_hi + seg * 32768;
    const unsigned short* W1l = wt_lo + seg * 32768;
    const unsigned short* W2h = W1h + 16384;
    const unsigned short* W2l = W1l + 16384;
    const float* b1v = bb + seg * 256;
    const float* b2v = b1v + 128;
    const int swap = (seg == 2);

    const int t = threadIdx.x;
    const int br0 = tile * 128;
    const int w = t >> 6, lane = t & 63;
    const int wr = w >> 1, wc = w & 1;
    const int quad = lane >> 4, cl = lane & 15;

    if (t < 128) scv[t] = invsq ? invsq[br0 + t] : 1.0f;

    f32x4 acc[4][4];
#pragma unroll
    for (int i = 0; i < 4; i++)
#pragma unroll
        for (int j = 0; j < 4; j++) acc[i][j] = (f32x4){0.f, 0.f, 0.f, 0.f};

    // ---- phase 1: h = A @ W1 ----
    for (int kt = 0; kt < 128; kt += 32) {
#pragma unroll
        for (int i = 0; i < 4; i++) {
            int f = t + 256 * i;
            int r = f >> 3, kq = f & 7;
            int gr = br0 + r;
            if (swap) gr ^= 1;
            const float4 v = *(const float4*)&A[(size_t)gr * D_ + kt + 4 * kq];
            unsigned short h0, l0, h1, l1, h2, l2, h3, l3;
            split2(v.x, h0, l0); split2(v.y, h1, l1);
            split2(v.z, h2, l2); split2(v.w, h3, l3);
            *(ushort4*)&a_hi[r][4 * kq] = make_ushort4(h0, h1, h2, h3);
            *(ushort4*)&a_lo[r][4 * kq] = make_ushort4(l0, l1, l2, l3);
            *(ushort4*)&b_hi[r][4 * kq] = *(const ushort4*)&W1h[(size_t)r * 128 + kt + 4 * kq];
            *(ushort4*)&b_lo[r][4 * kq] = *(const ushort4*)&W1l[(size_t)r * 128 + kt + 4 * kq];
        }
        __syncthreads();
        short8 af_h[4], af_l[4];
#pragma unroll
        for (int i = 0; i < 4; i++) {
            int row = 64 * wr + 16 * i + cl;
            af_h[i] = *(const short8*)&a_hi[row][quad * 8];
            af_l[i] = *(const short8*)&a_lo[row][quad * 8];
        }
#pragma unroll
        for (int j = 0; j < 4; j++) {
            int col = 64 * wc + 16 * j + cl;
            short8 bf_h = *(const short8*)&b_hi[col][quad * 8];
            short8 bf_l = *(const short8*)&b_lo[col][quad * 8];
#pragma unroll
            for (int i = 0; i < 4; i++) {
                acc[i][j] = __builtin_amdgcn_mfma_f32_16x16x32_bf16(af_h[i], bf_h, acc[i][j], 0, 0, 0);
                acc[i][j] = __builtin_amdgcn_mfma_f32_16x16x32_bf16(af_h[i], bf_l, acc[i][j], 0, 0, 0);
                acc[i][j] = __builtin_amdgcn_mfma_f32_16x16x32_bf16(af_l[i], bf_h, acc[i][j], 0, 0, 0);
            }
        }
        __syncthreads();
    }
    // h epilogue: bias + relu + split -> swizzled LDS. C/D: col=cl, row=quad*4+reg.
#pragma unroll
    for (int j = 0; j < 4; j++) {
        int col = 64 * wc + 16 * j + cl;
        float bv = b1v[col];
        int g = col >> 3, go = col & 7;
#pragma unroll
        for (int i = 0; i < 4; i++) {
            int rloc = 64 * wr + 16 * i + quad * 4;
#pragma unroll
            for (int rg = 0; rg < 4; rg++) {
                float v = fmaxf(acc[i][j][rg] + bv, 0.0f);
                unsigned short hh, ll;
                split2(v, hh, ll);
                int r = rloc + rg;
                int off = r * 128 + ((g ^ (r & 15)) << 3) + go;
                h_hi[off] = hh;
                h_lo[off] = ll;
            }
        }
    }
    __syncthreads();
    // ---- phase 2: out = (h @ W2 + b2) * scv -> bf16 ----
#pragma unroll
    for (int i = 0; i < 4; i++)
#pragma unroll
        for (int j = 0; j < 4; j++) acc[i][j] = (f32x4){0.f, 0.f, 0.f, 0.f};

    for (int kt = 0; kt < 128; kt += 32) {
        short8 af_h[4], af_l[4];
        int gbase = (kt >> 3) + quad;
#pragma unroll
        for (int i = 0; i < 4; i++) {
            int r = 64 * wr + 16 * i + cl;
            int off = r * 128 + ((gbase ^ cl) << 3);
            af_h[i] = *(const short8*)&h_hi[off];
            af_l[i] = *(const short8*)&h_lo[off];
        }
#pragma unroll
        for (int j = 0; j < 4; j++) {
            int col = 64 * wc + 16 * j + cl;
            const short8 bf_h = *(const short8*)&W2h[(size_t)col * 128 + kt + quad * 8];
            const short8 bf_l = *(const short8*)&W2l[(size_t)col * 128 + kt + quad * 8];
#pragma unroll
            for (int i = 0; i < 4; i++) {
                acc[i][j] = __builtin_amdgcn_mfma_f32_16x16x32_bf16(af_h[i], bf_h, acc[i][j], 0, 0, 0);
                acc[i][j] = __builtin_amdgcn_mfma_f32_16x16x32_bf16(af_h[i], bf_l, acc[i][j], 0, 0, 0);
                acc[i][j] = __builtin_amdgcn_mfma_f32_16x16x32_bf16(af_l[i], bf_h, acc[i][j], 0, 0, 0);
            }
        }
    }
#pragma unroll
    for (int j = 0; j < 4; j++) {
        int col = 64 * wc + 16 * j + cl;
        float bv = b2v[col];
        if (base_out && w < 2 && lane < 16)
            base_out[seg * 128 + col] = acc[0][j][0] + bv;   // row 0, pre-scale fp32
#pragma unroll
        for (int i = 0; i < 4; i++) {
            int rloc = 64 * wr + 16 * i + quad * 4;
#pragma unroll
            for (int rg = 0; rg < 4; rg++)
                outp[(size_t)(br0 + rloc + rg) * D_ + col] =
                    __float2bfloat16((acc[i][j][rg] + bv) * scv[rloc + rg]);
        }
    }
}

// ---------- fused update GEMMs; 128-row tiles (EXACT round-0 structure) ----------
template <int FINAL>
__global__ __launch_bounds__(256, 2) void update_k(
    const float* __restrict__ l_cur, const float* __restrict__ c_cur,
    const float* __restrict__ laggr, const float* __restrict__ caggr,
    const bf16* __restrict__ l2lb,
    const unsigned short* __restrict__ wt_hi, const unsigned short* __restrict__ wt_lo,
    const float* __restrict__ bb,
    float* __restrict__ c_nxt, float* __restrict__ l_nxt,
    void* __restrict__ dout, const int* __restrict__ flags) {
    __shared__ unsigned short a_hi[128][40], a_lo[128][40];
    __shared__ unsigned short b_hi[128][40], b_lo[128][40];
    const int t = threadIdx.x;
    int b = blockIdx.x;
    const bool cseg = (!FINAL) && (b < 256);
    const int tile = (FINAL || cseg) ? b : b - 256;
    const int K = cseg ? 256 : 384;
    const float* A0 = cseg ? c_cur : l_cur;
    const float* A1 = cseg ? caggr : laggr;
    const unsigned short* Wh = wt_hi + (cseg ? 98304 : 131072);
    const unsigned short* Wl = wt_lo + (cseg ? 98304 : 131072);
    const float* bias = bb + (cseg ? 768 : 896);
    const int br0 = tile * 128;
    const int w = t >> 6, lane = t & 63;
    const int wr = w >> 1, wc = w & 1;
    const int quad = lane >> 4, cl = lane & 15;

    f32x4 acc[4][4];
#pragma unroll
    for (int i = 0; i < 4; i++)
#pragma unroll
        for (int j = 0; j < 4; j++) acc[i][j] = (f32x4){0.f, 0.f, 0.f, 0.f};

    for (int kt = 0; kt < K; kt += 32) {
        const bool haslo = (kt < 256);
        const int koff = kt & 127;
#pragma unroll
        for (int i = 0; i < 4; i++) {
            int f = t + 256 * i;
            int r = f >> 3, kq = f & 7;
            if (haslo) {
                const float* As = (kt < 128) ? A0 : A1;
                const float4 v = *(const float4*)&As[(size_t)(br0 + r) * D_ + koff + 4 * kq];
                unsigned short h0, l0, h1, l1, h2, l2, h3, l3;
                split2(v.x, h0, l0); split2(v.y, h1, l1);
                split2(v.z, h2, l2); split2(v.w, h3, l3);
                *(ushort4*)&a_hi[r][4 * kq] = make_ushort4(h0, h1, h2, h3);
                *(ushort4*)&a_lo[r][4 * kq] = make_ushort4(l0, l1, l2, l3);
            } else {
                *(ushort4*)&a_hi[r][4 * kq] =
                    *(const ushort4*)&l2lb[(size_t)(br0 + r) * D_ + koff + 4 * kq];
            }
            *(ushort4*)&b_hi[r][4 * kq] = *(const ushort4*)&Wh[(size_t)r * K + kt + 4 * kq];
            *(ushort4*)&b_lo[r][4 * kq] = *(const ushort4*)&Wl[(size_t)r * K + kt + 4 * kq];
        }
        __syncthreads();
        short8 af_h[4], af_l[4];
#pragma unroll
        for (int i = 0; i < 4; i++) {
            int row = 64 * wr + 16 * i + cl;
            af_h[i] = *(const short8*)&a_hi[row][quad * 8];
            if (haslo) af_l[i] = *(const short8*)&a_lo[row][quad * 8];
        }
#pragma unroll
        for (int j = 0; j < 4; j++) {
            int col = 64 * wc + 16 * j + cl;
            short8 bf_h = *(const short8*)&b_hi[col][quad * 8];
            short8 bf_l = *(const short8*)&b_lo[col][quad * 8];
#pragma unroll
            for (int i = 0; i < 4; i++) {
                acc[i][j] = __builtin_amdgcn_mfma_f32_16x16x32_bf16(af_h[i], bf_h, acc[i][j], 0, 0, 0);
                acc[i][j] = __builtin_amdgcn_mfma_f32_16x16x32_bf16(af_h[i], bf_l, acc[i][j], 0, 0, 0);
                if (haslo)
                    acc[i][j] = __builtin_amdgcn_mfma_f32_16x16x32_bf16(af_l[i], bf_h, acc[i][j], 0, 0, 0);
            }
        }
        __syncthreads();
    }
    const int f32out = FINAL ? flags[0] : 1;
#pragma unroll
    for (int j = 0; j < 4; j++) {
        int col = 64 * wc + 16 * j + cl;
        float bv = bias[col];
#pragma unroll
        for (int i = 0; i < 4; i++) {
            int rbase = br0 + 64 * wr + 16 * i + quad * 4;
#pragma unroll
            for (int rg = 0; rg < 4; rg++) {
                float v = acc[i][j][rg] + bv;
                size_t idx = (size_t)(rbase + rg) * D_ + col;
                if (FINAL) {
                    if (f32out) ((float*)dout)[idx] = v;
                    else        ((bf16*)dout)[idx] = __float2bfloat16(v);
                } else {
                    (cseg ? c_nxt : l_nxt)[idx] = v;
                }
            }
        }
    }
}

extern "C" void kernel_launch(void* const* d_in, const int* in_sizes, int n_in,
                              void* d_out, int out_size, void* d_ws, size_t ws_size,
                              hipStream_t stream) {
    const int* li_raw = (const int*)d_in[0];
    const int* ci_raw = (const int*)d_in[1];

    // ---- workspace layout (flags after cdegi -> one zeroing memset) ----
    float* ws = (float*)d_ws;
    float* lbuf0 = ws;                               // L*D
    float* lbuf1 = lbuf0 + (size_t)L_ * D_;          // L*D  (doubles as bf16 l_msg)
    float* l2lb  = lbuf1 + (size_t)L_ * D_;          // L*D  (bf16 l2l messages)
    float* laggr = l2lb + (size_t)L_ * D_;           // L*D
    float* cbuf0 = laggr + (size_t)L_ * D_;          // C*D
    float* cbuf1 = cbuf0 + (size_t)C_ * D_;          // C*D  (doubles as bf16 c_msg)
    float* caggr = cbuf1 + (size_t)C_ * D_;          // C*D
    float* invsq_l = caggr + (size_t)C_ * D_;        // L
    float* invsq_c = invsq_l + L_;                   // C
    float* bb    = invsq_c + C_;                     // 1024 bias floats
    unsigned short* wt_hi = (unsigned short*)(bb + 1024);   // 180224 ushorts
    unsigned short* wt_lo = wt_hi + 180224;                 // 180224 ushorts
    int*   li    = (int*)(wt_lo + 180224);           // E
    int*   ci    = li + E_;                          // E
    int*   l_other = ci + E_;                        // E
    int*   c_other = l_other + E_;                   // E
    int*   ldegi = c_other + E_;                     // L
    int*   cdegi = ldegi + L_;                       // C
    int*   flags = cdegi + C_;                       // 2  (contiguous with deg arrays)
    int*   lptr  = flags + 2;                        // L
    int*   cptr  = lptr + L_;                        // C
    int*   lcur  = cptr + C_;                        // L
    int*   ccur  = lcur + L_;                        // C
    int*   bsumL = ccur + C_;                        // 256
    int*   bsumC = bsumL + 256;                      // 128
    float* baseb = (float*)(bsumC + 128);            // 384 fp32 (it=0 MLP base rows)
    float* ucbuf = baseb + 384;                      // 384 fp32 (it=0 update consts)

    // --- one memset zeroes degrees + flags; then dtype detection ---
    hipMemsetAsync(ldegi, 0, ((size_t)(L_ + C_) + 2) * sizeof(int), stream);
    detect_k<<<16, 512, 0, stream>>>((const unsigned short*)d_in[4], li_raw, flags);

    // --- fused preamble: fixdeg + weight-split + tile-0 embedding-init ---
    prep_k<<<2788, 256, 0, stream>>>(
        li_raw, ci_raw, li, ci, ldegi, cdegi,
        d_in[4], d_in[6], d_in[8], d_in[10], d_in[12], d_in[14], d_in[16], d_in[18],
        d_in[5], d_in[7], d_in[9], d_in[11], d_in[13], d_in[15], d_in[17], d_in[19],
        wt_hi, wt_lo, bb,
        d_in[2], d_in[3], lbuf0, cbuf0, flags);

    // --- CSR build ---
    scan1b_k<<<384, 256, 0, stream>>>(ldegi, cdegi, lptr, cptr, bsumL, bsumC);
    scan3b_k<<<384, 256, 0, stream>>>(lptr, cptr, bsumL, bsumC, lcur, ccur,
                                      ldegi, cdegi, invsq_l, invsq_c);
    place_k<<<E_ / 256, 256, 0, stream>>>(li, ci, lcur, ccur, l_other, c_other);

    float* l_cur = lbuf0; float* l_nxt = lbuf1;
    float* c_cur = cbuf0; float* c_nxt = cbuf1;

    const int nL = L_ / 128, nC = C_ / 128;

    // ---- it=0: embeddings row-uniform -> 3-block mlp3 captures base rows;
    //      gather0 synthesizes the rank-1 messages in-register (no message
    //      materialization); bcast writes only l2lb rows 0..127 for uconst;
    //      update0 runs only the aggregate K-range ----
    mlp3_k<<<3, 256, 0, stream>>>(
        l_cur, c_cur, wt_hi, wt_lo, bb, invsq_l, invsq_c,
        (bf16*)l_nxt, (bf16*)c_nxt, (bf16*)l2lb, 1, 1, baseb);
    bcast_k<<<8, 256, 0, stream>>>(baseb, (bf16*)l2lb);
    uconst_k<<<2, 256, 0, stream>>>(
        l_cur, c_cur, (const bf16*)l2lb, wt_hi, wt_lo, ucbuf);
    gather0_k<<<(C_ + L_) / 16, 256, 0, stream>>>(
        cptr, cdegi, c_other, baseb, invsq_l, invsq_c, caggr,
        lptr, ldegi, l_other, laggr, C_);
    update0_k<<<768, 256, 0, stream>>>(
        laggr, caggr, wt_hi, wt_lo, bb, ucbuf, c_nxt, l_nxt);
    { float* tmp = l_cur; l_cur = l_nxt; l_nxt = tmp;
      tmp = c_cur; c_cur = c_nxt; c_nxt = tmp; }

    // ---- it=1,2: full pipeline ----
    for (int it = 1; it < 3; it++) {
        mlp3_k<<<2 * nL + nC, 256, 0, stream>>>(
            l_cur, c_cur, wt_hi, wt_lo, bb, invsq_l, invsq_c,
            (bf16*)l_nxt, (bf16*)c_nxt, (bf16*)l2lb, nL, nC, nullptr);
        gather2_k<<<(C_ + L_) / 16, 256, 0, stream>>>(
            cptr, cdegi, c_other, (const unsigned int*)l_nxt, invsq_c, caggr,
            lptr, ldegi, l_other, (const unsigned int*)c_nxt, invsq_l, laggr, C_);
        update_k<0><<<768, 256, 0, stream>>>(
            l_cur, c_cur, laggr, caggr, (const bf16*)l2lb, wt_hi, wt_lo, bb,
            c_nxt, l_nxt, nullptr, flags);
        float* tmp = l_cur; l_cur = l_nxt; l_nxt = tmp;
        tmp = c_cur; c_cur = c_nxt; c_nxt = tmp;
    }
    // --- final iteration: c-update dead -> skip l2c MLP, c-gather, c-update;
    //     fuse output dtype conversion into the l-update epilogue ---
    mlp3_k<<<nC + nL, 256, 0, stream>>>(
        l_cur, c_cur, wt_hi, wt_lo, bb, invsq_l, invsq_c,
        (bf16*)l_nxt, (bf16*)c_nxt, (bf16*)l2lb, 0, nC, nullptr);
    gather2_k<<<L_ / 16, 256, 0, stream>>>(
        cptr, cdegi, c_other, (const unsigned int*)l_nxt, invsq_c, caggr,
        lptr, ldegi, l_other, (const unsigned int*)c_nxt, invsq_l, laggr, 0);
    update_k<1><<<512, 256, 0, stream>>>(
        l_cur, c_cur, laggr, caggr, (const bf16*)l2lb, wt_hi, wt_lo, bb,
        nullptr, nullptr, d_out, flags);
}